// Round 1
// baseline (1084.203 us; speedup 1.0000x reference)
//
#include <hip/hip_runtime.h>

#define N_NODES 100000
#define N_EDGES 1600000
#define IN_DIM 128
#define HID_DIM 64
#define OUT_DIM 64

// ---------------- degree: deg[row[e]] += w[e] ----------------
__global__ void deg_kernel(const int* __restrict__ rows, const float* __restrict__ w,
                           float* __restrict__ deg, int E) {
    int e = blockIdx.x * blockDim.x + threadIdx.x;
    if (e < E) atomicAdd(&deg[rows[e]], w[e]);
}

// ---------------- norm[e] = dis[row]*w*dis[col] ----------------
__global__ void norm_kernel(const int* __restrict__ rows, const int* __restrict__ cols,
                            const float* __restrict__ w, const float* __restrict__ deg,
                            float* __restrict__ norm, int E) {
    int e = blockIdx.x * blockDim.x + threadIdx.x;
    if (e >= E) return;
    float dr = deg[rows[e]];
    float dc = deg[cols[e]];
    float ir = dr > 0.f ? rsqrtf(fmaxf(dr, 1e-12f)) : 0.f;
    float ic = dc > 0.f ? rsqrtf(fmaxf(dc, 1e-12f)) : 0.f;
    norm[e] = ir * w[e] * ic;
}

// ---------------- out[i] = bias[i % 64] (accumulator init, fuses bias add) ----------------
__global__ void init_bias_kernel(float* __restrict__ out, const float* __restrict__ b, int n) {
    int i = blockIdx.x * blockDim.x + threadIdx.x;
    if (i < n) out[i] = b[i & 63];
}

// ---------------- GEMM: out[M,64] = act(A[M,K]) @ W[K,64]  (N fixed = 64) ----------------
// Block = 256 threads = 4 waves; 64 rows per block; each thread: 1 col x 16 rows.
// W staged in LDS (<=32KB). A-row address is wave-uniform -> scalar loads.
template <int RELU_IN>
__global__ void gemm64_kernel(const float* __restrict__ A, const float* __restrict__ W,
                              float* __restrict__ out, int M, int K) {
    __shared__ float Wl[IN_DIM * 64];  // max K=128
    for (int i = threadIdx.x; i < K * 64; i += blockDim.x) Wl[i] = W[i];
    __syncthreads();

    const int col  = threadIdx.x & 63;
    const int rg   = threadIdx.x >> 6;        // 0..3 (wave id)
    const int row0 = blockIdx.x * 64 + rg * 16;

    float acc[16];
#pragma unroll
    for (int i = 0; i < 16; ++i) acc[i] = 0.f;

    if (row0 + 16 <= M) {  // fast path: full 16-row tile
        const float* ap = A + (size_t)row0 * K;
        for (int k = 0; k < K; ++k) {
            float wv = Wl[k * 64 + col];
#pragma unroll
            for (int i = 0; i < 16; ++i) {
                float a = ap[(size_t)i * K + k];
                if (RELU_IN) a = fmaxf(a, 0.f);
                acc[i] = fmaf(a, wv, acc[i]);
            }
        }
        float* op = out + (size_t)row0 * 64 + col;
#pragma unroll
        for (int i = 0; i < 16; ++i) op[(size_t)i * 64] = acc[i];
    } else {  // tail block
        for (int k = 0; k < K; ++k) {
            float wv = Wl[k * 64 + col];
            for (int i = 0; i < 16; ++i) {
                int r = row0 + i;
                if (r < M) {
                    float a = A[(size_t)r * K + k];
                    if (RELU_IN) a = fmaxf(a, 0.f);
                    acc[i] = fmaf(a, wv, acc[i]);
                }
            }
        }
        for (int i = 0; i < 16; ++i) {
            int r = row0 + i;
            if (r < M) out[(size_t)r * 64 + col] = acc[i];
        }
    }
}

// ---------------- scatter: out[col[e]][:] += h[row[e]][:] * norm[e] ----------------
// One wave (64 lanes) per edge; lane = channel. Contiguous coalesced atomics.
__global__ void scatter_kernel(const float* __restrict__ h, const int* __restrict__ rows,
                               const int* __restrict__ cols, const float* __restrict__ norm,
                               float* __restrict__ out, int E) {
    long long gid = (long long)blockIdx.x * blockDim.x + threadIdx.x;
    int e = (int)(gid >> 6);
    int lane = (int)(gid & 63);
    if (e >= E) return;
    int r = rows[e];
    int c = cols[e];
    float nv = norm[e];
    float v = h[(size_t)r * 64 + lane] * nv;
    atomicAdd(&out[(size_t)c * 64 + lane], v);
}

extern "C" void kernel_launch(void* const* d_in, const int* in_sizes, int n_in,
                              void* d_out, int out_size, void* d_ws, size_t ws_size,
                              hipStream_t stream) {
    const float* x  = (const float*)d_in[0];
    const int*   ei = (const int*)d_in[1];   // [2, E] int32 (JAX x64 disabled)
    const float* ew = (const float*)d_in[2];
    const float* W1 = (const float*)d_in[3];
    const float* b1 = (const float*)d_in[4];
    const float* W2 = (const float*)d_in[5];
    const float* b2 = (const float*)d_in[6];
    float* out = (float*)d_out;
    float* ws  = (float*)d_ws;

    const int* rows = ei;             // edge_index[0]
    const int* cols = ei + N_EDGES;   // edge_index[1]

    // workspace layout (floats)
    float* deg  = ws;                 // [100000]
    float* norm = ws + 100000;        // [1600000]
    float* bufA = ws + 1700000;       // [6400000]  h1 = x@W1, later h2
    float* bufB = ws + 8100000;       // [6400000]  conv1 accumulator (b1-init)

    const int TPB = 256;

    // 1) degrees + norm
    hipMemsetAsync(deg, 0, N_NODES * sizeof(float), stream);
    deg_kernel<<<(N_EDGES + TPB - 1) / TPB, TPB, 0, stream>>>(rows, ew, deg, N_EDGES);
    norm_kernel<<<(N_EDGES + TPB - 1) / TPB, TPB, 0, stream>>>(rows, cols, ew, deg, norm, N_EDGES);

    // 2) h1 = x @ W1  -> bufA
    gemm64_kernel<0><<<(N_NODES + 63) / 64, TPB, 0, stream>>>(x, W1, bufA, N_NODES, IN_DIM);

    // 3) conv1: bufB = b1 (broadcast), then scatter-add h1[row]*norm into bufB[col]
    init_bias_kernel<<<(N_NODES * 64 + TPB - 1) / TPB, TPB, 0, stream>>>(bufB, b1, N_NODES * 64);
    {
        long long total = (long long)N_EDGES * 64;
        int blocks = (int)((total + TPB - 1) / TPB);
        scatter_kernel<<<blocks, TPB, 0, stream>>>(bufA, rows, cols, norm, bufB, N_EDGES);
    }

    // 4) h2 = relu(bufB) @ W2 -> bufA (h1 dead now)
    gemm64_kernel<1><<<(N_NODES + 63) / 64, TPB, 0, stream>>>(bufB, W2, bufA, N_NODES, HID_DIM);

    // 5) conv2: out = b2 (broadcast), then scatter-add h2[row]*norm into out[col]
    init_bias_kernel<<<(N_NODES * 64 + TPB - 1) / TPB, TPB, 0, stream>>>(out, b2, N_NODES * 64);
    {
        long long total = (long long)N_EDGES * 64;
        int blocks = (int)((total + TPB - 1) / TPB);
        scatter_kernel<<<blocks, TPB, 0, stream>>>(bufA, rows, cols, norm, out, N_EDGES);
    }
}

// Round 2
// 607.391 us; speedup vs baseline: 1.7850x; 1.7850x over previous
//
#include <hip/hip_runtime.h>

#define N_NODES 100000
#define N_EDGES 1600000
#define IN_DIM 128
#define HID_DIM 64
#define OUT_DIM 64

// ============ phase 1: degree (weighted, by row) + histogram (by col) ============
__global__ void deg_hist_kernel(const int* __restrict__ rows, const int* __restrict__ cols,
                                const float* __restrict__ w,
                                float* __restrict__ deg, int* __restrict__ counts, int E) {
    int e = blockIdx.x * blockDim.x + threadIdx.x;
    if (e >= E) return;
    atomicAdd(&deg[rows[e]], w[e]);
    atomicAdd(&counts[cols[e]], 1);
}

// ============ phase 2: exclusive scan of counts[n] -> offsets[n+1] ============
// 2a: per-block (1024 elems) partial sums
__global__ void block_sum_kernel(const int* __restrict__ counts, int* __restrict__ partials, int n) {
    __shared__ int sh[256];
    int base = blockIdx.x * 1024;
    int s = 0;
    for (int i = threadIdx.x; i < 1024; i += 256) {
        int idx = base + i;
        s += (idx < n) ? counts[idx] : 0;
    }
    sh[threadIdx.x] = s;
    __syncthreads();
    for (int off = 128; off > 0; off >>= 1) {
        if (threadIdx.x < off) sh[threadIdx.x] += sh[threadIdx.x + off];
        __syncthreads();
    }
    if (threadIdx.x == 0) partials[blockIdx.x] = sh[0];
}

// 2b: exclusive scan of partials (nb <= 256), single block of 256
__global__ void scan_partials_kernel(int* __restrict__ p, int nb) {
    __shared__ int sh[256];
    int t = threadIdx.x;
    int v = (t < nb) ? p[t] : 0;
    sh[t] = v;
    __syncthreads();
    for (int off = 1; off < 256; off <<= 1) {
        int add = (t >= off) ? sh[t - off] : 0;
        __syncthreads();
        sh[t] += add;
        __syncthreads();
    }
    if (t < nb) p[t] = sh[t] - v;  // exclusive
}

// 2c: final exclusive scan; each block covers 1024 elems (256 thr x 4)
__global__ void scan_final_kernel(const int* __restrict__ counts, const int* __restrict__ partials,
                                  int* __restrict__ offsets, int n) {
    __shared__ int sh[256];
    int t = threadIdx.x;
    int idx0 = blockIdx.x * 1024 + t * 4;
    int v[4];
    int s = 0;
#pragma unroll
    for (int j = 0; j < 4; ++j) {
        int id = idx0 + j;
        v[j] = (id < n) ? counts[id] : 0;
        s += v[j];
    }
    sh[t] = s;
    __syncthreads();
    for (int off = 1; off < 256; off <<= 1) {
        int add = (t >= off) ? sh[t - off] : 0;
        __syncthreads();
        sh[t] += add;
        __syncthreads();
    }
    int run = sh[t] - s + partials[blockIdx.x];  // exclusive prefix for this thread
#pragma unroll
    for (int j = 0; j < 4; ++j) {
        int id = idx0 + j;
        if (id < n) offsets[id] = run;
        run += v[j];
    }
    // thread covering element n-1 writes the total
    if (idx0 <= n - 1 && n - 1 < idx0 + 4) offsets[n] = run;
}

// ============ phase 3: fill CSR (by destination col), norm computed inline ============
__global__ void fill_csr_kernel(const int* __restrict__ rows, const int* __restrict__ cols,
                                const float* __restrict__ w, const float* __restrict__ deg,
                                int* __restrict__ cursor, int* __restrict__ csr_row,
                                float* __restrict__ csr_norm, int E) {
    int e = blockIdx.x * blockDim.x + threadIdx.x;
    if (e >= E) return;
    int r = rows[e];
    int c = cols[e];
    int p = atomicAdd(&cursor[c], 1);
    float dr = deg[r];
    float dc = deg[c];
    float ir = dr > 0.f ? rsqrtf(fmaxf(dr, 1e-12f)) : 0.f;
    float ic = dc > 0.f ? rsqrtf(fmaxf(dc, 1e-12f)) : 0.f;
    csr_row[p] = r;
    csr_norm[p] = ir * w[e] * ic;
}

// ============ GEMM: out[M,64] = A[M,K] @ W[K,64] ============
// 256 thr = 4 waves; 64 rows/block; thread = 1 col x 16 rows; float4 k-loads.
__global__ void gemm64_kernel(const float* __restrict__ A, const float* __restrict__ W,
                              float* __restrict__ out, int M, int K) {
    __shared__ float Wl[IN_DIM * 64];  // max K=128
    for (int i = threadIdx.x; i < K * 64; i += blockDim.x) Wl[i] = W[i];
    __syncthreads();

    const int col  = threadIdx.x & 63;
    const int rg   = threadIdx.x >> 6;
    const int row0 = blockIdx.x * 64 + rg * 16;

    float acc[16];
#pragma unroll
    for (int i = 0; i < 16; ++i) acc[i] = 0.f;

    if (row0 + 16 <= M) {
        const float* ap = A + (size_t)row0 * K;
        for (int k = 0; k < K; k += 4) {
            float w0 = Wl[(k + 0) * 64 + col];
            float w1 = Wl[(k + 1) * 64 + col];
            float w2 = Wl[(k + 2) * 64 + col];
            float w3 = Wl[(k + 3) * 64 + col];
#pragma unroll
            for (int i = 0; i < 16; ++i) {
                const float4 a = *reinterpret_cast<const float4*>(&ap[(size_t)i * K + k]);
                acc[i] = fmaf(a.x, w0, acc[i]);
                acc[i] = fmaf(a.y, w1, acc[i]);
                acc[i] = fmaf(a.z, w2, acc[i]);
                acc[i] = fmaf(a.w, w3, acc[i]);
            }
        }
        float* op = out + (size_t)row0 * 64 + col;
#pragma unroll
        for (int i = 0; i < 16; ++i) op[(size_t)i * 64] = acc[i];
    } else {
        for (int k = 0; k < K; ++k) {
            float wv = Wl[k * 64 + col];
            for (int i = 0; i < 16; ++i) {
                int r = row0 + i;
                if (r < M) acc[i] = fmaf(A[(size_t)r * K + k], wv, acc[i]);
            }
        }
        for (int i = 0; i < 16; ++i) {
            int r = row0 + i;
            if (r < M) out[(size_t)r * 64 + col] = acc[i];
        }
    }
}

// ============ gather conv: out[c] = bias + sum_{j in [off[c],off[c+1])} h[row[j]] * norm[j] ============
// One wave per destination node; lane = channel. No atomics.
template <int RELU_OUT>
__global__ void gather_conv_kernel(const float* __restrict__ h, const int* __restrict__ csr_row,
                                   const float* __restrict__ csr_norm, const int* __restrict__ offsets,
                                   const float* __restrict__ bias, float* __restrict__ out, int n) {
    int node = blockIdx.x * (blockDim.x >> 6) + (threadIdx.x >> 6);
    int lane = threadIdx.x & 63;
    if (node >= n) return;
    int s = offsets[node];
    int e = offsets[node + 1];
    float a0 = bias[lane], a1 = 0.f, a2 = 0.f, a3 = 0.f;
    int j = s;
    for (; j + 4 <= e; j += 4) {
        int r0 = csr_row[j], r1 = csr_row[j + 1], r2 = csr_row[j + 2], r3 = csr_row[j + 3];
        float n0 = csr_norm[j], n1 = csr_norm[j + 1], n2 = csr_norm[j + 2], n3 = csr_norm[j + 3];
        a0 = fmaf(h[(size_t)r0 * 64 + lane], n0, a0);
        a1 = fmaf(h[(size_t)r1 * 64 + lane], n1, a1);
        a2 = fmaf(h[(size_t)r2 * 64 + lane], n2, a2);
        a3 = fmaf(h[(size_t)r3 * 64 + lane], n3, a3);
    }
    for (; j < e; ++j)
        a0 = fmaf(h[(size_t)csr_row[j] * 64 + lane], csr_norm[j], a0);
    float acc = (a0 + a1) + (a2 + a3);
    if (RELU_OUT) acc = fmaxf(acc, 0.f);
    out[(size_t)node * 64 + lane] = acc;
}

extern "C" void kernel_launch(void* const* d_in, const int* in_sizes, int n_in,
                              void* d_out, int out_size, void* d_ws, size_t ws_size,
                              hipStream_t stream) {
    const float* x  = (const float*)d_in[0];
    const int*   ei = (const int*)d_in[1];
    const float* ew = (const float*)d_in[2];
    const float* W1 = (const float*)d_in[3];
    const float* b1 = (const float*)d_in[4];
    const float* W2 = (const float*)d_in[5];
    const float* b2 = (const float*)d_in[6];
    float* out = (float*)d_out;
    char*  ws  = (char*)d_ws;

    const int* rows = ei;
    const int* cols = ei + N_EDGES;

    // workspace layout (4B units)
    float* deg      = (float*)(ws);                        // [100000]
    int*   counts   = (int*)(ws + 400000);                 // [100000]
    int*   offsets  = (int*)(ws + 800000);                 // [100001]
    int*   cursor   = (int*)(ws + 1200032);                // [100000]
    int*   partials = (int*)(ws + 1600032);                // [256]
    int*   csr_row  = (int*)(ws + 1601056);                // [1600000]
    float* csr_norm = (float*)(ws + 8001056);              // [1600000]
    float* bufA     = (float*)(ws + 14401056);             // [6400000]

    const int TPB = 256;
    const int nEB = (N_EDGES + TPB - 1) / TPB;
    const int nSB = (N_NODES + 1023) / 1024;               // 98 scan blocks

    // 1) zero deg + counts (contiguous), then degree + histogram
    hipMemsetAsync(deg, 0, 800000, stream);
    deg_hist_kernel<<<nEB, TPB, 0, stream>>>(rows, cols, ew, deg, counts, N_EDGES);

    // 2) exclusive scan counts -> offsets
    block_sum_kernel<<<nSB, 256, 0, stream>>>(counts, partials, N_NODES);
    scan_partials_kernel<<<1, 256, 0, stream>>>(partials, nSB);
    scan_final_kernel<<<nSB, 256, 0, stream>>>(counts, partials, offsets, N_NODES);

    // 3) fill CSR (cursor = copy of offsets)
    hipMemcpyAsync(cursor, offsets, N_NODES * sizeof(int), hipMemcpyDeviceToDevice, stream);
    fill_csr_kernel<<<nEB, TPB, 0, stream>>>(rows, cols, ew, deg, cursor, csr_row, csr_norm, N_EDGES);

    // 4) h1 = x @ W1 -> bufA
    gemm64_kernel<<<(N_NODES + 63) / 64, TPB, 0, stream>>>(x, W1, bufA, N_NODES, IN_DIM);

    // 5) conv1 (bias b1, fused relu): gather bufA -> out (used as scratch)
    gather_conv_kernel<1><<<(N_NODES + 3) / 4, TPB, 0, stream>>>(bufA, csr_row, csr_norm, offsets, b1, out, N_NODES);

    // 6) h2 = out @ W2 -> bufA
    gemm64_kernel<<<(N_NODES + 63) / 64, TPB, 0, stream>>>(out, W2, bufA, N_NODES, HID_DIM);

    // 7) conv2 (bias b2): gather bufA -> out
    gather_conv_kernel<0><<<(N_NODES + 3) / 4, TPB, 0, stream>>>(bufA, csr_row, csr_norm, offsets, b2, out, N_NODES);
}

// Round 3
// 557.881 us; speedup vs baseline: 1.9434x; 1.0887x over previous
//
#include <hip/hip_runtime.h>

#define N_NODES 100000
#define N_EDGES 1600000
#define IN_DIM 128
#define HID_DIM 64
#define OUT_DIM 64
#define NXCD 8
#define P_XCD 100096  // per-XCD slice stride (elements), 128B-aligned so no line sharing

// ---- read hardware XCC (XCD) id: 0..7 on MI355X [learn_hip m09] ----
__device__ __forceinline__ int xcc_id() {
    int x;
    asm volatile("s_getreg_b32 %0, hwreg(HW_REG_XCC_ID)" : "=s"(x));
    return x & (NXCD - 1);
}

// ============ pass1: per-XCD weighted degree + per-XCD histogram + edge rank ============
// Atomics are WORKGROUP scope -> performed in the local XCD L2 (no cross-XCD
// coherence needed: each XCD owns its private slice). rank[e] = (xcd<<24)|local_rank.
__global__ void pass1_kernel(const int* __restrict__ rows, const int* __restrict__ cols,
                             const float* __restrict__ w, float* __restrict__ pdeg,
                             unsigned* __restrict__ pcnt, unsigned* __restrict__ rank, int E) {
    const int x = xcc_id();
    float*    dslice = pdeg + (size_t)x * P_XCD;
    unsigned* cslice = pcnt + (size_t)x * P_XCD;
    const int tid = blockIdx.x * blockDim.x + threadIdx.x;
    const int T = gridDim.x * blockDim.x;
#pragma unroll
    for (int j = 0; j < 4; ++j) {
        int e = tid + j * T;
        if (e < E) {
            int r = rows[e], c = cols[e];
            __hip_atomic_fetch_add(&dslice[r], w[e], __ATOMIC_RELAXED, __HIP_MEMORY_SCOPE_WORKGROUP);
            unsigned lr = __hip_atomic_fetch_add(&cslice[c], 1u, __ATOMIC_RELAXED, __HIP_MEMORY_SCOPE_WORKGROUP);
            rank[e] = ((unsigned)x << 24) | lr;
        }
    }
}

// ============ reduce: deg_inv_sqrt + global counts from per-XCD slices ============
__global__ void reduce_kernel(const float* __restrict__ pdeg, const unsigned* __restrict__ pcnt,
                              float* __restrict__ dis, int* __restrict__ counts, int n) {
    int i = blockIdx.x * blockDim.x + threadIdx.x;
    if (i >= n) return;
    float d = 0.f;
    unsigned c = 0;
#pragma unroll
    for (int x = 0; x < NXCD; ++x) {
        d += pdeg[(size_t)x * P_XCD + i];
        c += pcnt[(size_t)x * P_XCD + i];
    }
    dis[i] = d > 0.f ? rsqrtf(fmaxf(d, 1e-12f)) : 0.f;
    counts[i] = (int)c;
}

// ============ exclusive scan of counts[n] -> offsets[n+1] (3 kernels) ============
__global__ void block_sum_kernel(const int* __restrict__ counts, int* __restrict__ partials, int n) {
    __shared__ int sh[256];
    int base = blockIdx.x * 1024;
    int s = 0;
    for (int i = threadIdx.x; i < 1024; i += 256) {
        int idx = base + i;
        s += (idx < n) ? counts[idx] : 0;
    }
    sh[threadIdx.x] = s;
    __syncthreads();
    for (int off = 128; off > 0; off >>= 1) {
        if (threadIdx.x < off) sh[threadIdx.x] += sh[threadIdx.x + off];
        __syncthreads();
    }
    if (threadIdx.x == 0) partials[blockIdx.x] = sh[0];
}

__global__ void scan_partials_kernel(int* __restrict__ p, int nb) {
    __shared__ int sh[256];
    int t = threadIdx.x;
    int v = (t < nb) ? p[t] : 0;
    sh[t] = v;
    __syncthreads();
    for (int off = 1; off < 256; off <<= 1) {
        int add = (t >= off) ? sh[t - off] : 0;
        __syncthreads();
        sh[t] += add;
        __syncthreads();
    }
    if (t < nb) p[t] = sh[t] - v;  // exclusive
}

__global__ void scan_final_kernel(const int* __restrict__ counts, const int* __restrict__ partials,
                                  int* __restrict__ offsets, int n) {
    __shared__ int sh[256];
    int t = threadIdx.x;
    int idx0 = blockIdx.x * 1024 + t * 4;
    int v[4];
    int s = 0;
#pragma unroll
    for (int j = 0; j < 4; ++j) {
        int id = idx0 + j;
        v[j] = (id < n) ? counts[id] : 0;
        s += v[j];
    }
    sh[t] = s;
    __syncthreads();
    for (int off = 1; off < 256; off <<= 1) {
        int add = (t >= off) ? sh[t - off] : 0;
        __syncthreads();
        sh[t] += add;
        __syncthreads();
    }
    int run = sh[t] - s + partials[blockIdx.x];
#pragma unroll
    for (int j = 0; j < 4; ++j) {
        int id = idx0 + j;
        if (id < n) offsets[id] = run;
        run += v[j];
    }
    if (idx0 <= n - 1 && n - 1 < idx0 + 4) offsets[n] = run;
}

// ============ off2[i*8+x] = offsets[i] + prefix_x(pcnt[x][i]) ============
__global__ void off2_kernel(const int* __restrict__ offsets, const unsigned* __restrict__ pcnt,
                            unsigned* __restrict__ off2, int n) {
    int i = blockIdx.x * blockDim.x + threadIdx.x;
    if (i >= n) return;
    unsigned run = (unsigned)offsets[i];
#pragma unroll
    for (int x = 0; x < NXCD; ++x) {
        off2[(size_t)i * NXCD + x] = run;
        run += pcnt[(size_t)x * P_XCD + i];
    }
}

// ============ fill CSR, atomic-free: position from off2 + stored rank ============
__global__ void fill_kernel(const int* __restrict__ rows, const int* __restrict__ cols,
                            const float* __restrict__ w, const float* __restrict__ dis,
                            const unsigned* __restrict__ rank, const unsigned* __restrict__ off2,
                            int* __restrict__ csr_row, float* __restrict__ csr_norm, int E) {
    int e = blockIdx.x * blockDim.x + threadIdx.x;
    if (e >= E) return;
    int r = rows[e], c = cols[e];
    unsigned rk = rank[e];
    unsigned p = off2[(size_t)c * NXCD + (rk >> 24)] + (rk & 0xFFFFFFu);
    csr_row[p] = r;
    csr_norm[p] = dis[r] * w[e] * dis[c];
}

// ============ GEMM: out[M,64] = A[M,K] @ W[K,64] ============
__global__ void gemm64_kernel(const float* __restrict__ A, const float* __restrict__ W,
                              float* __restrict__ out, int M, int K) {
    __shared__ float Wl[IN_DIM * 64];
    for (int i = threadIdx.x; i < K * 64; i += blockDim.x) Wl[i] = W[i];
    __syncthreads();

    const int col  = threadIdx.x & 63;
    const int rg   = threadIdx.x >> 6;
    const int row0 = blockIdx.x * 64 + rg * 16;

    float acc[16];
#pragma unroll
    for (int i = 0; i < 16; ++i) acc[i] = 0.f;

    if (row0 + 16 <= M) {
        const float* ap = A + (size_t)row0 * K;
        for (int k = 0; k < K; k += 4) {
            float w0 = Wl[(k + 0) * 64 + col];
            float w1 = Wl[(k + 1) * 64 + col];
            float w2 = Wl[(k + 2) * 64 + col];
            float w3 = Wl[(k + 3) * 64 + col];
#pragma unroll
            for (int i = 0; i < 16; ++i) {
                const float4 a = *reinterpret_cast<const float4*>(&ap[(size_t)i * K + k]);
                acc[i] = fmaf(a.x, w0, acc[i]);
                acc[i] = fmaf(a.y, w1, acc[i]);
                acc[i] = fmaf(a.z, w2, acc[i]);
                acc[i] = fmaf(a.w, w3, acc[i]);
            }
        }
        float* op = out + (size_t)row0 * 64 + col;
#pragma unroll
        for (int i = 0; i < 16; ++i) op[(size_t)i * 64] = acc[i];
    } else {
        for (int k = 0; k < K; ++k) {
            float wv = Wl[k * 64 + col];
            for (int i = 0; i < 16; ++i) {
                int r = row0 + i;
                if (r < M) acc[i] = fmaf(A[(size_t)r * K + k], wv, acc[i]);
            }
        }
        for (int i = 0; i < 16; ++i) {
            int r = row0 + i;
            if (r < M) out[(size_t)r * 64 + col] = acc[i];
        }
    }
}

// ============ gather conv: one wave per destination node ============
template <int RELU_OUT>
__global__ void gather_conv_kernel(const float* __restrict__ h, const int* __restrict__ csr_row,
                                   const float* __restrict__ csr_norm, const int* __restrict__ offsets,
                                   const float* __restrict__ bias, float* __restrict__ out, int n) {
    int node = blockIdx.x * (blockDim.x >> 6) + (threadIdx.x >> 6);
    int lane = threadIdx.x & 63;
    if (node >= n) return;
    int s = offsets[node];
    int e = offsets[node + 1];
    float a0 = bias[lane], a1 = 0.f, a2 = 0.f, a3 = 0.f;
    int j = s;
    for (; j + 4 <= e; j += 4) {
        int r0 = csr_row[j], r1 = csr_row[j + 1], r2 = csr_row[j + 2], r3 = csr_row[j + 3];
        float n0 = csr_norm[j], n1 = csr_norm[j + 1], n2 = csr_norm[j + 2], n3 = csr_norm[j + 3];
        a0 = fmaf(h[(size_t)r0 * 64 + lane], n0, a0);
        a1 = fmaf(h[(size_t)r1 * 64 + lane], n1, a1);
        a2 = fmaf(h[(size_t)r2 * 64 + lane], n2, a2);
        a3 = fmaf(h[(size_t)r3 * 64 + lane], n3, a3);
    }
    for (; j < e; ++j)
        a0 = fmaf(h[(size_t)csr_row[j] * 64 + lane], csr_norm[j], a0);
    float acc = (a0 + a1) + (a2 + a3);
    if (RELU_OUT) acc = fmaxf(acc, 0.f);
    out[(size_t)node * 64 + lane] = acc;
}

extern "C" void kernel_launch(void* const* d_in, const int* in_sizes, int n_in,
                              void* d_out, int out_size, void* d_ws, size_t ws_size,
                              hipStream_t stream) {
    const float* x  = (const float*)d_in[0];
    const int*   ei = (const int*)d_in[1];
    const float* ew = (const float*)d_in[2];
    const float* W1 = (const float*)d_in[3];
    const float* b1 = (const float*)d_in[4];
    const float* W2 = (const float*)d_in[5];
    const float* b2 = (const float*)d_in[6];
    float* out = (float*)d_out;
    char*  ws  = (char*)d_ws;

    const int* rows = ei;
    const int* cols = ei + N_EDGES;

    // ---- workspace layout (byte offsets; early arrays alias not-yet-live regions) ----
    // persistent through gathers:
    int*      csr_row  = (int*)(ws + 0);                   // 6,400,000
    float*    csr_norm = (float*)(ws + 6400000);           // 6,400,000
    float*    bufA     = (float*)(ws + 12800000);          // 25,600,000 (h1 / h2)
    // early phase (dead before their aliasing writers run):
    float*    pdeg     = (float*)(ws + 0);                 // 3,203,072  [dies at fill]
    unsigned* pcnt     = (unsigned*)(ws + 3203072);        // 3,203,072  [dies at fill]
    int*      counts   = (int*)(ws + 6406144);             // 400,000    [dies at fill]
    int*      offsets  = (int*)(ws + 6806144);             // 400,004    [NOTE: gathers need offsets!]
    int*      partials = (int*)(ws + 7206148);             // 1,024      [dies at fill]
    unsigned* rank     = (unsigned*)(ws + 12800000);       // 6,400,000  [bufA alias; dies at gemm1]
    unsigned* off2     = (unsigned*)(ws + 19200000);       // 3,200,000  [bufA alias; dies at gemm1]
    float*    dis      = (float*)(ws + 22400000);          // 400,000    [bufA alias; dies at gemm1]
    // offsets is read by the gather kernels AFTER fill overwrote ws[6.8MB..7.2MB]!
    // -> keep a persistent copy of offsets outside the csr region:
    int*      offsets2 = (int*)(ws + 38400000);            // 400,004 persistent copy

    const int TPB = 256;
    const int nEB = (N_EDGES + TPB - 1) / TPB;             // 6250
    const int nNB = (N_NODES + TPB - 1) / TPB;             // 391
    const int nSB = (N_NODES + 1023) / 1024;               // 98

    // 1) zero per-XCD slices, then pass1 (deg + hist + rank), L2-local atomics
    hipMemsetAsync(ws, 0, 6406144, stream);
    pass1_kernel<<<(N_EDGES + TPB * 4 - 1) / (TPB * 4), TPB, 0, stream>>>(
        rows, cols, ew, pdeg, pcnt, rank, N_EDGES);

    // 2) reduce slices -> dis + counts; scan counts -> offsets
    reduce_kernel<<<nNB, TPB, 0, stream>>>(pdeg, pcnt, dis, counts, N_NODES);
    block_sum_kernel<<<nSB, 256, 0, stream>>>(counts, partials, N_NODES);
    scan_partials_kernel<<<1, 256, 0, stream>>>(partials, nSB);
    scan_final_kernel<<<nSB, 256, 0, stream>>>(counts, partials, offsets, N_NODES);
    hipMemcpyAsync(offsets2, offsets, (N_NODES + 1) * sizeof(int),
                   hipMemcpyDeviceToDevice, stream);

    // 3) per-(node,xcd) offsets, then atomic-free CSR fill (norm fused)
    off2_kernel<<<nNB, TPB, 0, stream>>>(offsets, pcnt, off2, N_NODES);
    fill_kernel<<<nEB, TPB, 0, stream>>>(rows, cols, ew, dis, rank, off2,
                                         csr_row, csr_norm, N_EDGES);

    // 4) h1 = x @ W1 -> bufA (kills rank/off2/dis)
    gemm64_kernel<<<(N_NODES + 63) / 64, TPB, 0, stream>>>(x, W1, bufA, N_NODES, IN_DIM);

    // 5) conv1 (+bias b1, fused relu): gather bufA -> out
    gather_conv_kernel<1><<<(N_NODES + 3) / 4, TPB, 0, stream>>>(
        bufA, csr_row, csr_norm, offsets2, b1, out, N_NODES);

    // 6) h2 = out @ W2 -> bufA
    gemm64_kernel<<<(N_NODES + 63) / 64, TPB, 0, stream>>>(out, W2, bufA, N_NODES, HID_DIM);

    // 7) conv2 (+bias b2): gather bufA -> out
    gather_conv_kernel<0><<<(N_NODES + 3) / 4, TPB, 0, stream>>>(
        bufA, csr_row, csr_norm, offsets2, b2, out, N_NODES);
}

// Round 4
// 415.362 us; speedup vs baseline: 2.6103x; 1.3431x over previous
//
#include <hip/hip_runtime.h>

#define N_NODES 100000
#define N_EDGES 1600000
#define IN_DIM 128
#define HID_DIM 64
#define OUT_DIM 64
#define NB 391      // node buckets of 256: ceil(100000/256)
#define NBLK 512    // edge-chunk blocks
#define CHUNK 3125  // 512*3125 = 1,600,000

// ============ count: per-block LDS histograms by col-bucket and row-bucket ============
__global__ void count_kernel(const int* __restrict__ rows, const int* __restrict__ cols,
                             int* __restrict__ MC, int* __restrict__ MR) {
    __shared__ unsigned hc[NB], hr[NB];
    for (int i = threadIdx.x; i < NB; i += 256) { hc[i] = 0; hr[i] = 0; }
    __syncthreads();
    const int s = blockIdx.x * CHUNK;
    const int e = min(s + CHUNK, N_EDGES);
    for (int i = s + threadIdx.x; i < e; i += 256) {
        atomicAdd(&hr[rows[i] >> 8], 1u);
        atomicAdd(&hc[cols[i] >> 8], 1u);
    }
    __syncthreads();
    for (int i = threadIdx.x; i < NB; i += 256) {
        MC[i * NBLK + blockIdx.x] = (int)hc[i];
        MR[i * NBLK + blockIdx.x] = (int)hr[i];
    }
}

// ============ exclusive scan (3 kernels), n up to 256*1024 ============
__global__ void block_sum_kernel(const int* __restrict__ counts, int* __restrict__ partials, int n) {
    __shared__ int sh[256];
    int base = blockIdx.x * 1024;
    int s = 0;
    for (int i = threadIdx.x; i < 1024; i += 256) {
        int idx = base + i;
        s += (idx < n) ? counts[idx] : 0;
    }
    sh[threadIdx.x] = s;
    __syncthreads();
    for (int off = 128; off > 0; off >>= 1) {
        if (threadIdx.x < off) sh[threadIdx.x] += sh[threadIdx.x + off];
        __syncthreads();
    }
    if (threadIdx.x == 0) partials[blockIdx.x] = sh[0];
}

__global__ void scan_partials_kernel(int* __restrict__ p, int nb) {
    __shared__ int sh[256];
    int t = threadIdx.x;
    int v = (t < nb) ? p[t] : 0;
    sh[t] = v;
    __syncthreads();
    for (int off = 1; off < 256; off <<= 1) {
        int add = (t >= off) ? sh[t - off] : 0;
        __syncthreads();
        sh[t] += add;
        __syncthreads();
    }
    if (t < nb) p[t] = sh[t] - v;  // exclusive
}

__global__ void scan_final_kernel(const int* __restrict__ counts, const int* __restrict__ partials,
                                  int* __restrict__ offsets, int n) {
    __shared__ int sh[256];
    int t = threadIdx.x;
    int idx0 = blockIdx.x * 1024 + t * 4;
    int v[4];
    int s = 0;
#pragma unroll
    for (int j = 0; j < 4; ++j) {
        int id = idx0 + j;
        v[j] = (id < n) ? counts[id] : 0;
        s += v[j];
    }
    sh[t] = s;
    __syncthreads();
    for (int off = 1; off < 256; off <<= 1) {
        int add = (t >= off) ? sh[t - off] : 0;
        __syncthreads();
        sh[t] += add;
        __syncthreads();
    }
    int run = sh[t] - s + partials[blockIdx.x];
#pragma unroll
    for (int j = 0; j < 4; ++j) {
        int id = idx0 + j;
        if (id < n) offsets[id] = run;
        run += v[j];
    }
    if (idx0 <= n - 1 && n - 1 < idx0 + 4) offsets[n] = run;
}

// ============ scatter: bin edges by col-bucket (pkA) and row-bucket (pkR), no global atomics ============
__global__ void scatter_kernel(const int* __restrict__ rows, const int* __restrict__ cols,
                               const float* __restrict__ w, const int* __restrict__ MCs,
                               const int* __restrict__ MRs,
                               unsigned long long* __restrict__ pkA,
                               unsigned long long* __restrict__ pkR) {
    __shared__ unsigned curC[NB], curR[NB];
    for (int i = threadIdx.x; i < NB; i += 256) {
        curC[i] = (unsigned)MCs[i * NBLK + blockIdx.x];
        curR[i] = (unsigned)MRs[i * NBLK + blockIdx.x];
    }
    __syncthreads();
    const int s = blockIdx.x * CHUNK;
    const int e = min(s + CHUNK, N_EDGES);
    for (int i = s + threadIdx.x; i < e; i += 256) {
        int r = rows[i], c = cols[i];
        unsigned wb = __float_as_uint(w[i]);
        unsigned pA = atomicAdd(&curC[c >> 8], 1u);  // LDS
        pkA[pA] = ((unsigned long long)wb << 32) | (unsigned)(((c & 255) << 17) | r);
        unsigned pR = atomicAdd(&curR[r >> 8], 1u);  // LDS
        pkR[pR] = ((unsigned long long)wb << 32) | (unsigned)(r & 255);
    }
}

// ============ deg reduce: block per row-bucket, LDS accumulation -> dis ============
__global__ void deg_reduce_kernel(const unsigned long long* __restrict__ pkR,
                                  const int* __restrict__ MRs, float* __restrict__ dis) {
    __shared__ float acc[256];
    const int b = blockIdx.x;
    acc[threadIdx.x] = 0.f;
    __syncthreads();
    const int s = MRs[b * NBLK];
    const int e = MRs[(b + 1) * NBLK];  // MRs[NB*NBLK] == N_EDGES
    for (int i = s + threadIdx.x; i < e; i += 256) {
        unsigned long long p = pkR[i];
        atomicAdd(&acc[(unsigned)p & 255u], __uint_as_float((unsigned)(p >> 32)));  // LDS
    }
    __syncthreads();
    int node = b * 256 + threadIdx.x;
    if (node < N_NODES) {
        float d = acc[threadIdx.x];
        dis[node] = d > 0.f ? rsqrtf(fmaxf(d, 1e-12f)) : 0.f;
    }
}

// ============ fill: block per col-bucket; LDS count+scan -> offsets + CSR (norm fused) ============
__global__ void fill_kernel(const unsigned long long* __restrict__ pkA,
                            const int* __restrict__ MCs, const float* __restrict__ dis,
                            int* __restrict__ csr_row, float* __restrict__ csr_norm,
                            int* __restrict__ offsets) {
    __shared__ unsigned hist[256];
    __shared__ unsigned excl[256];
    const int b = blockIdx.x;
    const int t = threadIdx.x;
    hist[t] = 0;
    __syncthreads();
    const int s = MCs[b * NBLK];
    const int e = MCs[(b + 1) * NBLK];
    for (int i = s + t; i < e; i += 256) {
        unsigned lo = (unsigned)pkA[i];
        atomicAdd(&hist[(lo >> 17) & 255u], 1u);  // LDS
    }
    __syncthreads();
    // inclusive scan -> exclusive
    unsigned v = hist[t];
    excl[t] = v;
    __syncthreads();
    for (int off = 1; off < 256; off <<= 1) {
        unsigned add = (t >= off) ? excl[t - off] : 0;
        __syncthreads();
        excl[t] += add;
        __syncthreads();
    }
    unsigned my = excl[t] - v + (unsigned)s;  // global exclusive offset for node b*256+t
    int node = b * 256 + t;
    if (node <= N_NODES) offsets[node] = (int)my;  // node==N_NODES lands here too (== E)
    hist[t] = my;  // reuse as cursor
    __syncthreads();
    for (int i = s + t; i < e; i += 256) {
        unsigned long long p = pkA[i];
        unsigned lo = (unsigned)p;
        unsigned cl = (lo >> 17) & 255u;
        int r = (int)(lo & 0x1FFFFu);
        unsigned pos = atomicAdd(&hist[cl], 1u);  // LDS
        csr_row[pos] = r;
        int c = (b << 8) + (int)cl;
        csr_norm[pos] = dis[r] * __uint_as_float((unsigned)(p >> 32)) * dis[c];
    }
}

// ============ GEMM: out[M,64] = A[M,K] @ W[K,64] ============
__global__ void gemm64_kernel(const float* __restrict__ A, const float* __restrict__ W,
                              float* __restrict__ out, int M, int K) {
    __shared__ float Wl[IN_DIM * 64];
    for (int i = threadIdx.x; i < K * 64; i += blockDim.x) Wl[i] = W[i];
    __syncthreads();

    const int col  = threadIdx.x & 63;
    const int rg   = threadIdx.x >> 6;
    const int row0 = blockIdx.x * 64 + rg * 16;

    float acc[16];
#pragma unroll
    for (int i = 0; i < 16; ++i) acc[i] = 0.f;

    if (row0 + 16 <= M) {
        const float* ap = A + (size_t)row0 * K;
        for (int k = 0; k < K; k += 4) {
            float w0 = Wl[(k + 0) * 64 + col];
            float w1 = Wl[(k + 1) * 64 + col];
            float w2 = Wl[(k + 2) * 64 + col];
            float w3 = Wl[(k + 3) * 64 + col];
#pragma unroll
            for (int i = 0; i < 16; ++i) {
                const float4 a = *reinterpret_cast<const float4*>(&ap[(size_t)i * K + k]);
                acc[i] = fmaf(a.x, w0, acc[i]);
                acc[i] = fmaf(a.y, w1, acc[i]);
                acc[i] = fmaf(a.z, w2, acc[i]);
                acc[i] = fmaf(a.w, w3, acc[i]);
            }
        }
        float* op = out + (size_t)row0 * 64 + col;
#pragma unroll
        for (int i = 0; i < 16; ++i) op[(size_t)i * 64] = acc[i];
    } else {
        for (int k = 0; k < K; ++k) {
            float wv = Wl[k * 64 + col];
            for (int i = 0; i < 16; ++i) {
                int r = row0 + i;
                if (r < M) acc[i] = fmaf(A[(size_t)r * K + k], wv, acc[i]);
            }
        }
        for (int i = 0; i < 16; ++i) {
            int r = row0 + i;
            if (r < M) out[(size_t)r * 64 + col] = acc[i];
        }
    }
}

// ============ gather conv: one wave per destination node ============
template <int RELU_OUT>
__global__ void gather_conv_kernel(const float* __restrict__ h, const int* __restrict__ csr_row,
                                   const float* __restrict__ csr_norm, const int* __restrict__ offsets,
                                   const float* __restrict__ bias, float* __restrict__ out, int n) {
    int node = blockIdx.x * (blockDim.x >> 6) + (threadIdx.x >> 6);
    int lane = threadIdx.x & 63;
    if (node >= n) return;
    int s = offsets[node];
    int e = offsets[node + 1];
    float a0 = bias[lane], a1 = 0.f, a2 = 0.f, a3 = 0.f;
    int j = s;
    for (; j + 4 <= e; j += 4) {
        int r0 = csr_row[j], r1 = csr_row[j + 1], r2 = csr_row[j + 2], r3 = csr_row[j + 3];
        float n0 = csr_norm[j], n1 = csr_norm[j + 1], n2 = csr_norm[j + 2], n3 = csr_norm[j + 3];
        a0 = fmaf(h[(size_t)r0 * 64 + lane], n0, a0);
        a1 = fmaf(h[(size_t)r1 * 64 + lane], n1, a1);
        a2 = fmaf(h[(size_t)r2 * 64 + lane], n2, a2);
        a3 = fmaf(h[(size_t)r3 * 64 + lane], n3, a3);
    }
    for (; j < e; ++j)
        a0 = fmaf(h[(size_t)csr_row[j] * 64 + lane], csr_norm[j], a0);
    float acc = (a0 + a1) + (a2 + a3);
    if (RELU_OUT) acc = fmaxf(acc, 0.f);
    out[(size_t)node * 64 + lane] = acc;
}

extern "C" void kernel_launch(void* const* d_in, const int* in_sizes, int n_in,
                              void* d_out, int out_size, void* d_ws, size_t ws_size,
                              hipStream_t stream) {
    const float* x  = (const float*)d_in[0];
    const int*   ei = (const int*)d_in[1];
    const float* ew = (const float*)d_in[2];
    const float* W1 = (const float*)d_in[3];
    const float* b1 = (const float*)d_in[4];
    const float* W2 = (const float*)d_in[5];
    const float* b2 = (const float*)d_in[6];
    float* out = (float*)d_out;
    char*  ws  = (char*)d_ws;

    const int* rows = ei;
    const int* cols = ei + N_EDGES;

    // ---- workspace (byte offsets) ----
    int*      csr_row  = (int*)(ws + 0);                       // 6,400,000
    float*    csr_norm = (float*)(ws + 6400000);               // 6,400,000
    float*    bufA     = (float*)(ws + 12800000);              // 25,600,000 (aliases pkA+pkR)
    unsigned long long* pkA = (unsigned long long*)(ws + 12800000);  // 12,800,000 [dies at fill]
    unsigned long long* pkR = (unsigned long long*)(ws + 25600000);  // 12,800,000 [dies at deg_reduce]
    int*      MC       = (int*)(ws + 38400000);                // 800,768
    int*      MCs      = (int*)(ws + 39250000);                // 800,772
    int*      MR       = (int*)(ws + 40100000);                // 800,768
    int*      MRs      = (int*)(ws + 40950000);                // 800,772
    int*      partials = (int*)(ws + 41800000);                // 1,024
    int*      offsets  = (int*)(ws + 41810000);                // 400,004
    float*    dis      = (float*)(ws + 42220000);              // 400,000

    const int TPB = 256;
    const int n2  = NB * NBLK;                   // 200,192 matrix elements
    const int nSB2 = (n2 + 1023) / 1024;         // 196 scan blocks

    // 1) per-block bucket histograms (by col and by row) — LDS atomics only
    count_kernel<<<NBLK, TPB, 0, stream>>>(rows, cols, MC, MR);

    // 2) scan both matrices -> per-(bucket,block) bases
    block_sum_kernel<<<nSB2, 256, 0, stream>>>(MC, partials, n2);
    scan_partials_kernel<<<1, 256, 0, stream>>>(partials, nSB2);
    scan_final_kernel<<<nSB2, 256, 0, stream>>>(MC, partials, MCs, n2);
    block_sum_kernel<<<nSB2, 256, 0, stream>>>(MR, partials, n2);
    scan_partials_kernel<<<1, 256, 0, stream>>>(partials, nSB2);
    scan_final_kernel<<<nSB2, 256, 0, stream>>>(MR, partials, MRs, n2);

    // 3) bin edges into col-bucket payloads (pkA) and row-bucket payloads (pkR)
    scatter_kernel<<<NBLK, TPB, 0, stream>>>(rows, cols, ew, MCs, MRs, pkA, pkR);

    // 4) deg -> dis (block per row-bucket, LDS accumulate)
    deg_reduce_kernel<<<NB, TPB, 0, stream>>>(pkR, MRs, dis);

    // 5) per-node offsets + CSR fill with fused norm (block per col-bucket)
    fill_kernel<<<NB, TPB, 0, stream>>>(pkA, MCs, dis, csr_row, csr_norm, offsets);

    // 6) h1 = x @ W1 -> bufA (kills pkA/pkR)
    gemm64_kernel<<<(N_NODES + 63) / 64, TPB, 0, stream>>>(x, W1, bufA, N_NODES, IN_DIM);

    // 7) conv1 (+b1, fused relu): gather bufA -> out
    gather_conv_kernel<1><<<(N_NODES + 3) / 4, TPB, 0, stream>>>(
        bufA, csr_row, csr_norm, offsets, b1, out, N_NODES);

    // 8) h2 = out @ W2 -> bufA
    gemm64_kernel<<<(N_NODES + 63) / 64, TPB, 0, stream>>>(out, W2, bufA, N_NODES, HID_DIM);

    // 9) conv2 (+b2): gather bufA -> out
    gather_conv_kernel<0><<<(N_NODES + 3) / 4, TPB, 0, stream>>>(
        bufA, csr_row, csr_norm, offsets, b2, out, N_NODES);
}

// Round 5
// 409.930 us; speedup vs baseline: 2.6449x; 1.0133x over previous
//
#include <hip/hip_runtime.h>

#define N_NODES 100000
#define N_EDGES 1600000
#define IN_DIM 128
#define HID_DIM 64
#define OUT_DIM 64
#define NB 391      // node buckets of 256: ceil(100000/256)
#define NBLK 512    // edge-chunk blocks
#define CHUNK 3125  // 512*3125 = 1,600,000

// ============ count: per-block LDS histograms by col-bucket and row-bucket ============
__global__ void count_kernel(const int* __restrict__ rows, const int* __restrict__ cols,
                             int* __restrict__ MC, int* __restrict__ MR) {
    __shared__ unsigned hc[NB], hr[NB];
    for (int i = threadIdx.x; i < NB; i += 256) { hc[i] = 0; hr[i] = 0; }
    __syncthreads();
    const int s = blockIdx.x * CHUNK;
    const int e = min(s + CHUNK, N_EDGES);
    for (int i = s + threadIdx.x; i < e; i += 256) {
        atomicAdd(&hr[rows[i] >> 8], 1u);
        atomicAdd(&hc[cols[i] >> 8], 1u);
    }
    __syncthreads();
    for (int i = threadIdx.x; i < NB; i += 256) {
        MC[i * NBLK + blockIdx.x] = (int)hc[i];
        MR[i * NBLK + blockIdx.x] = (int)hr[i];
    }
}

// ============ exclusive scan (3 kernels) ============
__global__ void block_sum_kernel(const int* __restrict__ counts, int* __restrict__ partials, int n) {
    __shared__ int sh[256];
    int base = blockIdx.x * 1024;
    int s = 0;
    for (int i = threadIdx.x; i < 1024; i += 256) {
        int idx = base + i;
        s += (idx < n) ? counts[idx] : 0;
    }
    sh[threadIdx.x] = s;
    __syncthreads();
    for (int off = 128; off > 0; off >>= 1) {
        if (threadIdx.x < off) sh[threadIdx.x] += sh[threadIdx.x + off];
        __syncthreads();
    }
    if (threadIdx.x == 0) partials[blockIdx.x] = sh[0];
}

__global__ void scan_partials_kernel(int* __restrict__ p, int nb) {
    __shared__ int sh[256];
    int t = threadIdx.x;
    int v = (t < nb) ? p[t] : 0;
    sh[t] = v;
    __syncthreads();
    for (int off = 1; off < 256; off <<= 1) {
        int add = (t >= off) ? sh[t - off] : 0;
        __syncthreads();
        sh[t] += add;
        __syncthreads();
    }
    if (t < nb) p[t] = sh[t] - v;  // exclusive
}

__global__ void scan_final_kernel(const int* __restrict__ counts, const int* __restrict__ partials,
                                  int* __restrict__ offsets, int n) {
    __shared__ int sh[256];
    int t = threadIdx.x;
    int idx0 = blockIdx.x * 1024 + t * 4;
    int v[4];
    int s = 0;
#pragma unroll
    for (int j = 0; j < 4; ++j) {
        int id = idx0 + j;
        v[j] = (id < n) ? counts[id] : 0;
        s += v[j];
    }
    sh[t] = s;
    __syncthreads();
    for (int off = 1; off < 256; off <<= 1) {
        int add = (t >= off) ? sh[t - off] : 0;
        __syncthreads();
        sh[t] += add;
        __syncthreads();
    }
    int run = sh[t] - s + partials[blockIdx.x];
#pragma unroll
    for (int j = 0; j < 4; ++j) {
        int id = idx0 + j;
        if (id < n) offsets[id] = run;
        run += v[j];
    }
    if (idx0 <= n - 1 && n - 1 < idx0 + 4) offsets[n] = run;
}

// ============ scatter: bin edges by col-bucket (pkA) and row-bucket (pkR) ============
__global__ void scatter_kernel(const int* __restrict__ rows, const int* __restrict__ cols,
                               const float* __restrict__ w, const int* __restrict__ MCs,
                               const int* __restrict__ MRs,
                               unsigned long long* __restrict__ pkA,
                               unsigned long long* __restrict__ pkR) {
    __shared__ unsigned curC[NB], curR[NB];
    for (int i = threadIdx.x; i < NB; i += 256) {
        curC[i] = (unsigned)MCs[i * NBLK + blockIdx.x];
        curR[i] = (unsigned)MRs[i * NBLK + blockIdx.x];
    }
    __syncthreads();
    const int s = blockIdx.x * CHUNK;
    const int e = min(s + CHUNK, N_EDGES);
    for (int i = s + threadIdx.x; i < e; i += 256) {
        int r = rows[i], c = cols[i];
        unsigned wb = __float_as_uint(w[i]);
        unsigned pA = atomicAdd(&curC[c >> 8], 1u);  // LDS
        pkA[pA] = ((unsigned long long)wb << 32) | (unsigned)(((c & 255) << 17) | r);
        unsigned pR = atomicAdd(&curR[r >> 8], 1u);  // LDS
        pkR[pR] = ((unsigned long long)wb << 32) | (unsigned)(r & 255);
    }
}

// ============ deg reduce: block per row-bucket, LDS accumulation -> dis ============
__global__ void deg_reduce_kernel(const unsigned long long* __restrict__ pkR,
                                  const int* __restrict__ MRs, float* __restrict__ dis) {
    __shared__ float acc[256];
    const int b = blockIdx.x;
    acc[threadIdx.x] = 0.f;
    __syncthreads();
    const int s = MRs[b * NBLK];
    const int e = MRs[(b + 1) * NBLK];
    for (int i = s + threadIdx.x; i < e; i += 256) {
        unsigned long long p = pkR[i];
        atomicAdd(&acc[(unsigned)p & 255u], __uint_as_float((unsigned)(p >> 32)));  // LDS
    }
    __syncthreads();
    int node = b * 256 + threadIdx.x;
    if (node < N_NODES) {
        float d = acc[threadIdx.x];
        dis[node] = d > 0.f ? rsqrtf(fmaxf(d, 1e-12f)) : 0.f;
    }
}

// ============ fill: block per col-bucket; LDS count+scan -> offsets + CSR ============
__global__ void fill_kernel(const unsigned long long* __restrict__ pkA,
                            const int* __restrict__ MCs, const float* __restrict__ dis,
                            int* __restrict__ csr_row, float* __restrict__ csr_norm,
                            int* __restrict__ offsets) {
    __shared__ unsigned hist[256];
    __shared__ unsigned excl[256];
    const int b = blockIdx.x;
    const int t = threadIdx.x;
    hist[t] = 0;
    __syncthreads();
    const int s = MCs[b * NBLK];
    const int e = MCs[(b + 1) * NBLK];
    for (int i = s + t; i < e; i += 256) {
        unsigned lo = (unsigned)pkA[i];
        atomicAdd(&hist[(lo >> 17) & 255u], 1u);  // LDS
    }
    __syncthreads();
    unsigned v = hist[t];
    excl[t] = v;
    __syncthreads();
    for (int off = 1; off < 256; off <<= 1) {
        unsigned add = (t >= off) ? excl[t - off] : 0;
        __syncthreads();
        excl[t] += add;
        __syncthreads();
    }
    unsigned my = excl[t] - v + (unsigned)s;
    int node = b * 256 + t;
    if (node <= N_NODES) offsets[node] = (int)my;
    hist[t] = my;  // reuse as cursor
    __syncthreads();
    for (int i = s + t; i < e; i += 256) {
        unsigned long long p = pkA[i];
        unsigned lo = (unsigned)p;
        unsigned cl = (lo >> 17) & 255u;
        int r = (int)(lo & 0x1FFFFu);
        unsigned pos = atomicAdd(&hist[cl], 1u);  // LDS
        csr_row[pos] = r;
        int c = (b << 8) + (int)cl;
        csr_norm[pos] = dis[r] * __uint_as_float((unsigned)(p >> 32)) * dis[c];
    }
}

// ============ GEMM: out[M,64] = A[M,K] @ W[K,64] — no LDS, max occupancy ============
// 256 thr = 4 waves; 32 rows/block; thread = 1 col x 8 rows. W read direct from
// global (L1/L2-resident: W1=32KB, W2=16KB). A-loads are wave-uniform broadcast
// float4 hitting the same cacheline across k -> L1. LDS=0 so occupancy hits the
// 32-wave/CU cap and load latency is hidden by TLP.
__global__ __launch_bounds__(256, 8) void gemm64_kernel(
        const float* __restrict__ A, const float* __restrict__ W,
        float* __restrict__ out, int M, int K) {
    const int col  = threadIdx.x & 63;
    const int rg   = threadIdx.x >> 6;
    const int row0 = blockIdx.x * 32 + rg * 8;

    float acc[8];
#pragma unroll
    for (int i = 0; i < 8; ++i) acc[i] = 0.f;

    if (row0 + 8 <= M) {
        const float* ap = A + (size_t)row0 * K;
        const float* wp = W + col;
        for (int k = 0; k < K; k += 4) {
            float w0 = wp[(k + 0) * 64];
            float w1 = wp[(k + 1) * 64];
            float w2 = wp[(k + 2) * 64];
            float w3 = wp[(k + 3) * 64];
#pragma unroll
            for (int i = 0; i < 8; ++i) {
                const float4 a = *reinterpret_cast<const float4*>(&ap[(size_t)i * K + k]);
                acc[i] = fmaf(a.x, w0, acc[i]);
                acc[i] = fmaf(a.y, w1, acc[i]);
                acc[i] = fmaf(a.z, w2, acc[i]);
                acc[i] = fmaf(a.w, w3, acc[i]);
            }
        }
        float* op = out + (size_t)row0 * 64 + col;
#pragma unroll
        for (int i = 0; i < 8; ++i) op[(size_t)i * 64] = acc[i];
    } else {
        const float* wp = W + col;
        for (int k = 0; k < K; ++k) {
            float wv = wp[k * 64];
            for (int i = 0; i < 8; ++i) {
                int r = row0 + i;
                if (r < M) acc[i] = fmaf(A[(size_t)r * K + k], wv, acc[i]);
            }
        }
        for (int i = 0; i < 8; ++i) {
            int r = row0 + i;
            if (r < M) out[(size_t)r * 64 + col] = acc[i];
        }
    }
}

// ============ gather conv: one wave per destination node ============
template <int RELU_OUT>
__global__ void gather_conv_kernel(const float* __restrict__ h, const int* __restrict__ csr_row,
                                   const float* __restrict__ csr_norm, const int* __restrict__ offsets,
                                   const float* __restrict__ bias, float* __restrict__ out, int n) {
    int node = blockIdx.x * (blockDim.x >> 6) + (threadIdx.x >> 6);
    int lane = threadIdx.x & 63;
    if (node >= n) return;
    int s = offsets[node];
    int e = offsets[node + 1];
    float a0 = bias[lane], a1 = 0.f, a2 = 0.f, a3 = 0.f;
    int j = s;
    for (; j + 4 <= e; j += 4) {
        int r0 = csr_row[j], r1 = csr_row[j + 1], r2 = csr_row[j + 2], r3 = csr_row[j + 3];
        float n0 = csr_norm[j], n1 = csr_norm[j + 1], n2 = csr_norm[j + 2], n3 = csr_norm[j + 3];
        a0 = fmaf(h[(size_t)r0 * 64 + lane], n0, a0);
        a1 = fmaf(h[(size_t)r1 * 64 + lane], n1, a1);
        a2 = fmaf(h[(size_t)r2 * 64 + lane], n2, a2);
        a3 = fmaf(h[(size_t)r3 * 64 + lane], n3, a3);
    }
    for (; j < e; ++j)
        a0 = fmaf(h[(size_t)csr_row[j] * 64 + lane], csr_norm[j], a0);
    float acc = (a0 + a1) + (a2 + a3);
    if (RELU_OUT) acc = fmaxf(acc, 0.f);
    out[(size_t)node * 64 + lane] = acc;
}

extern "C" void kernel_launch(void* const* d_in, const int* in_sizes, int n_in,
                              void* d_out, int out_size, void* d_ws, size_t ws_size,
                              hipStream_t stream) {
    const float* x  = (const float*)d_in[0];
    const int*   ei = (const int*)d_in[1];
    const float* ew = (const float*)d_in[2];
    const float* W1 = (const float*)d_in[3];
    const float* b1 = (const float*)d_in[4];
    const float* W2 = (const float*)d_in[5];
    const float* b2 = (const float*)d_in[6];
    float* out = (float*)d_out;
    char*  ws  = (char*)d_ws;

    const int* rows = ei;
    const int* cols = ei + N_EDGES;

    // ---- workspace (byte offsets) ----
    int*      csr_row  = (int*)(ws + 0);                       // 6,400,000
    float*    csr_norm = (float*)(ws + 6400000);               // 6,400,000
    float*    bufA     = (float*)(ws + 12800000);              // 25,600,000 (aliases pkA+pkR)
    unsigned long long* pkA = (unsigned long long*)(ws + 12800000);  // [dies at fill]
    unsigned long long* pkR = (unsigned long long*)(ws + 25600000);  // [dies at deg_reduce]
    int*      MC       = (int*)(ws + 38400000);                // 800,768
    int*      MCs      = (int*)(ws + 39250000);                // 800,772
    int*      MR       = (int*)(ws + 40100000);                // 800,768
    int*      MRs      = (int*)(ws + 40950000);                // 800,772
    int*      partials = (int*)(ws + 41800000);                // 1,024
    int*      offsets  = (int*)(ws + 41810000);                // 400,004
    float*    dis      = (float*)(ws + 42220000);              // 400,000

    const int TPB = 256;
    const int n2  = NB * NBLK;                   // 200,192
    const int nSB2 = (n2 + 1023) / 1024;         // 196

    // 1) per-block bucket histograms
    count_kernel<<<NBLK, TPB, 0, stream>>>(rows, cols, MC, MR);

    // 2) scan both matrices
    block_sum_kernel<<<nSB2, 256, 0, stream>>>(MC, partials, n2);
    scan_partials_kernel<<<1, 256, 0, stream>>>(partials, nSB2);
    scan_final_kernel<<<nSB2, 256, 0, stream>>>(MC, partials, MCs, n2);
    block_sum_kernel<<<nSB2, 256, 0, stream>>>(MR, partials, n2);
    scan_partials_kernel<<<1, 256, 0, stream>>>(partials, nSB2);
    scan_final_kernel<<<nSB2, 256, 0, stream>>>(MR, partials, MRs, n2);

    // 3) bin edges into payloads
    scatter_kernel<<<NBLK, TPB, 0, stream>>>(rows, cols, ew, MCs, MRs, pkA, pkR);

    // 4) deg -> dis
    deg_reduce_kernel<<<NB, TPB, 0, stream>>>(pkR, MRs, dis);

    // 5) per-node offsets + CSR fill
    fill_kernel<<<NB, TPB, 0, stream>>>(pkA, MCs, dis, csr_row, csr_norm, offsets);

    // 6) h1 = x @ W1 -> bufA (kills pkA/pkR)
    gemm64_kernel<<<(N_NODES + 31) / 32, TPB, 0, stream>>>(x, W1, bufA, N_NODES, IN_DIM);

    // 7) conv1 (+b1, fused relu): gather bufA -> out
    gather_conv_kernel<1><<<(N_NODES + 3) / 4, TPB, 0, stream>>>(
        bufA, csr_row, csr_norm, offsets, b1, out, N_NODES);

    // 8) h2 = out @ W2 -> bufA
    gemm64_kernel<<<(N_NODES + 31) / 32, TPB, 0, stream>>>(out, W2, bufA, N_NODES, HID_DIM);

    // 9) conv2 (+b2): gather bufA -> out
    gather_conv_kernel<0><<<(N_NODES + 3) / 4, TPB, 0, stream>>>(
        bufA, csr_row, csr_norm, offsets, b2, out, N_NODES);
}

// Round 6
// 343.999 us; speedup vs baseline: 3.1518x; 1.1917x over previous
//
#include <hip/hip_runtime.h>

#define N_NODES 100000
#define N_EDGES 1600000
#define IN_DIM 128
#define HID_DIM 64
#define OUT_DIM 64
#define NB 391      // node buckets of 256: ceil(100000/256)
#define NBLK 512    // edge-chunk blocks
#define CHUNK 3125  // 512*3125 = 1,600,000

// ============ count: per-block LDS histograms by col-bucket and row-bucket ============
__global__ void count_kernel(const int* __restrict__ rows, const int* __restrict__ cols,
                             int* __restrict__ MC, int* __restrict__ MR) {
    __shared__ unsigned hc[NB], hr[NB];
    for (int i = threadIdx.x; i < NB; i += 256) { hc[i] = 0; hr[i] = 0; }
    __syncthreads();
    const int s = blockIdx.x * CHUNK;
    const int e = min(s + CHUNK, N_EDGES);
    for (int i = s + threadIdx.x; i < e; i += 256) {
        atomicAdd(&hr[rows[i] >> 8], 1u);
        atomicAdd(&hc[cols[i] >> 8], 1u);
    }
    __syncthreads();
    for (int i = threadIdx.x; i < NB; i += 256) {
        MC[i * NBLK + blockIdx.x] = (int)hc[i];
        MR[i * NBLK + blockIdx.x] = (int)hr[i];
    }
}

// ============ exclusive scan (3 kernels) ============
__global__ void block_sum_kernel(const int* __restrict__ counts, int* __restrict__ partials, int n) {
    __shared__ int sh[256];
    int base = blockIdx.x * 1024;
    int s = 0;
    for (int i = threadIdx.x; i < 1024; i += 256) {
        int idx = base + i;
        s += (idx < n) ? counts[idx] : 0;
    }
    sh[threadIdx.x] = s;
    __syncthreads();
    for (int off = 128; off > 0; off >>= 1) {
        if (threadIdx.x < off) sh[threadIdx.x] += sh[threadIdx.x + off];
        __syncthreads();
    }
    if (threadIdx.x == 0) partials[blockIdx.x] = sh[0];
}

__global__ void scan_partials_kernel(int* __restrict__ p, int nb) {
    __shared__ int sh[256];
    int t = threadIdx.x;
    int v = (t < nb) ? p[t] : 0;
    sh[t] = v;
    __syncthreads();
    for (int off = 1; off < 256; off <<= 1) {
        int add = (t >= off) ? sh[t - off] : 0;
        __syncthreads();
        sh[t] += add;
        __syncthreads();
    }
    if (t < nb) p[t] = sh[t] - v;  // exclusive
}

__global__ void scan_final_kernel(const int* __restrict__ counts, const int* __restrict__ partials,
                                  int* __restrict__ offsets, int n) {
    __shared__ int sh[256];
    int t = threadIdx.x;
    int idx0 = blockIdx.x * 1024 + t * 4;
    int v[4];
    int s = 0;
#pragma unroll
    for (int j = 0; j < 4; ++j) {
        int id = idx0 + j;
        v[j] = (id < n) ? counts[id] : 0;
        s += v[j];
    }
    sh[t] = s;
    __syncthreads();
    for (int off = 1; off < 256; off <<= 1) {
        int add = (t >= off) ? sh[t - off] : 0;
        __syncthreads();
        sh[t] += add;
        __syncthreads();
    }
    int run = sh[t] - s + partials[blockIdx.x];
#pragma unroll
    for (int j = 0; j < 4; ++j) {
        int id = idx0 + j;
        if (id < n) offsets[id] = run;
        run += v[j];
    }
    if (idx0 <= n - 1 && n - 1 < idx0 + 4) offsets[n] = run;
}

// ============ scatter: bin edges by col-bucket (pkA) and row-bucket (pkR) ============
__global__ void scatter_kernel(const int* __restrict__ rows, const int* __restrict__ cols,
                               const float* __restrict__ w, const int* __restrict__ MCs,
                               const int* __restrict__ MRs,
                               unsigned long long* __restrict__ pkA,
                               unsigned long long* __restrict__ pkR) {
    __shared__ unsigned curC[NB], curR[NB];
    for (int i = threadIdx.x; i < NB; i += 256) {
        curC[i] = (unsigned)MCs[i * NBLK + blockIdx.x];
        curR[i] = (unsigned)MRs[i * NBLK + blockIdx.x];
    }
    __syncthreads();
    const int s = blockIdx.x * CHUNK;
    const int e = min(s + CHUNK, N_EDGES);
    for (int i = s + threadIdx.x; i < e; i += 256) {
        int r = rows[i], c = cols[i];
        unsigned wb = __float_as_uint(w[i]);
        unsigned pA = atomicAdd(&curC[c >> 8], 1u);  // LDS
        pkA[pA] = ((unsigned long long)wb << 32) | (unsigned)(((c & 255) << 17) | r);
        unsigned pR = atomicAdd(&curR[r >> 8], 1u);  // LDS
        pkR[pR] = ((unsigned long long)wb << 32) | (unsigned)(r & 255);
    }
}

// ============ deg reduce: block per row-bucket, LDS accumulation -> dis ============
__global__ void deg_reduce_kernel(const unsigned long long* __restrict__ pkR,
                                  const int* __restrict__ MRs, float* __restrict__ dis) {
    __shared__ float acc[256];
    const int b = blockIdx.x;
    acc[threadIdx.x] = 0.f;
    __syncthreads();
    const int s = MRs[b * NBLK];
    const int e = MRs[(b + 1) * NBLK];
    for (int i = s + threadIdx.x; i < e; i += 256) {
        unsigned long long p = pkR[i];
        atomicAdd(&acc[(unsigned)p & 255u], __uint_as_float((unsigned)(p >> 32)));  // LDS
    }
    __syncthreads();
    int node = b * 256 + threadIdx.x;
    if (node < N_NODES) {
        float d = acc[threadIdx.x];
        dis[node] = d > 0.f ? rsqrtf(fmaxf(d, 1e-12f)) : 0.f;
    }
}

// ============ fill: block per col-bucket; LDS count+scan -> offsets + CSR ============
__global__ void fill_kernel(const unsigned long long* __restrict__ pkA,
                            const int* __restrict__ MCs, const float* __restrict__ dis,
                            int* __restrict__ csr_row, float* __restrict__ csr_norm,
                            int* __restrict__ offsets) {
    __shared__ unsigned hist[256];
    __shared__ unsigned excl[256];
    const int b = blockIdx.x;
    const int t = threadIdx.x;
    hist[t] = 0;
    __syncthreads();
    const int s = MCs[b * NBLK];
    const int e = MCs[(b + 1) * NBLK];
    for (int i = s + t; i < e; i += 256) {
        unsigned lo = (unsigned)pkA[i];
        atomicAdd(&hist[(lo >> 17) & 255u], 1u);  // LDS
    }
    __syncthreads();
    unsigned v = hist[t];
    excl[t] = v;
    __syncthreads();
    for (int off = 1; off < 256; off <<= 1) {
        unsigned add = (t >= off) ? excl[t - off] : 0;
        __syncthreads();
        excl[t] += add;
        __syncthreads();
    }
    unsigned my = excl[t] - v + (unsigned)s;
    int node = b * 256 + t;
    if (node <= N_NODES) offsets[node] = (int)my;
    hist[t] = my;  // reuse as cursor
    __syncthreads();
    for (int i = s + t; i < e; i += 256) {
        unsigned long long p = pkA[i];
        unsigned lo = (unsigned)p;
        unsigned cl = (lo >> 17) & 255u;
        int r = (int)(lo & 0x1FFFFu);
        unsigned pos = atomicAdd(&hist[cl], 1u);  // LDS
        csr_row[pos] = r;
        int c = (b << 8) + (int)cl;
        csr_norm[pos] = dis[r] * __uint_as_float((unsigned)(p >> 32)) * dis[c];
    }
}

// ============ GEMM1: out[100000,64] = A[100000,128] @ W[128,64] ============
// Bulk LDS staging: A-tile (32x128 = 16KB) + W (32KB) loaded with back-to-back
// coalesced float4 (high MLP), one barrier, inner loop entirely from LDS.
// A reads in compute are wave-uniform broadcasts (conflict-free); W reads are
// per-lane consecutive (conflict-free). 48KB LDS -> 3 blocks/CU.
__global__ __launch_bounds__(256) void gemm1_kernel(
        const float* __restrict__ A, const float* __restrict__ W, float* __restrict__ out) {
    __shared__ float Al[32 * 128];   // 16 KB
    __shared__ float Wl[128 * 64];   // 32 KB
    const int tid = threadIdx.x;
    const int row0 = blockIdx.x * 32;          // 3125 * 32 = 100000 exactly

    const float4* wg = (const float4*)W;
    float4* wl = (float4*)Wl;
#pragma unroll
    for (int i = 0; i < 8; ++i) wl[tid + i * 256] = wg[tid + i * 256];      // 2048 f4
    const float4* ag = (const float4*)(A + (size_t)row0 * 128);
    float4* al4 = (float4*)Al;
#pragma unroll
    for (int i = 0; i < 4; ++i) al4[tid + i * 256] = ag[tid + i * 256];     // 1024 f4
    __syncthreads();

    const int col = tid & 63;
    const int rg  = tid >> 6;
    const float* al = Al + rg * 8 * 128;

    float acc[8];
#pragma unroll
    for (int i = 0; i < 8; ++i) acc[i] = 0.f;

    for (int k = 0; k < 128; k += 4) {
        float w0 = Wl[(k + 0) * 64 + col];
        float w1 = Wl[(k + 1) * 64 + col];
        float w2 = Wl[(k + 2) * 64 + col];
        float w3 = Wl[(k + 3) * 64 + col];
#pragma unroll
        for (int i = 0; i < 8; ++i) {
            const float4 a = *reinterpret_cast<const float4*>(&al[i * 128 + k]);
            acc[i] = fmaf(a.x, w0, acc[i]);
            acc[i] = fmaf(a.y, w1, acc[i]);
            acc[i] = fmaf(a.z, w2, acc[i]);
            acc[i] = fmaf(a.w, w3, acc[i]);
        }
    }
    float* op = out + (size_t)(row0 + rg * 8) * 64 + col;
#pragma unroll
    for (int i = 0; i < 8; ++i) op[(size_t)i * 64] = acc[i];
}

// ============ gather conv1 + fused [bias, relu, @W2] epilogue ============
// One wave per destination node (512 thr = 8 nodes/block). After the gather,
// the wave holds conv1's 64-channel row in t (lane=channel). h2 = relu-row @ W2
// via 64 shfl-broadcast + FMA steps against LDS-staged W2 (16KB).
__global__ __launch_bounds__(512) void gather1_fused_kernel(
        const float* __restrict__ h, const int* __restrict__ csr_row,
        const float* __restrict__ csr_norm, const int* __restrict__ offsets,
        const float* __restrict__ b1, const float* __restrict__ W2,
        float* __restrict__ h2, int n) {
    __shared__ float W2l[64 * 64];  // 16 KB
    {
        const float4* wg = (const float4*)W2;
        float4* wl = (float4*)W2l;
#pragma unroll
        for (int i = 0; i < 2; ++i) wl[threadIdx.x + i * 512] = wg[threadIdx.x + i * 512];
    }
    __syncthreads();

    int node = blockIdx.x * 8 + (threadIdx.x >> 6);   // 12500 * 8 = 100000 exactly
    int lane = threadIdx.x & 63;
    if (node >= n) return;
    int s = offsets[node];
    int e = offsets[node + 1];
    float a0 = b1[lane], a1 = 0.f, a2 = 0.f, a3 = 0.f;
    int j = s;
    for (; j + 4 <= e; j += 4) {
        int r0 = csr_row[j], r1 = csr_row[j + 1], r2 = csr_row[j + 2], r3 = csr_row[j + 3];
        float n0 = csr_norm[j], n1 = csr_norm[j + 1], n2 = csr_norm[j + 2], n3 = csr_norm[j + 3];
        a0 = fmaf(h[(size_t)r0 * 64 + lane], n0, a0);
        a1 = fmaf(h[(size_t)r1 * 64 + lane], n1, a1);
        a2 = fmaf(h[(size_t)r2 * 64 + lane], n2, a2);
        a3 = fmaf(h[(size_t)r3 * 64 + lane], n3, a3);
    }
    for (; j < e; ++j)
        a0 = fmaf(h[(size_t)csr_row[j] * 64 + lane], csr_norm[j], a0);
    float t = fmaxf((a0 + a1) + (a2 + a3), 0.f);   // conv1 + b1, relu

    // h2 row = t @ W2
    float o = 0.f;
#pragma unroll 8
    for (int q = 0; q < 64; ++q) {
        float tq = __shfl(t, q);
        o = fmaf(tq, W2l[q * 64 + lane], o);
    }
    h2[(size_t)node * 64 + lane] = o;
}

// ============ gather conv2: one wave per destination node ============
__global__ void gather_conv_kernel(const float* __restrict__ h, const int* __restrict__ csr_row,
                                   const float* __restrict__ csr_norm, const int* __restrict__ offsets,
                                   const float* __restrict__ bias, float* __restrict__ out, int n) {
    int node = blockIdx.x * (blockDim.x >> 6) + (threadIdx.x >> 6);
    int lane = threadIdx.x & 63;
    if (node >= n) return;
    int s = offsets[node];
    int e = offsets[node + 1];
    float a0 = bias[lane], a1 = 0.f, a2 = 0.f, a3 = 0.f;
    int j = s;
    for (; j + 4 <= e; j += 4) {
        int r0 = csr_row[j], r1 = csr_row[j + 1], r2 = csr_row[j + 2], r3 = csr_row[j + 3];
        float n0 = csr_norm[j], n1 = csr_norm[j + 1], n2 = csr_norm[j + 2], n3 = csr_norm[j + 3];
        a0 = fmaf(h[(size_t)r0 * 64 + lane], n0, a0);
        a1 = fmaf(h[(size_t)r1 * 64 + lane], n1, a1);
        a2 = fmaf(h[(size_t)r2 * 64 + lane], n2, a2);
        a3 = fmaf(h[(size_t)r3 * 64 + lane], n3, a3);
    }
    for (; j < e; ++j)
        a0 = fmaf(h[(size_t)csr_row[j] * 64 + lane], csr_norm[j], a0);
    out[(size_t)node * 64 + lane] = (a0 + a1) + (a2 + a3);
}

extern "C" void kernel_launch(void* const* d_in, const int* in_sizes, int n_in,
                              void* d_out, int out_size, void* d_ws, size_t ws_size,
                              hipStream_t stream) {
    const float* x  = (const float*)d_in[0];
    const int*   ei = (const int*)d_in[1];
    const float* ew = (const float*)d_in[2];
    const float* W1 = (const float*)d_in[3];
    const float* b1 = (const float*)d_in[4];
    const float* W2 = (const float*)d_in[5];
    const float* b2 = (const float*)d_in[6];
    float* out = (float*)d_out;
    char*  ws  = (char*)d_ws;

    const int* rows = ei;
    const int* cols = ei + N_EDGES;

    // ---- workspace (byte offsets) ----
    int*      csr_row  = (int*)(ws + 0);                       // 6,400,000
    float*    csr_norm = (float*)(ws + 6400000);               // 6,400,000
    float*    bufA     = (float*)(ws + 12800000);              // 25,600,000 (h2; aliases pkA+pkR)
    unsigned long long* pkA = (unsigned long long*)(ws + 12800000);  // [dies at fill]
    unsigned long long* pkR = (unsigned long long*)(ws + 25600000);  // [dies at deg_reduce]
    int*      MC       = (int*)(ws + 38400000);                // 800,768
    int*      MCs      = (int*)(ws + 39250000);                // 800,772
    int*      MR       = (int*)(ws + 40100000);                // 800,768
    int*      MRs      = (int*)(ws + 40950000);                // 800,772
    int*      partials = (int*)(ws + 41800000);                // 1,024
    int*      offsets  = (int*)(ws + 41810000);                // 400,004
    float*    dis      = (float*)(ws + 42220000);              // 400,000

    const int TPB = 256;
    const int n2  = NB * NBLK;                   // 200,192
    const int nSB2 = (n2 + 1023) / 1024;         // 196

    // 1) per-block bucket histograms
    count_kernel<<<NBLK, TPB, 0, stream>>>(rows, cols, MC, MR);

    // 2) scan both matrices
    block_sum_kernel<<<nSB2, 256, 0, stream>>>(MC, partials, n2);
    scan_partials_kernel<<<1, 256, 0, stream>>>(partials, nSB2);
    scan_final_kernel<<<nSB2, 256, 0, stream>>>(MC, partials, MCs, n2);
    block_sum_kernel<<<nSB2, 256, 0, stream>>>(MR, partials, n2);
    scan_partials_kernel<<<1, 256, 0, stream>>>(partials, nSB2);
    scan_final_kernel<<<nSB2, 256, 0, stream>>>(MR, partials, MRs, n2);

    // 3) bin edges into payloads
    scatter_kernel<<<NBLK, TPB, 0, stream>>>(rows, cols, ew, MCs, MRs, pkA, pkR);

    // 4) deg -> dis
    deg_reduce_kernel<<<NB, TPB, 0, stream>>>(pkR, MRs, dis);

    // 5) per-node offsets + CSR fill
    fill_kernel<<<NB, TPB, 0, stream>>>(pkA, MCs, dis, csr_row, csr_norm, offsets);

    // 6) h1 = x @ W1 -> out (d_out used as scratch)
    gemm1_kernel<<<N_NODES / 32, 256, 0, stream>>>(x, W1, out);

    // 7) conv1 + b1 + relu + @W2 fused: gather out(h1) -> bufA(h2)  [kills pkA/pkR]
    gather1_fused_kernel<<<N_NODES / 8, 512, 0, stream>>>(
        out, csr_row, csr_norm, offsets, b1, W2, bufA, N_NODES);

    // 8) conv2 + b2: gather bufA(h2) -> out (final)
    gather_conv_kernel<<<(N_NODES + 3) / 4, TPB, 0, stream>>>(
        bufA, csr_row, csr_norm, offsets, b2, out, N_NODES);
}

// Round 7
// 327.147 us; speedup vs baseline: 3.3141x; 1.0515x over previous
//
#include <hip/hip_runtime.h>
#include <hip/hip_fp16.h>

#define N_NODES 100000
#define N_EDGES 1600000
#define IN_DIM 128
#define HID_DIM 64
#define OUT_DIM 64
#define NB 391      // node buckets of 256: ceil(100000/256)
#define NBLK 512    // edge-chunk blocks
#define CHUNK 3125  // 512*3125 = 1,600,000

// ============ count: per-block LDS histograms by col-bucket and row-bucket ============
__global__ void count_kernel(const int* __restrict__ rows, const int* __restrict__ cols,
                             int* __restrict__ MC, int* __restrict__ MR) {
    __shared__ unsigned hc[NB], hr[NB];
    for (int i = threadIdx.x; i < NB; i += 256) { hc[i] = 0; hr[i] = 0; }
    __syncthreads();
    const int s = blockIdx.x * CHUNK;
    const int e = min(s + CHUNK, N_EDGES);
    for (int i = s + threadIdx.x; i < e; i += 256) {
        atomicAdd(&hr[rows[i] >> 8], 1u);
        atomicAdd(&hc[cols[i] >> 8], 1u);
    }
    __syncthreads();
    for (int i = threadIdx.x; i < NB; i += 256) {
        MC[i * NBLK + blockIdx.x] = (int)hc[i];
        MR[i * NBLK + blockIdx.x] = (int)hr[i];
    }
}

// ============ exclusive scan (3 kernels) ============
__global__ void block_sum_kernel(const int* __restrict__ counts, int* __restrict__ partials, int n) {
    __shared__ int sh[256];
    int base = blockIdx.x * 1024;
    int s = 0;
    for (int i = threadIdx.x; i < 1024; i += 256) {
        int idx = base + i;
        s += (idx < n) ? counts[idx] : 0;
    }
    sh[threadIdx.x] = s;
    __syncthreads();
    for (int off = 128; off > 0; off >>= 1) {
        if (threadIdx.x < off) sh[threadIdx.x] += sh[threadIdx.x + off];
        __syncthreads();
    }
    if (threadIdx.x == 0) partials[blockIdx.x] = sh[0];
}

__global__ void scan_partials_kernel(int* __restrict__ p, int nb) {
    __shared__ int sh[256];
    int t = threadIdx.x;
    int v = (t < nb) ? p[t] : 0;
    sh[t] = v;
    __syncthreads();
    for (int off = 1; off < 256; off <<= 1) {
        int add = (t >= off) ? sh[t - off] : 0;
        __syncthreads();
        sh[t] += add;
        __syncthreads();
    }
    if (t < nb) p[t] = sh[t] - v;  // exclusive
}

__global__ void scan_final_kernel(const int* __restrict__ counts, const int* __restrict__ partials,
                                  int* __restrict__ offsets, int n) {
    __shared__ int sh[256];
    int t = threadIdx.x;
    int idx0 = blockIdx.x * 1024 + t * 4;
    int v[4];
    int s = 0;
#pragma unroll
    for (int j = 0; j < 4; ++j) {
        int id = idx0 + j;
        v[j] = (id < n) ? counts[id] : 0;
        s += v[j];
    }
    sh[t] = s;
    __syncthreads();
    for (int off = 1; off < 256; off <<= 1) {
        int add = (t >= off) ? sh[t - off] : 0;
        __syncthreads();
        sh[t] += add;
        __syncthreads();
    }
    int run = sh[t] - s + partials[blockIdx.x];
#pragma unroll
    for (int j = 0; j < 4; ++j) {
        int id = idx0 + j;
        if (id < n) offsets[id] = run;
        run += v[j];
    }
    if (idx0 <= n - 1 && n - 1 < idx0 + 4) offsets[n] = run;
}

// ============ scatter: bin edges by col-bucket (pkA) and row-bucket (pkR) ============
__global__ void scatter_kernel(const int* __restrict__ rows, const int* __restrict__ cols,
                               const float* __restrict__ w, const int* __restrict__ MCs,
                               const int* __restrict__ MRs,
                               unsigned long long* __restrict__ pkA,
                               unsigned long long* __restrict__ pkR) {
    __shared__ unsigned curC[NB], curR[NB];
    for (int i = threadIdx.x; i < NB; i += 256) {
        curC[i] = (unsigned)MCs[i * NBLK + blockIdx.x];
        curR[i] = (unsigned)MRs[i * NBLK + blockIdx.x];
    }
    __syncthreads();
    const int s = blockIdx.x * CHUNK;
    const int e = min(s + CHUNK, N_EDGES);
    for (int i = s + threadIdx.x; i < e; i += 256) {
        int r = rows[i], c = cols[i];
        unsigned wb = __float_as_uint(w[i]);
        unsigned pA = atomicAdd(&curC[c >> 8], 1u);  // LDS
        pkA[pA] = ((unsigned long long)wb << 32) | (unsigned)(((c & 255) << 17) | r);
        unsigned pR = atomicAdd(&curR[r >> 8], 1u);  // LDS
        pkR[pR] = ((unsigned long long)wb << 32) | (unsigned)(r & 255);
    }
}

// ============ deg reduce: block per row-bucket, LDS accumulation -> dis ============
__global__ void deg_reduce_kernel(const unsigned long long* __restrict__ pkR,
                                  const int* __restrict__ MRs, float* __restrict__ dis) {
    __shared__ float acc[256];
    const int b = blockIdx.x;
    acc[threadIdx.x] = 0.f;
    __syncthreads();
    const int s = MRs[b * NBLK];
    const int e = MRs[(b + 1) * NBLK];
    for (int i = s + threadIdx.x; i < e; i += 256) {
        unsigned long long p = pkR[i];
        atomicAdd(&acc[(unsigned)p & 255u], __uint_as_float((unsigned)(p >> 32)));  // LDS
    }
    __syncthreads();
    int node = b * 256 + threadIdx.x;
    if (node < N_NODES) {
        float d = acc[threadIdx.x];
        dis[node] = d > 0.f ? rsqrtf(fmaxf(d, 1e-12f)) : 0.f;
    }
}

// ============ fill: block per col-bucket; LDS count+scan -> offsets + CSR(int2) ============
__global__ void fill_kernel(const unsigned long long* __restrict__ pkA,
                            const int* __restrict__ MCs, const float* __restrict__ dis,
                            int2* __restrict__ csr, int* __restrict__ offsets) {
    __shared__ unsigned hist[256];
    __shared__ unsigned excl[256];
    const int b = blockIdx.x;
    const int t = threadIdx.x;
    hist[t] = 0;
    __syncthreads();
    const int s = MCs[b * NBLK];
    const int e = MCs[(b + 1) * NBLK];
    for (int i = s + t; i < e; i += 256) {
        unsigned lo = (unsigned)pkA[i];
        atomicAdd(&hist[(lo >> 17) & 255u], 1u);  // LDS
    }
    __syncthreads();
    unsigned v = hist[t];
    excl[t] = v;
    __syncthreads();
    for (int off = 1; off < 256; off <<= 1) {
        unsigned add = (t >= off) ? excl[t - off] : 0;
        __syncthreads();
        excl[t] += add;
        __syncthreads();
    }
    unsigned my = excl[t] - v + (unsigned)s;
    int node = b * 256 + t;
    if (node <= N_NODES) offsets[node] = (int)my;
    hist[t] = my;  // reuse as cursor
    __syncthreads();
    for (int i = s + t; i < e; i += 256) {
        unsigned long long p = pkA[i];
        unsigned lo = (unsigned)p;
        unsigned cl = (lo >> 17) & 255u;
        int r = (int)(lo & 0x1FFFFu);
        unsigned pos = atomicAdd(&hist[cl], 1u);  // LDS
        int c = (b << 8) + (int)cl;
        float nv = dis[r] * __uint_as_float((unsigned)(p >> 32)) * dis[c];
        csr[pos] = make_int2(r, __float_as_int(nv));
    }
}

// ============ GEMM1: h1[100000,64](fp16) = A[100000,128] @ W[128,64] ============
// Bulk LDS staging, inner loop entirely from LDS, fp16 output (halves write).
__global__ __launch_bounds__(256) void gemm1_kernel(
        const float* __restrict__ A, const float* __restrict__ W, __half* __restrict__ out) {
    __shared__ float Al[32 * 128];   // 16 KB
    __shared__ float Wl[128 * 64];   // 32 KB
    const int tid = threadIdx.x;
    const int row0 = blockIdx.x * 32;          // 3125 * 32 = 100000 exactly

    const float4* wg = (const float4*)W;
    float4* wl = (float4*)Wl;
#pragma unroll
    for (int i = 0; i < 8; ++i) wl[tid + i * 256] = wg[tid + i * 256];
    const float4* ag = (const float4*)(A + (size_t)row0 * 128);
    float4* al4 = (float4*)Al;
#pragma unroll
    for (int i = 0; i < 4; ++i) al4[tid + i * 256] = ag[tid + i * 256];
    __syncthreads();

    const int col = tid & 63;
    const int rg  = tid >> 6;
    const float* al = Al + rg * 8 * 128;

    float acc[8];
#pragma unroll
    for (int i = 0; i < 8; ++i) acc[i] = 0.f;

    for (int k = 0; k < 128; k += 4) {
        float w0 = Wl[(k + 0) * 64 + col];
        float w1 = Wl[(k + 1) * 64 + col];
        float w2 = Wl[(k + 2) * 64 + col];
        float w3 = Wl[(k + 3) * 64 + col];
#pragma unroll
        for (int i = 0; i < 8; ++i) {
            const float4 a = *reinterpret_cast<const float4*>(&al[i * 128 + k]);
            acc[i] = fmaf(a.x, w0, acc[i]);
            acc[i] = fmaf(a.y, w1, acc[i]);
            acc[i] = fmaf(a.z, w2, acc[i]);
            acc[i] = fmaf(a.w, w3, acc[i]);
        }
    }
    __half* op = out + (size_t)(row0 + rg * 8) * 64 + col;
#pragma unroll
    for (int i = 0; i < 8; ++i) op[(size_t)i * 64] = __float2half(acc[i]);
}

// ============ gather conv1 + fused [b1, relu, @W2] -> h2 (fp16) ============
// One wave per destination node. h is fp16 (128B/row -> half the fetch).
__global__ __launch_bounds__(512) void gather1_fused_kernel(
        const __half* __restrict__ h, const int2* __restrict__ csr,
        const int* __restrict__ offsets, const float* __restrict__ b1,
        const float* __restrict__ W2, __half* __restrict__ h2, int n) {
    __shared__ float W2l[64 * 64];  // 16 KB
    {
        const float4* wg = (const float4*)W2;
        float4* wl = (float4*)W2l;
#pragma unroll
        for (int i = 0; i < 2; ++i) wl[threadIdx.x + i * 512] = wg[threadIdx.x + i * 512];
    }
    __syncthreads();

    int node = blockIdx.x * 8 + (threadIdx.x >> 6);
    int lane = threadIdx.x & 63;
    if (node >= n) return;
    int s = offsets[node];
    int e = offsets[node + 1];
    float a0 = b1[lane], a1 = 0.f, a2 = 0.f, a3 = 0.f;
    int j = s;
    for (; j + 4 <= e; j += 4) {
        int2 p0 = csr[j], p1 = csr[j + 1], p2 = csr[j + 2], p3 = csr[j + 3];
        a0 = fmaf(__half2float(h[(size_t)p0.x * 64 + lane]), __int_as_float(p0.y), a0);
        a1 = fmaf(__half2float(h[(size_t)p1.x * 64 + lane]), __int_as_float(p1.y), a1);
        a2 = fmaf(__half2float(h[(size_t)p2.x * 64 + lane]), __int_as_float(p2.y), a2);
        a3 = fmaf(__half2float(h[(size_t)p3.x * 64 + lane]), __int_as_float(p3.y), a3);
    }
    for (; j < e; ++j) {
        int2 p = csr[j];
        a0 = fmaf(__half2float(h[(size_t)p.x * 64 + lane]), __int_as_float(p.y), a0);
    }
    float t = fmaxf((a0 + a1) + (a2 + a3), 0.f);   // conv1 + b1, relu

    // h2 row = t @ W2 (shfl-broadcast against LDS W2)
    float o = 0.f;
#pragma unroll 8
    for (int q = 0; q < 64; ++q) {
        float tq = __shfl(t, q);
        o = fmaf(tq, W2l[q * 64 + lane], o);
    }
    h2[(size_t)node * 64 + lane] = __float2half(o);
}

// ============ gather conv2: fp16 h2 -> fp32 out (+b2) ============
__global__ void gather_conv2_kernel(const __half* __restrict__ h, const int2* __restrict__ csr,
                                    const int* __restrict__ offsets, const float* __restrict__ bias,
                                    float* __restrict__ out, int n) {
    int node = blockIdx.x * (blockDim.x >> 6) + (threadIdx.x >> 6);
    int lane = threadIdx.x & 63;
    if (node >= n) return;
    int s = offsets[node];
    int e = offsets[node + 1];
    float a0 = bias[lane], a1 = 0.f, a2 = 0.f, a3 = 0.f;
    int j = s;
    for (; j + 4 <= e; j += 4) {
        int2 p0 = csr[j], p1 = csr[j + 1], p2 = csr[j + 2], p3 = csr[j + 3];
        a0 = fmaf(__half2float(h[(size_t)p0.x * 64 + lane]), __int_as_float(p0.y), a0);
        a1 = fmaf(__half2float(h[(size_t)p1.x * 64 + lane]), __int_as_float(p1.y), a1);
        a2 = fmaf(__half2float(h[(size_t)p2.x * 64 + lane]), __int_as_float(p2.y), a2);
        a3 = fmaf(__half2float(h[(size_t)p3.x * 64 + lane]), __int_as_float(p3.y), a3);
    }
    for (; j < e; ++j) {
        int2 p = csr[j];
        a0 = fmaf(__half2float(h[(size_t)p.x * 64 + lane]), __int_as_float(p.y), a0);
    }
    out[(size_t)node * 64 + lane] = (a0 + a1) + (a2 + a3);
}

extern "C" void kernel_launch(void* const* d_in, const int* in_sizes, int n_in,
                              void* d_out, int out_size, void* d_ws, size_t ws_size,
                              hipStream_t stream) {
    const float* x  = (const float*)d_in[0];
    const int*   ei = (const int*)d_in[1];
    const float* ew = (const float*)d_in[2];
    const float* W1 = (const float*)d_in[3];
    const float* b1 = (const float*)d_in[4];
    const float* W2 = (const float*)d_in[5];
    const float* b2 = (const float*)d_in[6];
    float* out = (float*)d_out;
    char*  ws  = (char*)d_ws;

    const int* rows = ei;
    const int* cols = ei + N_EDGES;

    // ---- workspace (byte offsets) ----
    int2*     csr      = (int2*)(ws + 0);                      // 12,800,000 (row+norm packed)
    unsigned long long* pkA = (unsigned long long*)(ws + 12800000);  // 12,800,000 [dies at fill]
    unsigned long long* pkR = (unsigned long long*)(ws + 25600000);  // 12,800,000 [dies at deg_reduce]
    __half*   h1       = (__half*)(ws + 12800000);             // 12,800,000 fp16 (over pkA)
    __half*   h2       = (__half*)(ws + 25600000);             // 12,800,000 fp16 (over pkR)
    int*      MC       = (int*)(ws + 38400000);                // 800,768
    int*      MCs      = (int*)(ws + 39250000);                // 800,772
    int*      MR       = (int*)(ws + 40100000);                // 800,768
    int*      MRs      = (int*)(ws + 40950000);                // 800,772
    int*      partials = (int*)(ws + 41800000);                // 1,024
    int*      offsets  = (int*)(ws + 41810000);                // 400,004
    float*    dis      = (float*)(ws + 42220000);              // 400,000

    const int TPB = 256;
    const int n2  = NB * NBLK;                   // 200,192
    const int nSB2 = (n2 + 1023) / 1024;         // 196

    // 1) per-block bucket histograms
    count_kernel<<<NBLK, TPB, 0, stream>>>(rows, cols, MC, MR);

    // 2) scan both matrices
    block_sum_kernel<<<nSB2, 256, 0, stream>>>(MC, partials, n2);
    scan_partials_kernel<<<1, 256, 0, stream>>>(partials, nSB2);
    scan_final_kernel<<<nSB2, 256, 0, stream>>>(MC, partials, MCs, n2);
    block_sum_kernel<<<nSB2, 256, 0, stream>>>(MR, partials, n2);
    scan_partials_kernel<<<1, 256, 0, stream>>>(partials, nSB2);
    scan_final_kernel<<<nSB2, 256, 0, stream>>>(MR, partials, MRs, n2);

    // 3) bin edges into payloads
    scatter_kernel<<<NBLK, TPB, 0, stream>>>(rows, cols, ew, MCs, MRs, pkA, pkR);

    // 4) deg -> dis
    deg_reduce_kernel<<<NB, TPB, 0, stream>>>(pkR, MRs, dis);

    // 5) per-node offsets + packed CSR fill
    fill_kernel<<<NB, TPB, 0, stream>>>(pkA, MCs, dis, csr, offsets);

    // 6) h1(fp16) = x @ W1 (writes over dead pkA)
    gemm1_kernel<<<N_NODES / 32, 256, 0, stream>>>(x, W1, h1);

    // 7) conv1 + b1 + relu + @W2 fused -> h2(fp16) (writes over dead pkR)
    gather1_fused_kernel<<<N_NODES / 8, 512, 0, stream>>>(
        h1, csr, offsets, b1, W2, h2, N_NODES);

    // 8) conv2 + b2 -> out (fp32 final)
    gather_conv2_kernel<<<(N_NODES + 3) / 4, TPB, 0, stream>>>(
        h2, csr, offsets, b2, out, N_NODES);
}

// Round 8
// 255.029 us; speedup vs baseline: 4.2513x; 1.2828x over previous
//
#include <hip/hip_runtime.h>
#include <hip/hip_fp16.h>

#define N_NODES 100000
#define N_EDGES 1600000
#define IN_DIM 128
#define HID_DIM 64
#define OUT_DIM 64
#define NB 391      // node buckets of 256: ceil(100000/256)
#define NBLK 512    // edge-chunk blocks
#define CHUNK 3125  // 512*3125 = 1,600,000

// ============ count: per-block LDS histograms by col-bucket and row-bucket ============
__global__ void count_kernel(const int* __restrict__ rows, const int* __restrict__ cols,
                             int* __restrict__ MC, int* __restrict__ MR) {
    __shared__ unsigned hc[NB], hr[NB];
    for (int i = threadIdx.x; i < NB; i += 256) { hc[i] = 0; hr[i] = 0; }
    __syncthreads();
    const int s = blockIdx.x * CHUNK;
    const int e = min(s + CHUNK, N_EDGES);
    for (int i = s + threadIdx.x; i < e; i += 256) {
        atomicAdd(&hr[rows[i] >> 8], 1u);
        atomicAdd(&hc[cols[i] >> 8], 1u);
    }
    __syncthreads();
    for (int i = threadIdx.x; i < NB; i += 256) {
        MC[i * NBLK + blockIdx.x] = (int)hc[i];
        MR[i * NBLK + blockIdx.x] = (int)hr[i];
    }
}

// ============ exclusive scan (3 kernels) ============
__global__ void block_sum_kernel(const int* __restrict__ counts, int* __restrict__ partials, int n) {
    __shared__ int sh[256];
    int base = blockIdx.x * 1024;
    int s = 0;
    for (int i = threadIdx.x; i < 1024; i += 256) {
        int idx = base + i;
        s += (idx < n) ? counts[idx] : 0;
    }
    sh[threadIdx.x] = s;
    __syncthreads();
    for (int off = 128; off > 0; off >>= 1) {
        if (threadIdx.x < off) sh[threadIdx.x] += sh[threadIdx.x + off];
        __syncthreads();
    }
    if (threadIdx.x == 0) partials[blockIdx.x] = sh[0];
}

__global__ void scan_partials_kernel(int* __restrict__ p, int nb) {
    __shared__ int sh[256];
    int t = threadIdx.x;
    int v = (t < nb) ? p[t] : 0;
    sh[t] = v;
    __syncthreads();
    for (int off = 1; off < 256; off <<= 1) {
        int add = (t >= off) ? sh[t - off] : 0;
        __syncthreads();
        sh[t] += add;
        __syncthreads();
    }
    if (t < nb) p[t] = sh[t] - v;  // exclusive
}

__global__ void scan_final_kernel(const int* __restrict__ counts, const int* __restrict__ partials,
                                  int* __restrict__ offsets, int n) {
    __shared__ int sh[256];
    int t = threadIdx.x;
    int idx0 = blockIdx.x * 1024 + t * 4;
    int v[4];
    int s = 0;
#pragma unroll
    for (int j = 0; j < 4; ++j) {
        int id = idx0 + j;
        v[j] = (id < n) ? counts[id] : 0;
        s += v[j];
    }
    sh[t] = s;
    __syncthreads();
    for (int off = 1; off < 256; off <<= 1) {
        int add = (t >= off) ? sh[t - off] : 0;
        __syncthreads();
        sh[t] += add;
        __syncthreads();
    }
    int run = sh[t] - s + partials[blockIdx.x];
#pragma unroll
    for (int j = 0; j < 4; ++j) {
        int id = idx0 + j;
        if (id < n) offsets[id] = run;
        run += v[j];
    }
    if (idx0 <= n - 1 && n - 1 < idx0 + 4) offsets[n] = run;
}

// ============ scatter: bin edges by col-bucket (pkA) and row-bucket (pkR) ============
__global__ void scatter_kernel(const int* __restrict__ rows, const int* __restrict__ cols,
                               const float* __restrict__ w, const int* __restrict__ MCs,
                               const int* __restrict__ MRs,
                               unsigned long long* __restrict__ pkA,
                               unsigned long long* __restrict__ pkR) {
    __shared__ unsigned curC[NB], curR[NB];
    for (int i = threadIdx.x; i < NB; i += 256) {
        curC[i] = (unsigned)MCs[i * NBLK + blockIdx.x];
        curR[i] = (unsigned)MRs[i * NBLK + blockIdx.x];
    }
    __syncthreads();
    const int s = blockIdx.x * CHUNK;
    const int e = min(s + CHUNK, N_EDGES);
    for (int i = s + threadIdx.x; i < e; i += 256) {
        int r = rows[i], c = cols[i];
        unsigned wb = __float_as_uint(w[i]);
        unsigned pA = atomicAdd(&curC[c >> 8], 1u);  // LDS
        pkA[pA] = ((unsigned long long)wb << 32) | (unsigned)(((c & 255) << 17) | r);
        unsigned pR = atomicAdd(&curR[r >> 8], 1u);  // LDS
        pkR[pR] = ((unsigned long long)wb << 32) | (unsigned)(r & 255);
    }
}

// ============ deg reduce: block per row-bucket, LDS accumulation -> dis ============
__global__ void deg_reduce_kernel(const unsigned long long* __restrict__ pkR,
                                  const int* __restrict__ MRs, float* __restrict__ dis) {
    __shared__ float acc[256];
    const int b = blockIdx.x;
    acc[threadIdx.x] = 0.f;
    __syncthreads();
    const int s = MRs[b * NBLK];
    const int e = MRs[(b + 1) * NBLK];
    for (int i = s + threadIdx.x; i < e; i += 256) {
        unsigned long long p = pkR[i];
        atomicAdd(&acc[(unsigned)p & 255u], __uint_as_float((unsigned)(p >> 32)));  // LDS
    }
    __syncthreads();
    int node = b * 256 + threadIdx.x;
    if (node < N_NODES) {
        float d = acc[threadIdx.x];
        dis[node] = d > 0.f ? rsqrtf(fmaxf(d, 1e-12f)) : 0.f;
    }
}

// ============ fill: block per col-bucket; LDS count+scan -> offsets + CSR(int2) ============
__global__ void fill_kernel(const unsigned long long* __restrict__ pkA,
                            const int* __restrict__ MCs, const float* __restrict__ dis,
                            int2* __restrict__ csr, int* __restrict__ offsets) {
    __shared__ unsigned hist[256];
    __shared__ unsigned excl[256];
    const int b = blockIdx.x;
    const int t = threadIdx.x;
    hist[t] = 0;
    __syncthreads();
    const int s = MCs[b * NBLK];
    const int e = MCs[(b + 1) * NBLK];
    for (int i = s + t; i < e; i += 256) {
        unsigned lo = (unsigned)pkA[i];
        atomicAdd(&hist[(lo >> 17) & 255u], 1u);  // LDS
    }
    __syncthreads();
    unsigned v = hist[t];
    excl[t] = v;
    __syncthreads();
    for (int off = 1; off < 256; off <<= 1) {
        unsigned add = (t >= off) ? excl[t - off] : 0;
        __syncthreads();
        excl[t] += add;
        __syncthreads();
    }
    unsigned my = excl[t] - v + (unsigned)s;
    int node = b * 256 + t;
    if (node <= N_NODES) offsets[node] = (int)my;
    hist[t] = my;  // reuse as cursor
    __syncthreads();
    for (int i = s + t; i < e; i += 256) {
        unsigned long long p = pkA[i];
        unsigned lo = (unsigned)p;
        unsigned cl = (lo >> 17) & 255u;
        int r = (int)(lo & 0x1FFFFu);
        unsigned pos = atomicAdd(&hist[cl], 1u);  // LDS
        int c = (b << 8) + (int)cl;
        float nv = dis[r] * __uint_as_float((unsigned)(p >> 32)) * dis[c];
        csr[pos] = make_int2(r, __float_as_int(nv));
    }
}

// ============ GEMM1: h1[100000,64](fp16) = A[100000,128] @ W[128,64] ============
__global__ __launch_bounds__(256) void gemm1_kernel(
        const float* __restrict__ A, const float* __restrict__ W, __half* __restrict__ out) {
    __shared__ float Al[32 * 128];   // 16 KB
    __shared__ float Wl[128 * 64];   // 32 KB
    const int tid = threadIdx.x;
    const int row0 = blockIdx.x * 32;

    const float4* wg = (const float4*)W;
    float4* wl = (float4*)Wl;
#pragma unroll
    for (int i = 0; i < 8; ++i) wl[tid + i * 256] = wg[tid + i * 256];
    const float4* ag = (const float4*)(A + (size_t)row0 * 128);
    float4* al4 = (float4*)Al;
#pragma unroll
    for (int i = 0; i < 4; ++i) al4[tid + i * 256] = ag[tid + i * 256];
    __syncthreads();

    const int col = tid & 63;
    const int rg  = tid >> 6;
    const float* al = Al + rg * 8 * 128;

    float acc[8];
#pragma unroll
    for (int i = 0; i < 8; ++i) acc[i] = 0.f;

    for (int k = 0; k < 128; k += 4) {
        float w0 = Wl[(k + 0) * 64 + col];
        float w1 = Wl[(k + 1) * 64 + col];
        float w2 = Wl[(k + 2) * 64 + col];
        float w3 = Wl[(k + 3) * 64 + col];
#pragma unroll
        for (int i = 0; i < 8; ++i) {
            const float4 a = *reinterpret_cast<const float4*>(&al[i * 128 + k]);
            acc[i] = fmaf(a.x, w0, acc[i]);
            acc[i] = fmaf(a.y, w1, acc[i]);
            acc[i] = fmaf(a.z, w2, acc[i]);
            acc[i] = fmaf(a.w, w3, acc[i]);
        }
    }
    __half* op = out + (size_t)(row0 + rg * 8) * 64 + col;
#pragma unroll
    for (int i = 0; i < 8; ++i) op[(size_t)i * 64] = __float2half(acc[i]);
}

// ============ vectorized gather: one wave per node, 8B/lane, 4 edges per load ============
// lane = 16*g + q : edge-slot g in [0,4), channel-quad q in [0,16).
// Per iteration: 2 h-loads cover 8 edges (8 cache lines in flight / 4 load instrs).
// Cross-slot combine: shfl_xor 16/32. BIAS_RELU=1: += bias, relu (conv1).
template <int BIAS_RELU>
__global__ __launch_bounds__(512) void gather_vec_kernel(
        const __half* __restrict__ h, const int2* __restrict__ csr,
        const int* __restrict__ offsets, const float* __restrict__ bias,
        __half* __restrict__ outh, int n) {
    int node = blockIdx.x * 8 + (threadIdx.x >> 6);
    int lane = threadIdx.x & 63;
    int q = lane & 15;
    int g = lane >> 4;
    if (node >= n) return;
    int s = offsets[node];
    int e = offsets[node + 1];

    float ax = 0.f, ay = 0.f, az = 0.f, aw = 0.f;
    for (int j = s; j < e; j += 8) {
        int eA = j + g;
        int eB = j + 4 + g;
        int2 pA = csr[min(eA, e - 1)];
        int2 pB = csr[min(eB, e - 1)];
        uint2 uA = *reinterpret_cast<const uint2*>(h + ((size_t)pA.x << 6) + (q << 2));
        uint2 uB = *reinterpret_cast<const uint2*>(h + ((size_t)pB.x << 6) + (q << 2));
        float nA = (eA < e) ? __int_as_float(pA.y) : 0.f;
        float nB = (eB < e) ? __int_as_float(pB.y) : 0.f;
        float2 a0 = __half22float2(__builtin_bit_cast(__half2, uA.x));
        float2 a1 = __half22float2(__builtin_bit_cast(__half2, uA.y));
        float2 b0 = __half22float2(__builtin_bit_cast(__half2, uB.x));
        float2 b1v = __half22float2(__builtin_bit_cast(__half2, uB.y));
        ax = fmaf(a0.x, nA, ax); ay = fmaf(a0.y, nA, ay);
        az = fmaf(a1.x, nA, az); aw = fmaf(a1.y, nA, aw);
        ax = fmaf(b0.x, nB, ax); ay = fmaf(b0.y, nB, ay);
        az = fmaf(b1v.x, nB, az); aw = fmaf(b1v.y, nB, aw);
    }
    // combine the 4 edge-slots
    ax += __shfl_xor(ax, 16); ay += __shfl_xor(ay, 16);
    az += __shfl_xor(az, 16); aw += __shfl_xor(aw, 16);
    ax += __shfl_xor(ax, 32); ay += __shfl_xor(ay, 32);
    az += __shfl_xor(az, 32); aw += __shfl_xor(aw, 32);

    if (BIAS_RELU) {
        const float4 bv = *reinterpret_cast<const float4*>(bias + (q << 2));
        ax = fmaxf(ax + bv.x, 0.f); ay = fmaxf(ay + bv.y, 0.f);
        az = fmaxf(az + bv.z, 0.f); aw = fmaxf(aw + bv.w, 0.f);
    }
    if (g == 0) {
        __half2 o0 = __float22half2_rn(make_float2(ax, ay));
        __half2 o1 = __float22half2_rn(make_float2(az, aw));
        uint2 u = make_uint2(__builtin_bit_cast(unsigned, o0), __builtin_bit_cast(unsigned, o1));
        *reinterpret_cast<uint2*>(outh + ((size_t)node << 6) + (q << 2)) = u;
    }
}

// ============ GEMM2: out[100000,64](fp32) = G[100000,64](fp16) @ W2[64,64] + b2 ============
__global__ __launch_bounds__(256) void gemm2_kernel(
        const __half* __restrict__ G, const float* __restrict__ W,
        const float* __restrict__ b, float* __restrict__ out) {
    __shared__ float Al[32 * 64];   // 8 KB
    __shared__ float Wl[64 * 64];   // 16 KB
    const int tid = threadIdx.x;
    const int row0 = blockIdx.x * 32;

    const float4* wg = (const float4*)W;
    float4* wl = (float4*)Wl;
#pragma unroll
    for (int i = 0; i < 4; ++i) wl[tid + i * 256] = wg[tid + i * 256];
    {   // stage A-tile: 2048 fp16 = 256 x uint4, convert to fp32
        const uint4* ag = (const uint4*)(G + ((size_t)row0 << 6));
        uint4 u = ag[tid];
        float2 f0 = __half22float2(__builtin_bit_cast(__half2, u.x));
        float2 f1 = __half22float2(__builtin_bit_cast(__half2, u.y));
        float2 f2 = __half22float2(__builtin_bit_cast(__half2, u.z));
        float2 f3 = __half22float2(__builtin_bit_cast(__half2, u.w));
        float4* d = (float4*)(Al + tid * 8);
        d[0] = make_float4(f0.x, f0.y, f1.x, f1.y);
        d[1] = make_float4(f2.x, f2.y, f3.x, f3.y);
    }
    __syncthreads();

    const int col = tid & 63;
    const int rg  = tid >> 6;
    const float* al = Al + rg * 8 * 64;

    float acc[8];
#pragma unroll
    for (int i = 0; i < 8; ++i) acc[i] = 0.f;

    for (int k = 0; k < 64; k += 4) {
        float w0 = Wl[(k + 0) * 64 + col];
        float w1 = Wl[(k + 1) * 64 + col];
        float w2 = Wl[(k + 2) * 64 + col];
        float w3 = Wl[(k + 3) * 64 + col];
#pragma unroll
        for (int i = 0; i < 8; ++i) {
            const float4 a = *reinterpret_cast<const float4*>(&al[i * 64 + k]);
            acc[i] = fmaf(a.x, w0, acc[i]);
            acc[i] = fmaf(a.y, w1, acc[i]);
            acc[i] = fmaf(a.z, w2, acc[i]);
            acc[i] = fmaf(a.w, w3, acc[i]);
        }
    }
    float bb = b[col];
    float* op = out + (size_t)(row0 + rg * 8) * 64 + col;
#pragma unroll
    for (int i = 0; i < 8; ++i) op[(size_t)i * 64] = acc[i] + bb;
}

extern "C" void kernel_launch(void* const* d_in, const int* in_sizes, int n_in,
                              void* d_out, int out_size, void* d_ws, size_t ws_size,
                              hipStream_t stream) {
    const float* x  = (const float*)d_in[0];
    const int*   ei = (const int*)d_in[1];
    const float* ew = (const float*)d_in[2];
    const float* W1 = (const float*)d_in[3];
    const float* b1 = (const float*)d_in[4];
    const float* W2 = (const float*)d_in[5];
    const float* b2 = (const float*)d_in[6];
    float* out = (float*)d_out;
    char*  ws  = (char*)d_ws;

    const int* rows = ei;
    const int* cols = ei + N_EDGES;

    // ---- workspace (byte offsets) ----
    int2*     csr      = (int2*)(ws + 0);                      // 12,800,000
    unsigned long long* pkA = (unsigned long long*)(ws + 12800000);  // [dies at fill]
    unsigned long long* pkR = (unsigned long long*)(ws + 25600000);  // [dies at deg_reduce]
    __half*   h1       = (__half*)(ws + 12800000);             // fp16, over pkA [dies at gather2]
    __half*   g        = (__half*)(ws + 12800000);             // fp16, over h1 (gather2 out)
    __half*   t        = (__half*)(ws + 25600000);             // fp16, over pkR (gather1 out)
    int*      MC       = (int*)(ws + 38400000);                // 800,768
    int*      MCs      = (int*)(ws + 39250000);                // 800,772
    int*      MR       = (int*)(ws + 40100000);                // 800,768
    int*      MRs      = (int*)(ws + 40950000);                // 800,772
    int*      partials = (int*)(ws + 41800000);                // 1,024
    int*      offsets  = (int*)(ws + 41810000);                // 400,004
    float*    dis      = (float*)(ws + 42220000);              // 400,000

    const int TPB = 256;
    const int n2  = NB * NBLK;                   // 200,192
    const int nSB2 = (n2 + 1023) / 1024;         // 196

    // 1) per-block bucket histograms
    count_kernel<<<NBLK, TPB, 0, stream>>>(rows, cols, MC, MR);

    // 2) scan both matrices
    block_sum_kernel<<<nSB2, 256, 0, stream>>>(MC, partials, n2);
    scan_partials_kernel<<<1, 256, 0, stream>>>(partials, nSB2);
    scan_final_kernel<<<nSB2, 256, 0, stream>>>(MC, partials, MCs, n2);
    block_sum_kernel<<<nSB2, 256, 0, stream>>>(MR, partials, n2);
    scan_partials_kernel<<<1, 256, 0, stream>>>(partials, nSB2);
    scan_final_kernel<<<nSB2, 256, 0, stream>>>(MR, partials, MRs, n2);

    // 3) bin edges into payloads
    scatter_kernel<<<NBLK, TPB, 0, stream>>>(rows, cols, ew, MCs, MRs, pkA, pkR);

    // 4) deg -> dis
    deg_reduce_kernel<<<NB, TPB, 0, stream>>>(pkR, MRs, dis);

    // 5) per-node offsets + packed CSR fill
    fill_kernel<<<NB, TPB, 0, stream>>>(pkA, MCs, dis, csr, offsets);

    // 6) h1(fp16) = x @ W1 (over dead pkA)
    gemm1_kernel<<<N_NODES / 32, 256, 0, stream>>>(x, W1, h1);

    // 7) t = relu(gather(h1) + b1)  (over dead pkR)
    gather_vec_kernel<1><<<N_NODES / 8, 512, 0, stream>>>(h1, csr, offsets, b1, t, N_NODES);

    // 8) g = gather(t)  (over dead h1; W2 deferred — commutes with the weighted sum)
    gather_vec_kernel<0><<<N_NODES / 8, 512, 0, stream>>>(t, csr, offsets, b1, g, N_NODES);

    // 9) out = g @ W2 + b2 (dense, coalesced)
    gemm2_kernel<<<N_NODES / 32, 256, 0, stream>>>(g, W2, b2, out);
}

// Round 9
// 232.346 us; speedup vs baseline: 4.6663x; 1.0976x over previous
//
#include <hip/hip_runtime.h>
#include <hip/hip_fp16.h>

#define N_NODES 100000
#define N_EDGES 1600000
#define IN_DIM 128
#define HID_DIM 64
#define OUT_DIM 64
#define NBKT 196    // node buckets of 512: ceil(100000/512)
#define BSH 9       // bucket shift
#define BMSK 511
#define NBLK 512    // edge-chunk blocks
#define CHUNK 3125  // 512*3125 = 1,600,000
#define MROW (NBKT * NBLK)   // 100,352: start of row-region in combined count matrix

// ============ count: per-block LDS histograms by col-bucket and row-bucket ============
// Writes into ONE combined matrix M: col-region [0, MROW), row-region [MROW, 2*MROW).
__global__ void count_kernel(const int* __restrict__ rows, const int* __restrict__ cols,
                             int* __restrict__ M) {
    __shared__ unsigned hc[NBKT], hr[NBKT];
    for (int i = threadIdx.x; i < NBKT; i += 256) { hc[i] = 0; hr[i] = 0; }
    __syncthreads();
    const int s = blockIdx.x * CHUNK;
    const int e = min(s + CHUNK, N_EDGES);
    for (int i = s + threadIdx.x; i < e; i += 256) {
        atomicAdd(&hr[rows[i] >> BSH], 1u);
        atomicAdd(&hc[cols[i] >> BSH], 1u);
    }
    __syncthreads();
    for (int i = threadIdx.x; i < NBKT; i += 256) {
        M[i * NBLK + blockIdx.x] = (int)hc[i];
        M[MROW + i * NBLK + blockIdx.x] = (int)hr[i];
    }
}

// ============ exclusive scan (3 kernels), one chain over the combined matrix ============
__global__ void block_sum_kernel(const int* __restrict__ counts, int* __restrict__ partials, int n) {
    __shared__ int sh[256];
    int base = blockIdx.x * 1024;
    int s = 0;
    for (int i = threadIdx.x; i < 1024; i += 256) {
        int idx = base + i;
        s += (idx < n) ? counts[idx] : 0;
    }
    sh[threadIdx.x] = s;
    __syncthreads();
    for (int off = 128; off > 0; off >>= 1) {
        if (threadIdx.x < off) sh[threadIdx.x] += sh[threadIdx.x + off];
        __syncthreads();
    }
    if (threadIdx.x == 0) partials[blockIdx.x] = sh[0];
}

__global__ void scan_partials_kernel(int* __restrict__ p, int nb) {
    __shared__ int sh[256];
    int t = threadIdx.x;
    int v = (t < nb) ? p[t] : 0;
    sh[t] = v;
    __syncthreads();
    for (int off = 1; off < 256; off <<= 1) {
        int add = (t >= off) ? sh[t - off] : 0;
        __syncthreads();
        sh[t] += add;
        __syncthreads();
    }
    if (t < nb) p[t] = sh[t] - v;  // exclusive
}

__global__ void scan_final_kernel(const int* __restrict__ counts, const int* __restrict__ partials,
                                  int* __restrict__ offsets, int n) {
    __shared__ int sh[256];
    int t = threadIdx.x;
    int idx0 = blockIdx.x * 1024 + t * 4;
    int v[4];
    int s = 0;
#pragma unroll
    for (int j = 0; j < 4; ++j) {
        int id = idx0 + j;
        v[j] = (id < n) ? counts[id] : 0;
        s += v[j];
    }
    sh[t] = s;
    __syncthreads();
    for (int off = 1; off < 256; off <<= 1) {
        int add = (t >= off) ? sh[t - off] : 0;
        __syncthreads();
        sh[t] += add;
        __syncthreads();
    }
    int run = sh[t] - s + partials[blockIdx.x];
#pragma unroll
    for (int j = 0; j < 4; ++j) {
        int id = idx0 + j;
        if (id < n) offsets[id] = run;
        run += v[j];
    }
    if (idx0 <= n - 1 && n - 1 < idx0 + 4) offsets[n] = run;
}

// ============ scatter: bin edges into combined payload pk (col-region, row-region) ============
__global__ void scatter_kernel(const int* __restrict__ rows, const int* __restrict__ cols,
                               const float* __restrict__ w, const int* __restrict__ Ms,
                               unsigned long long* __restrict__ pk) {
    __shared__ unsigned curC[NBKT], curR[NBKT];
    for (int i = threadIdx.x; i < NBKT; i += 256) {
        curC[i] = (unsigned)Ms[i * NBLK + blockIdx.x];
        curR[i] = (unsigned)Ms[MROW + i * NBLK + blockIdx.x];  // values already offset by 1.6M
    }
    __syncthreads();
    const int s = blockIdx.x * CHUNK;
    const int e = min(s + CHUNK, N_EDGES);
    for (int i = s + threadIdx.x; i < e; i += 256) {
        int r = rows[i], c = cols[i];
        unsigned wb = __float_as_uint(w[i]);
        unsigned pA = atomicAdd(&curC[c >> BSH], 1u);  // LDS
        pk[pA] = ((unsigned long long)wb << 32) | (unsigned)(((c & BMSK) << 17) | r);
        unsigned pR = atomicAdd(&curR[r >> BSH], 1u);  // LDS
        pk[pR] = ((unsigned long long)wb << 32) | (unsigned)(r & BMSK);
    }
}

// ============ deg reduce: block per row-bucket (512 nodes), LDS accumulation -> dis ============
__global__ void deg_reduce_kernel(const unsigned long long* __restrict__ pk,
                                  const int* __restrict__ Ms, float* __restrict__ dis) {
    __shared__ float acc[512];
    const int b = blockIdx.x;
    const int t = threadIdx.x;
    acc[t] = 0.f; acc[t + 256] = 0.f;
    __syncthreads();
    const int s = Ms[MROW + b * NBLK];
    const int e = Ms[MROW + (b + 1) * NBLK];   // b=NBKT-1 -> Ms[2*MROW] = 3.2M total
    for (int i = s + t; i < e; i += 256) {
        unsigned long long p = pk[i];
        atomicAdd(&acc[(unsigned)p & (unsigned)BMSK], __uint_as_float((unsigned)(p >> 32)));
    }
    __syncthreads();
#pragma unroll
    for (int k = 0; k < 2; ++k) {
        int node = b * 512 + t + k * 256;
        if (node < N_NODES) {
            float d = acc[t + k * 256];
            dis[node] = d > 0.f ? rsqrtf(fmaxf(d, 1e-12f)) : 0.f;
        }
    }
}

// ============ fill: block per col-bucket (512 nodes); LDS count+scan -> offsets + CSR ============
__global__ void fill_kernel(const unsigned long long* __restrict__ pk,
                            const int* __restrict__ Ms, const float* __restrict__ dis,
                            int2* __restrict__ csr, int* __restrict__ offsets) {
    __shared__ unsigned hist[512];
    __shared__ unsigned pairs[256];
    const int b = blockIdx.x;
    const int t = threadIdx.x;
    hist[t] = 0; hist[t + 256] = 0;
    __syncthreads();
    const int s = Ms[b * NBLK];
    const int e = Ms[(b + 1) * NBLK];          // b=NBKT-1 -> Ms[MROW] = 1.6M
    for (int i = s + t; i < e; i += 256) {
        unsigned lo = (unsigned)pk[i];
        atomicAdd(&hist[(lo >> 17) & (unsigned)BMSK], 1u);
    }
    __syncthreads();
    unsigned h0 = hist[2 * t], h1 = hist[2 * t + 1];
    pairs[t] = h0 + h1;
    __syncthreads();
    for (int off = 1; off < 256; off <<= 1) {
        unsigned add = (t >= off) ? pairs[t - off] : 0;
        __syncthreads();
        pairs[t] += add;
        __syncthreads();
    }
    unsigned P = pairs[t] - (h0 + h1) + (unsigned)s;  // exclusive, global base
    unsigned e0 = P, e1 = P + h0;
    int n0 = b * 512 + 2 * t;
    int n1 = n0 + 1;
    if (n0 <= N_NODES) offsets[n0] = (int)e0;
    if (n1 <= N_NODES) offsets[n1] = (int)e1;
    hist[2 * t] = e0; hist[2 * t + 1] = e1;   // reuse as cursors
    __syncthreads();
    for (int i = s + t; i < e; i += 256) {
        unsigned long long p = pk[i];
        unsigned lo = (unsigned)p;
        unsigned cl = (lo >> 17) & (unsigned)BMSK;
        int r = (int)(lo & 0x1FFFFu);
        unsigned pos = atomicAdd(&hist[cl], 1u);  // LDS
        int c = (b << BSH) + (int)cl;
        float nv = dis[r] * __uint_as_float((unsigned)(p >> 32)) * dis[c];
        csr[pos] = make_int2(r, __float_as_int(nv));
    }
}

// ============ GEMM1: h1[100000,64](fp16) = A[100000,128] @ W[128,64] ============
__global__ __launch_bounds__(256) void gemm1_kernel(
        const float* __restrict__ A, const float* __restrict__ W, __half* __restrict__ out) {
    __shared__ float Al[32 * 128];   // 16 KB
    __shared__ float Wl[128 * 64];   // 32 KB
    const int tid = threadIdx.x;
    const int row0 = blockIdx.x * 32;

    const float4* wg = (const float4*)W;
    float4* wl = (float4*)Wl;
#pragma unroll
    for (int i = 0; i < 8; ++i) wl[tid + i * 256] = wg[tid + i * 256];
    const float4* ag = (const float4*)(A + (size_t)row0 * 128);
    float4* al4 = (float4*)Al;
#pragma unroll
    for (int i = 0; i < 4; ++i) al4[tid + i * 256] = ag[tid + i * 256];
    __syncthreads();

    const int col = tid & 63;
    const int rg  = tid >> 6;
    const float* al = Al + rg * 8 * 128;

    float acc[8];
#pragma unroll
    for (int i = 0; i < 8; ++i) acc[i] = 0.f;

    for (int k = 0; k < 128; k += 4) {
        float w0 = Wl[(k + 0) * 64 + col];
        float w1 = Wl[(k + 1) * 64 + col];
        float w2 = Wl[(k + 2) * 64 + col];
        float w3 = Wl[(k + 3) * 64 + col];
#pragma unroll
        for (int i = 0; i < 8; ++i) {
            const float4 a = *reinterpret_cast<const float4*>(&al[i * 128 + k]);
            acc[i] = fmaf(a.x, w0, acc[i]);
            acc[i] = fmaf(a.y, w1, acc[i]);
            acc[i] = fmaf(a.z, w2, acc[i]);
            acc[i] = fmaf(a.w, w3, acc[i]);
        }
    }
    __half* op = out + (size_t)(row0 + rg * 8) * 64 + col;
#pragma unroll
    for (int i = 0; i < 8; ++i) op[(size_t)i * 64] = __float2half(acc[i]);
}

// ============ gather: one wave per node, 16B/lane (half8), 16 edges per iteration ============
// lane = 8*g + q : edge-slot g in [0,8), channel-octet q in [0,8).
// Per iteration: 2 h-loads + 2 csr-loads per lane cover 16 edges (16 lines in flight).
template <int BIAS_RELU>
__global__ __launch_bounds__(512) void gather_vec_kernel(
        const __half* __restrict__ h, const int2* __restrict__ csr,
        const int* __restrict__ offsets, const float* __restrict__ bias,
        __half* __restrict__ outh, int n) {
    int node = blockIdx.x * 8 + (threadIdx.x >> 6);
    int lane = threadIdx.x & 63;
    int q = lane & 7;
    int g = lane >> 3;
    int s = offsets[node];
    int e = offsets[node + 1];

    float a0 = 0.f, a1 = 0.f, a2 = 0.f, a3 = 0.f, a4 = 0.f, a5 = 0.f, a6 = 0.f, a7 = 0.f;
    for (int j = s; j < e; j += 16) {
        int eA = j + g;
        int eB = j + 8 + g;
        int2 pA = csr[min(eA, e - 1)];
        int2 pB = csr[min(eB, e - 1)];
        float nA = (eA < e) ? __int_as_float(pA.y) : 0.f;
        float nB = (eB < e) ? __int_as_float(pB.y) : 0.f;
        uint4 uA = *reinterpret_cast<const uint4*>(h + ((size_t)pA.x << 6) + (q << 3));
        uint4 uB = *reinterpret_cast<const uint4*>(h + ((size_t)pB.x << 6) + (q << 3));
        float2 f;
        f = __half22float2(__builtin_bit_cast(__half2, uA.x)); a0 = fmaf(f.x, nA, a0); a1 = fmaf(f.y, nA, a1);
        f = __half22float2(__builtin_bit_cast(__half2, uA.y)); a2 = fmaf(f.x, nA, a2); a3 = fmaf(f.y, nA, a3);
        f = __half22float2(__builtin_bit_cast(__half2, uA.z)); a4 = fmaf(f.x, nA, a4); a5 = fmaf(f.y, nA, a5);
        f = __half22float2(__builtin_bit_cast(__half2, uA.w)); a6 = fmaf(f.x, nA, a6); a7 = fmaf(f.y, nA, a7);
        f = __half22float2(__builtin_bit_cast(__half2, uB.x)); a0 = fmaf(f.x, nB, a0); a1 = fmaf(f.y, nB, a1);
        f = __half22float2(__builtin_bit_cast(__half2, uB.y)); a2 = fmaf(f.x, nB, a2); a3 = fmaf(f.y, nB, a3);
        f = __half22float2(__builtin_bit_cast(__half2, uB.z)); a4 = fmaf(f.x, nB, a4); a5 = fmaf(f.y, nB, a5);
        f = __half22float2(__builtin_bit_cast(__half2, uB.w)); a6 = fmaf(f.x, nB, a6); a7 = fmaf(f.y, nB, a7);
    }
    // combine the 8 edge-slots (xor over lane bits 3,4,5)
#pragma unroll
    for (int m = 8; m <= 32; m <<= 1) {
        a0 += __shfl_xor(a0, m); a1 += __shfl_xor(a1, m);
        a2 += __shfl_xor(a2, m); a3 += __shfl_xor(a3, m);
        a4 += __shfl_xor(a4, m); a5 += __shfl_xor(a5, m);
        a6 += __shfl_xor(a6, m); a7 += __shfl_xor(a7, m);
    }
    if (BIAS_RELU) {
        const float4 b0 = *reinterpret_cast<const float4*>(bias + (q << 3));
        const float4 b1 = *reinterpret_cast<const float4*>(bias + (q << 3) + 4);
        a0 = fmaxf(a0 + b0.x, 0.f); a1 = fmaxf(a1 + b0.y, 0.f);
        a2 = fmaxf(a2 + b0.z, 0.f); a3 = fmaxf(a3 + b0.w, 0.f);
        a4 = fmaxf(a4 + b1.x, 0.f); a5 = fmaxf(a5 + b1.y, 0.f);
        a6 = fmaxf(a6 + b1.z, 0.f); a7 = fmaxf(a7 + b1.w, 0.f);
    }
    if (g == 0) {
        __half2 o0 = __float22half2_rn(make_float2(a0, a1));
        __half2 o1 = __float22half2_rn(make_float2(a2, a3));
        __half2 o2 = __float22half2_rn(make_float2(a4, a5));
        __half2 o3 = __float22half2_rn(make_float2(a6, a7));
        uint4 u = make_uint4(__builtin_bit_cast(unsigned, o0), __builtin_bit_cast(unsigned, o1),
                             __builtin_bit_cast(unsigned, o2), __builtin_bit_cast(unsigned, o3));
        *reinterpret_cast<uint4*>(outh + ((size_t)node << 6) + (q << 3)) = u;
    }
}

// ============ GEMM2: out[100000,64](fp32) = G[100000,64](fp16) @ W2[64,64] + b2 ============
__global__ __launch_bounds__(256) void gemm2_kernel(
        const __half* __restrict__ G, const float* __restrict__ W,
        const float* __restrict__ b, float* __restrict__ out) {
    __shared__ float Al[32 * 64];   // 8 KB
    __shared__ float Wl[64 * 64];   // 16 KB
    const int tid = threadIdx.x;
    const int row0 = blockIdx.x * 32;

    const float4* wg = (const float4*)W;
    float4* wl = (float4*)Wl;
#pragma unroll
    for (int i = 0; i < 4; ++i) wl[tid + i * 256] = wg[tid + i * 256];
    {
        const uint4* ag = (const uint4*)(G + ((size_t)row0 << 6));
        uint4 u = ag[tid];
        float2 f0 = __half22float2(__builtin_bit_cast(__half2, u.x));
        float2 f1 = __half22float2(__builtin_bit_cast(__half2, u.y));
        float2 f2 = __half22float2(__builtin_bit_cast(__half2, u.z));
        float2 f3 = __half22float2(__builtin_bit_cast(__half2, u.w));
        float4* d = (float4*)(Al + tid * 8);
        d[0] = make_float4(f0.x, f0.y, f1.x, f1.y);
        d[1] = make_float4(f2.x, f2.y, f3.x, f3.y);
    }
    __syncthreads();

    const int col = tid & 63;
    const int rg  = tid >> 6;
    const float* al = Al + rg * 8 * 64;

    float acc[8];
#pragma unroll
    for (int i = 0; i < 8; ++i) acc[i] = 0.f;

    for (int k = 0; k < 64; k += 4) {
        float w0 = Wl[(k + 0) * 64 + col];
        float w1 = Wl[(k + 1) * 64 + col];
        float w2 = Wl[(k + 2) * 64 + col];
        float w3 = Wl[(k + 3) * 64 + col];
#pragma unroll
        for (int i = 0; i < 8; ++i) {
            const float4 a = *reinterpret_cast<const float4*>(&al[i * 64 + k]);
            acc[i] = fmaf(a.x, w0, acc[i]);
            acc[i] = fmaf(a.y, w1, acc[i]);
            acc[i] = fmaf(a.z, w2, acc[i]);
            acc[i] = fmaf(a.w, w3, acc[i]);
        }
    }
    float bb = b[col];
    float* op = out + (size_t)(row0 + rg * 8) * 64 + col;
#pragma unroll
    for (int i = 0; i < 8; ++i) op[(size_t)i * 64] = acc[i] + bb;
}

extern "C" void kernel_launch(void* const* d_in, const int* in_sizes, int n_in,
                              void* d_out, int out_size, void* d_ws, size_t ws_size,
                              hipStream_t stream) {
    const float* x  = (const float*)d_in[0];
    const int*   ei = (const int*)d_in[1];
    const float* ew = (const float*)d_in[2];
    const float* W1 = (const float*)d_in[3];
    const float* b1 = (const float*)d_in[4];
    const float* W2 = (const float*)d_in[5];
    const float* b2 = (const float*)d_in[6];
    float* out = (float*)d_out;
    char*  ws  = (char*)d_ws;

    const int* rows = ei;
    const int* cols = ei + N_EDGES;

    // ---- workspace (byte offsets) ----
    int2*     csr      = (int2*)(ws + 0);                      // 12,800,000
    unsigned long long* pk = (unsigned long long*)(ws + 12800000);  // 25,600,000 (col|row regions)
    __half*   h1       = (__half*)(ws + 12800000);             // fp16, over col-region [dies at gather2]
    __half*   g        = (__half*)(ws + 12800000);             // fp16, over h1 (gather2 out)
    __half*   t        = (__half*)(ws + 25600000);             // fp16, over row-region (gather1 out)
    int*      M        = (int*)(ws + 38400000);                // 802,816 (combined counts)
    int*      Ms       = (int*)(ws + 39202816);                // 802,820 (scanned, +total)
    int*      partials = (int*)(ws + 40005636);                // 788
    int*      offsets  = (int*)(ws + 40006424);                // 400,004
    float*    dis      = (float*)(ws + 40406428);              // 400,000

    const int TPB = 256;
    const int n2  = 2 * MROW;                    // 200,704
    const int nSB2 = (n2 + 1023) / 1024;         // 197

    // 1) per-block bucket histograms (combined matrix)
    count_kernel<<<NBLK, TPB, 0, stream>>>(rows, cols, M);

    // 2) one scan chain over the combined matrix
    block_sum_kernel<<<nSB2, 256, 0, stream>>>(M, partials, n2);
    scan_partials_kernel<<<1, 256, 0, stream>>>(partials, nSB2);
    scan_final_kernel<<<nSB2, 256, 0, stream>>>(M, partials, Ms, n2);

    // 3) bin edges into the combined payload
    scatter_kernel<<<NBLK, TPB, 0, stream>>>(rows, cols, ew, Ms, pk);

    // 4) deg -> dis (row region)
    deg_reduce_kernel<<<NBKT, TPB, 0, stream>>>(pk, Ms, dis);

    // 5) per-node offsets + packed CSR fill (col region)
    fill_kernel<<<NBKT, TPB, 0, stream>>>(pk, Ms, dis, csr, offsets);

    // 6) h1(fp16) = x @ W1 (over dead col-region)
    gemm1_kernel<<<N_NODES / 32, 256, 0, stream>>>(x, W1, h1);

    // 7) t = relu(gather(h1) + b1)  (over dead row-region)
    gather_vec_kernel<1><<<N_NODES / 8, 512, 0, stream>>>(h1, csr, offsets, b1, t, N_NODES);

    // 8) g = gather(t)  (over dead h1; W2 deferred)
    gather_vec_kernel<0><<<N_NODES / 8, 512, 0, stream>>>(t, csr, offsets, b1, g, N_NODES);

    // 9) out = g @ W2 + b2 (dense, coalesced)
    gemm2_kernel<<<N_NODES / 32, 256, 0, stream>>>(g, W2, b2, out);
}

// Round 10
// 199.814 us; speedup vs baseline: 5.4261x; 1.1628x over previous
//
#include <hip/hip_runtime.h>
#include <hip/hip_fp16.h>

#define N_NODES 100000
#define N_EDGES 1600000
#define IN_DIM 128
#define HID_DIM 64
#define OUT_DIM 64
#define NBKT 196    // node buckets of 512: ceil(100000/512)
#define BSH 9       // bucket shift
#define BMSK 511
#define NBLK 512    // edge-chunk blocks
#define CHUNK 3125  // 512*3125 = 1,600,000
#define MROW (NBKT * NBLK)   // 100,352: start of row-region in combined count matrix

typedef _Float16 half8 __attribute__((ext_vector_type(8)));
typedef float f32x4 __attribute__((ext_vector_type(4)));

// ============ count: per-block LDS histograms by col-bucket and row-bucket ============
__global__ void count_kernel(const int* __restrict__ rows, const int* __restrict__ cols,
                             int* __restrict__ M) {
    __shared__ unsigned hc[NBKT], hr[NBKT];
    for (int i = threadIdx.x; i < NBKT; i += 256) { hc[i] = 0; hr[i] = 0; }
    __syncthreads();
    const int s = blockIdx.x * CHUNK;
    const int e = min(s + CHUNK, N_EDGES);
    for (int i = s + threadIdx.x; i < e; i += 256) {
        atomicAdd(&hr[rows[i] >> BSH], 1u);
        atomicAdd(&hc[cols[i] >> BSH], 1u);
    }
    __syncthreads();
    for (int i = threadIdx.x; i < NBKT; i += 256) {
        M[i * NBLK + blockIdx.x] = (int)hc[i];
        M[MROW + i * NBLK + blockIdx.x] = (int)hr[i];
    }
}

// ============ exclusive scan (3 kernels) ============
__global__ void block_sum_kernel(const int* __restrict__ counts, int* __restrict__ partials, int n) {
    __shared__ int sh[256];
    int base = blockIdx.x * 1024;
    int s = 0;
    for (int i = threadIdx.x; i < 1024; i += 256) {
        int idx = base + i;
        s += (idx < n) ? counts[idx] : 0;
    }
    sh[threadIdx.x] = s;
    __syncthreads();
    for (int off = 128; off > 0; off >>= 1) {
        if (threadIdx.x < off) sh[threadIdx.x] += sh[threadIdx.x + off];
        __syncthreads();
    }
    if (threadIdx.x == 0) partials[blockIdx.x] = sh[0];
}

__global__ void scan_partials_kernel(int* __restrict__ p, int nb) {
    __shared__ int sh[256];
    int t = threadIdx.x;
    int v = (t < nb) ? p[t] : 0;
    sh[t] = v;
    __syncthreads();
    for (int off = 1; off < 256; off <<= 1) {
        int add = (t >= off) ? sh[t - off] : 0;
        __syncthreads();
        sh[t] += add;
        __syncthreads();
    }
    if (t < nb) p[t] = sh[t] - v;  // exclusive
}

__global__ void scan_final_kernel(const int* __restrict__ counts, const int* __restrict__ partials,
                                  int* __restrict__ offsets, int n) {
    __shared__ int sh[256];
    int t = threadIdx.x;
    int idx0 = blockIdx.x * 1024 + t * 4;
    int v[4];
    int s = 0;
#pragma unroll
    for (int j = 0; j < 4; ++j) {
        int id = idx0 + j;
        v[j] = (id < n) ? counts[id] : 0;
        s += v[j];
    }
    sh[t] = s;
    __syncthreads();
    for (int off = 1; off < 256; off <<= 1) {
        int add = (t >= off) ? sh[t - off] : 0;
        __syncthreads();
        sh[t] += add;
        __syncthreads();
    }
    int run = sh[t] - s + partials[blockIdx.x];
#pragma unroll
    for (int j = 0; j < 4; ++j) {
        int id = idx0 + j;
        if (id < n) offsets[id] = run;
        run += v[j];
    }
    if (idx0 <= n - 1 && n - 1 < idx0 + 4) offsets[n] = run;
}

// ============ scatter: bin edges into combined payload pk ============
__global__ void scatter_kernel(const int* __restrict__ rows, const int* __restrict__ cols,
                               const float* __restrict__ w, const int* __restrict__ Ms,
                               unsigned long long* __restrict__ pk) {
    __shared__ unsigned curC[NBKT], curR[NBKT];
    for (int i = threadIdx.x; i < NBKT; i += 256) {
        curC[i] = (unsigned)Ms[i * NBLK + blockIdx.x];
        curR[i] = (unsigned)Ms[MROW + i * NBLK + blockIdx.x];
    }
    __syncthreads();
    const int s = blockIdx.x * CHUNK;
    const int e = min(s + CHUNK, N_EDGES);
    for (int i = s + threadIdx.x; i < e; i += 256) {
        int r = rows[i], c = cols[i];
        unsigned wb = __float_as_uint(w[i]);
        unsigned pA = atomicAdd(&curC[c >> BSH], 1u);  // LDS
        pk[pA] = ((unsigned long long)wb << 32) | (unsigned)(((c & BMSK) << 17) | r);
        unsigned pR = atomicAdd(&curR[r >> BSH], 1u);  // LDS
        pk[pR] = ((unsigned long long)wb << 32) | (unsigned)(r & BMSK);
    }
}

// ============ deg reduce: block per row-bucket (512 nodes) -> dis ============
__global__ void deg_reduce_kernel(const unsigned long long* __restrict__ pk,
                                  const int* __restrict__ Ms, float* __restrict__ dis) {
    __shared__ float acc[512];
    const int b = blockIdx.x;
    const int t = threadIdx.x;
    acc[t] = 0.f; acc[t + 256] = 0.f;
    __syncthreads();
    const int s = Ms[MROW + b * NBLK];
    const int e = Ms[MROW + (b + 1) * NBLK];
    for (int i = s + t; i < e; i += 256) {
        unsigned long long p = pk[i];
        atomicAdd(&acc[(unsigned)p & (unsigned)BMSK], __uint_as_float((unsigned)(p >> 32)));
    }
    __syncthreads();
#pragma unroll
    for (int k = 0; k < 2; ++k) {
        int node = b * 512 + t + k * 256;
        if (node < N_NODES) {
            float d = acc[t + k * 256];
            dis[node] = d > 0.f ? rsqrtf(fmaxf(d, 1e-12f)) : 0.f;
        }
    }
}

// ============ fill: block per col-bucket (512 nodes) -> offsets + CSR ============
__global__ void fill_kernel(const unsigned long long* __restrict__ pk,
                            const int* __restrict__ Ms, const float* __restrict__ dis,
                            int2* __restrict__ csr, int* __restrict__ offsets) {
    __shared__ unsigned hist[512];
    __shared__ unsigned pairs[256];
    const int b = blockIdx.x;
    const int t = threadIdx.x;
    hist[t] = 0; hist[t + 256] = 0;
    __syncthreads();
    const int s = Ms[b * NBLK];
    const int e = Ms[(b + 1) * NBLK];
    for (int i = s + t; i < e; i += 256) {
        unsigned lo = (unsigned)pk[i];
        atomicAdd(&hist[(lo >> 17) & (unsigned)BMSK], 1u);
    }
    __syncthreads();
    unsigned h0 = hist[2 * t], h1 = hist[2 * t + 1];
    pairs[t] = h0 + h1;
    __syncthreads();
    for (int off = 1; off < 256; off <<= 1) {
        unsigned add = (t >= off) ? pairs[t - off] : 0;
        __syncthreads();
        pairs[t] += add;
        __syncthreads();
    }
    unsigned P = pairs[t] - (h0 + h1) + (unsigned)s;
    unsigned e0 = P, e1 = P + h0;
    int n0 = b * 512 + 2 * t;
    int n1 = n0 + 1;
    if (n0 <= N_NODES) offsets[n0] = (int)e0;
    if (n1 <= N_NODES) offsets[n1] = (int)e1;
    hist[2 * t] = e0; hist[2 * t + 1] = e1;   // reuse as cursors
    __syncthreads();
    for (int i = s + t; i < e; i += 256) {
        unsigned long long p = pk[i];
        unsigned lo = (unsigned)p;
        unsigned cl = (lo >> 17) & (unsigned)BMSK;
        int r = (int)(lo & 0x1FFFFu);
        unsigned pos = atomicAdd(&hist[cl], 1u);  // LDS
        int c = (b << BSH) + (int)cl;
        float nv = dis[r] * __uint_as_float((unsigned)(p >> 32)) * dis[c];
        csr[pos] = make_int2(r, __float_as_int(nv));
    }
}

// ============ wfrag: pack W1/W2 into fp16 MFMA B-fragments ============
// Frag t (=fg*64+lane): fg = chunk*4 + ct. Lane l holds B[k][col], col=ct*16+(l&15),
// k = chunk*32 + (l>>4)*8 + j, j=0..7 -> 8 consecutive halves (16B, coalesced read).
__global__ void wfrag_kernel(const float* __restrict__ W1, const float* __restrict__ W2,
                             __half* __restrict__ F1, __half* __restrict__ F2) {
    int t = blockIdx.x * 256 + threadIdx.x;
    if (t < 1024) {           // W1: 4 chunks x 4 coltiles
        int lane = t & 63, fg = t >> 6;
        int col = (fg & 3) * 16 + (lane & 15);
        int kb = (fg >> 2) * 32 + (lane >> 4) * 8;
        __half v[8];
#pragma unroll
        for (int j = 0; j < 8; ++j) v[j] = __float2half(W1[(kb + j) * 64 + col]);
        *reinterpret_cast<uint4*>(F1 + (size_t)t * 8) = *reinterpret_cast<uint4*>(v);
    } else if (t < 1536) {    // W2: 2 chunks x 4 coltiles
        int u = t - 1024;
        int lane = u & 63, fg = u >> 6;
        int col = (fg & 3) * 16 + (lane & 15);
        int kb = (fg >> 2) * 32 + (lane >> 4) * 8;
        __half v[8];
#pragma unroll
        for (int j = 0; j < 8; ++j) v[j] = __float2half(W2[(kb + j) * 64 + col]);
        *reinterpret_cast<uint4*>(F2 + (size_t)u * 8) = *reinterpret_cast<uint4*>(v);
    }
}

// ============ GEMM1 (MFMA): h1[100000,64](fp16) = x[100000,128] @ W1 ============
// 4 waves/block, wave = 16 rows x 64 cols. A-frag from global fp32 (cvt), B-frag
// from pre-packed F1 (L2-hot). No LDS.
__global__ __launch_bounds__(256) void gemm1_mfma(
        const float* __restrict__ x, const __half* __restrict__ F1, __half* __restrict__ h1) {
    const int wid = threadIdx.x >> 6, lane = threadIdx.x & 63;
    const int row0 = blockIdx.x * 64 + wid * 16;
    int arow = min(row0 + (lane & 15), N_NODES - 1);
    const int kb0 = (lane >> 4) * 8;
    const float* ap = x + (size_t)arow * 128 + kb0;

    f32x4 acc[4] = {};
#pragma unroll
    for (int c = 0; c < 4; ++c) {
        float4 a0 = *reinterpret_cast<const float4*>(ap + c * 32);
        float4 a1 = *reinterpret_cast<const float4*>(ap + c * 32 + 4);
        half8 af;
        af[0] = (_Float16)a0.x; af[1] = (_Float16)a0.y; af[2] = (_Float16)a0.z; af[3] = (_Float16)a0.w;
        af[4] = (_Float16)a1.x; af[5] = (_Float16)a1.y; af[6] = (_Float16)a1.z; af[7] = (_Float16)a1.w;
#pragma unroll
        for (int ct = 0; ct < 4; ++ct) {
            half8 bf = *reinterpret_cast<const half8*>(F1 + ((size_t)(c * 4 + ct) * 64 + lane) * 8);
            acc[ct] = __builtin_amdgcn_mfma_f32_16x16x32_f16(af, bf, acc[ct], 0, 0, 0);
        }
    }
    const int prow = row0 + ((lane >> 4) << 2);
    const int col = lane & 15;
#pragma unroll
    for (int ct = 0; ct < 4; ++ct)
#pragma unroll
        for (int r = 0; r < 4; ++r) {
            int rr = prow + r;
            if (rr < N_NODES) h1[(size_t)rr * 64 + ct * 16 + col] = __float2half(acc[ct][r]);
        }
}

// ============ GEMM2 (MFMA): out[100000,64](fp32) = g[100000,64](fp16) @ W2 + b2 ============
__global__ __launch_bounds__(256) void gemm2_mfma(
        const __half* __restrict__ g, const __half* __restrict__ F2,
        const float* __restrict__ b2, float* __restrict__ out) {
    const int wid = threadIdx.x >> 6, lane = threadIdx.x & 63;
    const int row0 = blockIdx.x * 64 + wid * 16;
    int arow = min(row0 + (lane & 15), N_NODES - 1);
    const int kb0 = (lane >> 4) * 8;
    const __half* ap = g + (size_t)arow * 64 + kb0;

    f32x4 acc[4] = {};
#pragma unroll
    for (int c = 0; c < 2; ++c) {
        half8 af = *reinterpret_cast<const half8*>(ap + c * 32);
#pragma unroll
        for (int ct = 0; ct < 4; ++ct) {
            half8 bf = *reinterpret_cast<const half8*>(F2 + ((size_t)(c * 4 + ct) * 64 + lane) * 8);
            acc[ct] = __builtin_amdgcn_mfma_f32_16x16x32_f16(af, bf, acc[ct], 0, 0, 0);
        }
    }
    const int prow = row0 + ((lane >> 4) << 2);
    const int col = lane & 15;
#pragma unroll
    for (int ct = 0; ct < 4; ++ct) {
        float bb = b2[ct * 16 + col];
#pragma unroll
        for (int r = 0; r < 4; ++r) {
            int rr = prow + r;
            if (rr < N_NODES) out[(size_t)rr * 64 + ct * 16 + col] = acc[ct][r] + bb;
        }
    }
}

// ============ gather: one wave per node, 16B/lane (half8), 16 edges/iter ============
template <int BIAS_RELU>
__global__ __launch_bounds__(512) void gather_vec_kernel(
        const __half* __restrict__ h, const int2* __restrict__ csr,
        const int* __restrict__ offsets, const float* __restrict__ bias,
        __half* __restrict__ outh, int n) {
    int node = blockIdx.x * 8 + (threadIdx.x >> 6);
    int lane = threadIdx.x & 63;
    int q = lane & 7;
    int g = lane >> 3;
    int s = offsets[node];
    int e = offsets[node + 1];

    float a0 = 0.f, a1 = 0.f, a2 = 0.f, a3 = 0.f, a4 = 0.f, a5 = 0.f, a6 = 0.f, a7 = 0.f;
    for (int j = s; j < e; j += 16) {
        int eA = j + g;
        int eB = j + 8 + g;
        int2 pA = csr[min(eA, e - 1)];
        int2 pB = csr[min(eB, e - 1)];
        float nA = (eA < e) ? __int_as_float(pA.y) : 0.f;
        float nB = (eB < e) ? __int_as_float(pB.y) : 0.f;
        uint4 uA = *reinterpret_cast<const uint4*>(h + ((size_t)pA.x << 6) + (q << 3));
        uint4 uB = *reinterpret_cast<const uint4*>(h + ((size_t)pB.x << 6) + (q << 3));
        float2 f;
        f = __half22float2(__builtin_bit_cast(__half2, uA.x)); a0 = fmaf(f.x, nA, a0); a1 = fmaf(f.y, nA, a1);
        f = __half22float2(__builtin_bit_cast(__half2, uA.y)); a2 = fmaf(f.x, nA, a2); a3 = fmaf(f.y, nA, a3);
        f = __half22float2(__builtin_bit_cast(__half2, uA.z)); a4 = fmaf(f.x, nA, a4); a5 = fmaf(f.y, nA, a5);
        f = __half22float2(__builtin_bit_cast(__half2, uA.w)); a6 = fmaf(f.x, nA, a6); a7 = fmaf(f.y, nA, a7);
        f = __half22float2(__builtin_bit_cast(__half2, uB.x)); a0 = fmaf(f.x, nB, a0); a1 = fmaf(f.y, nB, a1);
        f = __half22float2(__builtin_bit_cast(__half2, uB.y)); a2 = fmaf(f.x, nB, a2); a3 = fmaf(f.y, nB, a3);
        f = __half22float2(__builtin_bit_cast(__half2, uB.z)); a4 = fmaf(f.x, nB, a4); a5 = fmaf(f.y, nB, a5);
        f = __half22float2(__builtin_bit_cast(__half2, uB.w)); a6 = fmaf(f.x, nB, a6); a7 = fmaf(f.y, nB, a7);
    }
#pragma unroll
    for (int m = 8; m <= 32; m <<= 1) {
        a0 += __shfl_xor(a0, m); a1 += __shfl_xor(a1, m);
        a2 += __shfl_xor(a2, m); a3 += __shfl_xor(a3, m);
        a4 += __shfl_xor(a4, m); a5 += __shfl_xor(a5, m);
        a6 += __shfl_xor(a6, m); a7 += __shfl_xor(a7, m);
    }
    if (BIAS_RELU) {
        const float4 b0 = *reinterpret_cast<const float4*>(bias + (q << 3));
        const float4 b1 = *reinterpret_cast<const float4*>(bias + (q << 3) + 4);
        a0 = fmaxf(a0 + b0.x, 0.f); a1 = fmaxf(a1 + b0.y, 0.f);
        a2 = fmaxf(a2 + b0.z, 0.f); a3 = fmaxf(a3 + b0.w, 0.f);
        a4 = fmaxf(a4 + b1.x, 0.f); a5 = fmaxf(a5 + b1.y, 0.f);
        a6 = fmaxf(a6 + b1.z, 0.f); a7 = fmaxf(a7 + b1.w, 0.f);
    }
    if (g == 0) {
        __half2 o0 = __float22half2_rn(make_float2(a0, a1));
        __half2 o1 = __float22half2_rn(make_float2(a2, a3));
        __half2 o2 = __float22half2_rn(make_float2(a4, a5));
        __half2 o3 = __float22half2_rn(make_float2(a6, a7));
        uint4 u = make_uint4(__builtin_bit_cast(unsigned, o0), __builtin_bit_cast(unsigned, o1),
                             __builtin_bit_cast(unsigned, o2), __builtin_bit_cast(unsigned, o3));
        *reinterpret_cast<uint4*>(outh + ((size_t)node << 6) + (q << 3)) = u;
    }
}

extern "C" void kernel_launch(void* const* d_in, const int* in_sizes, int n_in,
                              void* d_out, int out_size, void* d_ws, size_t ws_size,
                              hipStream_t stream) {
    const float* x  = (const float*)d_in[0];
    const int*   ei = (const int*)d_in[1];
    const float* ew = (const float*)d_in[2];
    const float* W1 = (const float*)d_in[3];
    const float* b1 = (const float*)d_in[4];
    const float* W2 = (const float*)d_in[5];
    const float* b2 = (const float*)d_in[6];
    float* out = (float*)d_out;
    char*  ws  = (char*)d_ws;

    const int* rows = ei;
    const int* cols = ei + N_EDGES;

    // ---- workspace (byte offsets) ----
    int2*     csr      = (int2*)(ws + 0);                      // 12,800,000
    unsigned long long* pk = (unsigned long long*)(ws + 12800000);  // 25,600,000 (col|row regions)
    __half*   h1       = (__half*)(ws + 12800000);             // fp16, over col-region
    __half*   g        = (__half*)(ws + 12800000);             // fp16, over h1 (gather2 out)
    __half*   t        = (__half*)(ws + 25600000);             // fp16, over row-region (gather1 out)
    int*      M        = (int*)(ws + 38400000);                // 802,816
    int*      Ms       = (int*)(ws + 39202816);                // 802,820
    int*      partials = (int*)(ws + 40005636);                // 788
    int*      offsets  = (int*)(ws + 40006424);                // 400,004
    float*    dis      = (float*)(ws + 40406428);              // 400,000
    __half*   F1       = (__half*)(ws + 40806432);             // 16,384 (W1 fragments)
    __half*   F2       = (__half*)(ws + 40822816);             // 8,192  (W2 fragments)

    const int TPB = 256;
    const int n2  = 2 * MROW;                    // 200,704
    const int nSB2 = (n2 + 1023) / 1024;         // 197

    // 0) pack W fragments (independent of graph phase)
    wfrag_kernel<<<6, TPB, 0, stream>>>(W1, W2, F1, F2);

    // 1) per-block bucket histograms (combined matrix)
    count_kernel<<<NBLK, TPB, 0, stream>>>(rows, cols, M);

    // 2) one scan chain over the combined matrix
    block_sum_kernel<<<nSB2, 256, 0, stream>>>(M, partials, n2);
    scan_partials_kernel<<<1, 256, 0, stream>>>(partials, nSB2);
    scan_final_kernel<<<nSB2, 256, 0, stream>>>(M, partials, Ms, n2);

    // 3) bin edges into the combined payload
    scatter_kernel<<<NBLK, TPB, 0, stream>>>(rows, cols, ew, Ms, pk);

    // 4) deg -> dis (row region)
    deg_reduce_kernel<<<NBKT, TPB, 0, stream>>>(pk, Ms, dis);

    // 5) per-node offsets + packed CSR fill (col region)
    fill_kernel<<<NBKT, TPB, 0, stream>>>(pk, Ms, dis, csr, offsets);

    // 6) h1(fp16) = x @ W1 via MFMA (over dead col-region)
    gemm1_mfma<<<(N_NODES + 63) / 64, TPB, 0, stream>>>(x, F1, h1);

    // 7) t = relu(gather(h1) + b1)  (over dead row-region)
    gather_vec_kernel<1><<<N_NODES / 8, 512, 0, stream>>>(h1, csr, offsets, b1, t, N_NODES);

    // 8) g = gather(t)  (over dead h1; W2 deferred)
    gather_vec_kernel<0><<<N_NODES / 8, 512, 0, stream>>>(t, csr, offsets, b1, g, N_NODES);

    // 9) out = g @ W2 + b2 via MFMA
    gemm2_mfma<<<(N_NODES + 63) / 64, TPB, 0, stream>>>(g, F2, b2, out);
}

// Round 11
// 193.826 us; speedup vs baseline: 5.5937x; 1.0309x over previous
//
#include <hip/hip_runtime.h>
#include <hip/hip_fp16.h>

#define N_NODES 100000
#define N_EDGES 1600000
#define IN_DIM 128
#define HID_DIM 64
#define OUT_DIM 64
#define NBKT 196    // node buckets of 512: ceil(100000/512)
#define BSH 9       // bucket shift
#define BMSK 511
#define NBLK 512    // edge-chunk blocks
#define CHUNK 3125  // 512*3125 = 1,600,000
#define MROW (NBKT * NBLK)   // 100,352: start of row-region in combined count matrix

typedef _Float16 half8 __attribute__((ext_vector_type(8)));
typedef float f32x4 __attribute__((ext_vector_type(4)));

// ============ count: per-block LDS histograms by col-bucket and row-bucket ============
__global__ void count_kernel(const int* __restrict__ rows, const int* __restrict__ cols,
                             int* __restrict__ M) {
    __shared__ unsigned hc[NBKT], hr[NBKT];
    for (int i = threadIdx.x; i < NBKT; i += 256) { hc[i] = 0; hr[i] = 0; }
    __syncthreads();
    const int s = blockIdx.x * CHUNK;
    const int e = min(s + CHUNK, N_EDGES);
    for (int i = s + threadIdx.x; i < e; i += 256) {
        atomicAdd(&hr[rows[i] >> BSH], 1u);
        atomicAdd(&hc[cols[i] >> BSH], 1u);
    }
    __syncthreads();
    for (int i = threadIdx.x; i < NBKT; i += 256) {
        M[i * NBLK + blockIdx.x] = (int)hc[i];
        M[MROW + i * NBLK + blockIdx.x] = (int)hr[i];
    }
}

// ============ exclusive scan (3 kernels) ============
__global__ void block_sum_kernel(const int* __restrict__ counts, int* __restrict__ partials, int n) {
    __shared__ int sh[256];
    int base = blockIdx.x * 1024;
    int s = 0;
    for (int i = threadIdx.x; i < 1024; i += 256) {
        int idx = base + i;
        s += (idx < n) ? counts[idx] : 0;
    }
    sh[threadIdx.x] = s;
    __syncthreads();
    for (int off = 128; off > 0; off >>= 1) {
        if (threadIdx.x < off) sh[threadIdx.x] += sh[threadIdx.x + off];
        __syncthreads();
    }
    if (threadIdx.x == 0) partials[blockIdx.x] = sh[0];
}

__global__ void scan_partials_kernel(int* __restrict__ p, int nb) {
    __shared__ int sh[256];
    int t = threadIdx.x;
    int v = (t < nb) ? p[t] : 0;
    sh[t] = v;
    __syncthreads();
    for (int off = 1; off < 256; off <<= 1) {
        int add = (t >= off) ? sh[t - off] : 0;
        __syncthreads();
        sh[t] += add;
        __syncthreads();
    }
    if (t < nb) p[t] = sh[t] - v;  // exclusive
}

__global__ void scan_final_kernel(const int* __restrict__ counts, const int* __restrict__ partials,
                                  int* __restrict__ offsets, int n) {
    __shared__ int sh[256];
    int t = threadIdx.x;
    int idx0 = blockIdx.x * 1024 + t * 4;
    int v[4];
    int s = 0;
#pragma unroll
    for (int j = 0; j < 4; ++j) {
        int id = idx0 + j;
        v[j] = (id < n) ? counts[id] : 0;
        s += v[j];
    }
    sh[t] = s;
    __syncthreads();
    for (int off = 1; off < 256; off <<= 1) {
        int add = (t >= off) ? sh[t - off] : 0;
        __syncthreads();
        sh[t] += add;
        __syncthreads();
    }
    int run = sh[t] - s + partials[blockIdx.x];
#pragma unroll
    for (int j = 0; j < 4; ++j) {
        int id = idx0 + j;
        if (id < n) offsets[id] = run;
        run += v[j];
    }
    if (idx0 <= n - 1 && n - 1 < idx0 + 4) offsets[n] = run;
}

// ============ scatter v2: block-local LDS counting sort, coalesced write-out ============
// Stage A bins the block's 3125 edges by col-bucket in LDS, then streams them to pkA
// (consecutive LDS slots -> consecutive global addresses within each bucket run).
// Stage B does the same by row-bucket into the 4B pkR (fp16 w | 9b local row).
__global__ __launch_bounds__(256) void scatter_kernel(
        const int* __restrict__ rows, const int* __restrict__ cols,
        const float* __restrict__ w, const int* __restrict__ M, const int* __restrict__ Ms,
        unsigned long long* __restrict__ pkA, unsigned* __restrict__ pkR) {
    __shared__ unsigned long long pay[CHUNK];
    __shared__ unsigned char bkt[CHUNK + 3];
    __shared__ unsigned scn[256];
    __shared__ unsigned base[NBKT], cur[NBKT], gbase[NBKT];
    const int blk = blockIdx.x, t = threadIdx.x;
    const int s = blk * CHUNK;

    // ---- stage A: col-bucket payload (w32 | c_local9 | r17) ----
    unsigned cnt = (t < NBKT) ? (unsigned)M[t * NBLK + blk] : 0;
    scn[t] = cnt;
    __syncthreads();
    for (int off = 1; off < 256; off <<= 1) {
        unsigned a = (t >= off) ? scn[t - off] : 0;
        __syncthreads();
        scn[t] += a;
        __syncthreads();
    }
    if (t < NBKT) {
        unsigned b0 = scn[t] - cnt;
        base[t] = b0; cur[t] = b0;
        gbase[t] = (unsigned)Ms[t * NBLK + blk];
    }
    __syncthreads();
    for (int i = s + t; i < s + CHUNK; i += 256) {
        int r = rows[i], c = cols[i];
        unsigned b = (unsigned)c >> BSH;
        unsigned p = atomicAdd(&cur[b], 1u);  // LDS
        pay[p] = ((unsigned long long)__float_as_uint(w[i]) << 32) |
                 (unsigned)(((c & BMSK) << 17) | r);
        bkt[p] = (unsigned char)b;
    }
    __syncthreads();
    for (int i = t; i < CHUNK; i += 256) {
        unsigned b = bkt[i];
        pkA[gbase[b] + (i - base[b])] = pay[i];
    }
    __syncthreads();

    // ---- stage B: row-bucket payload (fp16 w << 16 | r_local9) ----
    cnt = (t < NBKT) ? (unsigned)M[MROW + t * NBLK + blk] : 0;
    scn[t] = cnt;
    __syncthreads();
    for (int off = 1; off < 256; off <<= 1) {
        unsigned a = (t >= off) ? scn[t - off] : 0;
        __syncthreads();
        scn[t] += a;
        __syncthreads();
    }
    if (t < NBKT) {
        unsigned b0 = scn[t] - cnt;
        base[t] = b0; cur[t] = b0;
        gbase[t] = (unsigned)Ms[MROW + t * NBLK + blk] - (unsigned)N_EDGES;
    }
    __syncthreads();
    unsigned* pay32 = (unsigned*)pay;
    for (int i = s + t; i < s + CHUNK; i += 256) {
        int r = rows[i];
        unsigned b = (unsigned)r >> BSH;
        unsigned p = atomicAdd(&cur[b], 1u);  // LDS
        unsigned short hw = __half_as_ushort(__float2half(w[i]));
        pay32[p] = ((unsigned)hw << 16) | (unsigned)(r & BMSK);
        bkt[p] = (unsigned char)b;
    }
    __syncthreads();
    for (int i = t; i < CHUNK; i += 256) {
        unsigned b = bkt[i];
        pkR[gbase[b] + (i - base[b])] = pay32[i];
    }
}

// ============ deg reduce: block per row-bucket (512 nodes), 4B payloads -> dis ============
__global__ void deg_reduce_kernel(const unsigned* __restrict__ pkR,
                                  const int* __restrict__ Ms, float* __restrict__ dis) {
    __shared__ float acc[512];
    const int b = blockIdx.x;
    const int t = threadIdx.x;
    acc[t] = 0.f; acc[t + 256] = 0.f;
    __syncthreads();
    const int s = Ms[MROW + b * NBLK] - N_EDGES;
    const int e = Ms[MROW + (b + 1) * NBLK] - N_EDGES;
    for (int i = s + t; i < e; i += 256) {
        unsigned u = pkR[i];
        float wv = __half2float(__ushort_as_half((unsigned short)(u >> 16)));
        atomicAdd(&acc[u & (unsigned)BMSK], wv);  // LDS
    }
    __syncthreads();
#pragma unroll
    for (int k = 0; k < 2; ++k) {
        int node = b * 512 + t + k * 256;
        if (node < N_NODES) {
            float d = acc[t + k * 256];
            dis[node] = d > 0.f ? rsqrtf(fmaxf(d, 1e-12f)) : 0.f;
        }
    }
}

// ============ fill: block per col-bucket -> offsets + CSR (r, w) — dis deferred ============
__global__ void fill_kernel(const unsigned long long* __restrict__ pk,
                            const int* __restrict__ Ms,
                            int2* __restrict__ csr, int* __restrict__ offsets) {
    __shared__ unsigned hist[512];
    __shared__ unsigned pairs[256];
    const int b = blockIdx.x;
    const int t = threadIdx.x;
    hist[t] = 0; hist[t + 256] = 0;
    __syncthreads();
    const int s = Ms[b * NBLK];
    const int e = Ms[(b + 1) * NBLK];
    for (int i = s + t; i < e; i += 256) {
        unsigned lo = (unsigned)pk[i];
        atomicAdd(&hist[(lo >> 17) & (unsigned)BMSK], 1u);
    }
    __syncthreads();
    unsigned h0 = hist[2 * t], h1 = hist[2 * t + 1];
    pairs[t] = h0 + h1;
    __syncthreads();
    for (int off = 1; off < 256; off <<= 1) {
        unsigned add = (t >= off) ? pairs[t - off] : 0;
        __syncthreads();
        pairs[t] += add;
        __syncthreads();
    }
    unsigned P = pairs[t] - (h0 + h1) + (unsigned)s;
    unsigned e0 = P, e1 = P + h0;
    int n0 = b * 512 + 2 * t;
    int n1 = n0 + 1;
    if (n0 <= N_NODES) offsets[n0] = (int)e0;
    if (n1 <= N_NODES) offsets[n1] = (int)e1;
    hist[2 * t] = e0; hist[2 * t + 1] = e1;   // reuse as cursors
    __syncthreads();
    for (int i = s + t; i < e; i += 256) {
        unsigned long long p = pk[i];
        unsigned lo = (unsigned)p;
        unsigned cl = (lo >> 17) & (unsigned)BMSK;
        int r = (int)(lo & 0x1FFFFu);
        unsigned pos = atomicAdd(&hist[cl], 1u);  // LDS
        csr[pos] = make_int2(r, (int)(unsigned)(p >> 32));   // raw w bits
    }
}

// ============ wfrag: pack W1/W2 into fp16 MFMA B-fragments ============
__global__ void wfrag_kernel(const float* __restrict__ W1, const float* __restrict__ W2,
                             __half* __restrict__ F1, __half* __restrict__ F2) {
    int t = blockIdx.x * 256 + threadIdx.x;
    if (t < 1024) {
        int lane = t & 63, fg = t >> 6;
        int col = (fg & 3) * 16 + (lane & 15);
        int kb = (fg >> 2) * 32 + (lane >> 4) * 8;
        __half v[8];
#pragma unroll
        for (int j = 0; j < 8; ++j) v[j] = __float2half(W1[(kb + j) * 64 + col]);
        *reinterpret_cast<uint4*>(F1 + (size_t)t * 8) = *reinterpret_cast<uint4*>(v);
    } else if (t < 1536) {
        int u = t - 1024;
        int lane = u & 63, fg = u >> 6;
        int col = (fg & 3) * 16 + (lane & 15);
        int kb = (fg >> 2) * 32 + (lane >> 4) * 8;
        __half v[8];
#pragma unroll
        for (int j = 0; j < 8; ++j) v[j] = __float2half(W2[(kb + j) * 64 + col]);
        *reinterpret_cast<uint4*>(F2 + (size_t)u * 8) = *reinterpret_cast<uint4*>(v);
    }
}

// ============ GEMM1 (MFMA): h1[r] = dis[r] * (x @ W1)[r], fp16 out ============
__global__ __launch_bounds__(256) void gemm1_mfma(
        const float* __restrict__ x, const __half* __restrict__ F1,
        const float* __restrict__ dis, __half* __restrict__ h1) {
    const int wid = threadIdx.x >> 6, lane = threadIdx.x & 63;
    const int row0 = blockIdx.x * 64 + wid * 16;
    int arow = min(row0 + (lane & 15), N_NODES - 1);
    const int kb0 = (lane >> 4) * 8;
    const float* ap = x + (size_t)arow * 128 + kb0;

    f32x4 acc[4] = {};
#pragma unroll
    for (int c = 0; c < 4; ++c) {
        float4 a0 = *reinterpret_cast<const float4*>(ap + c * 32);
        float4 a1 = *reinterpret_cast<const float4*>(ap + c * 32 + 4);
        half8 af;
        af[0] = (_Float16)a0.x; af[1] = (_Float16)a0.y; af[2] = (_Float16)a0.z; af[3] = (_Float16)a0.w;
        af[4] = (_Float16)a1.x; af[5] = (_Float16)a1.y; af[6] = (_Float16)a1.z; af[7] = (_Float16)a1.w;
#pragma unroll
        for (int ct = 0; ct < 4; ++ct) {
            half8 bf = *reinterpret_cast<const half8*>(F1 + ((size_t)(c * 4 + ct) * 64 + lane) * 8);
            acc[ct] = __builtin_amdgcn_mfma_f32_16x16x32_f16(af, bf, acc[ct], 0, 0, 0);
        }
    }
    const int prow = row0 + ((lane >> 4) << 2);
    const int col = lane & 15;
#pragma unroll
    for (int r = 0; r < 4; ++r) {
        int rr = prow + r;
        if (rr < N_NODES) {
            float dv = dis[rr];
#pragma unroll
            for (int ct = 0; ct < 4; ++ct)
                h1[(size_t)rr * 64 + ct * 16 + col] = __float2half(acc[ct][r] * dv);
        }
    }
}

// ============ GEMM2 (MFMA): out = g @ W2 + b2, fp32 out ============
__global__ __launch_bounds__(256) void gemm2_mfma(
        const __half* __restrict__ g, const __half* __restrict__ F2,
        const float* __restrict__ b2, float* __restrict__ out) {
    const int wid = threadIdx.x >> 6, lane = threadIdx.x & 63;
    const int row0 = blockIdx.x * 64 + wid * 16;
    int arow = min(row0 + (lane & 15), N_NODES - 1);
    const int kb0 = (lane >> 4) * 8;
    const __half* ap = g + (size_t)arow * 64 + kb0;

    f32x4 acc[4] = {};
#pragma unroll
    for (int c = 0; c < 2; ++c) {
        half8 af = *reinterpret_cast<const half8*>(ap + c * 32);
#pragma unroll
        for (int ct = 0; ct < 4; ++ct) {
            half8 bf = *reinterpret_cast<const half8*>(F2 + ((size_t)(c * 4 + ct) * 64 + lane) * 8);
            acc[ct] = __builtin_amdgcn_mfma_f32_16x16x32_f16(af, bf, acc[ct], 0, 0, 0);
        }
    }
    const int prow = row0 + ((lane >> 4) << 2);
    const int col = lane & 15;
#pragma unroll
    for (int ct = 0; ct < 4; ++ct) {
        float bb = b2[ct * 16 + col];
#pragma unroll
        for (int r = 0; r < 4; ++r) {
            int rr = prow + r;
            if (rr < N_NODES) out[(size_t)rr * 64 + ct * 16 + col] = acc[ct][r] + bb;
        }
    }
}

// ============ gather: one wave per node, 16B/lane (half8), 16 edges/iter ============
// BIAS_RELU=1 (conv1): out = dis[v]*relu(dis[v]*S + b1).  =0 (conv2): out = dis[v]*S.
template <int BIAS_RELU>
__global__ __launch_bounds__(512) void gather_vec_kernel(
        const __half* __restrict__ h, const int2* __restrict__ csr,
        const int* __restrict__ offsets, const float* __restrict__ bias,
        const float* __restrict__ dis, __half* __restrict__ outh, int n) {
    int node = blockIdx.x * 8 + (threadIdx.x >> 6);
    int lane = threadIdx.x & 63;
    int q = lane & 7;
    int g = lane >> 3;
    int s = offsets[node];
    int e = offsets[node + 1];

    float a0 = 0.f, a1 = 0.f, a2 = 0.f, a3 = 0.f, a4 = 0.f, a5 = 0.f, a6 = 0.f, a7 = 0.f;
    for (int j = s; j < e; j += 16) {
        int eA = j + g;
        int eB = j + 8 + g;
        int2 pA = csr[min(eA, e - 1)];
        int2 pB = csr[min(eB, e - 1)];
        float nA = (eA < e) ? __int_as_float(pA.y) : 0.f;
        float nB = (eB < e) ? __int_as_float(pB.y) : 0.f;
        uint4 uA = *reinterpret_cast<const uint4*>(h + ((size_t)pA.x << 6) + (q << 3));
        uint4 uB = *reinterpret_cast<const uint4*>(h + ((size_t)pB.x << 6) + (q << 3));
        float2 f;
        f = __half22float2(__builtin_bit_cast(__half2, uA.x)); a0 = fmaf(f.x, nA, a0); a1 = fmaf(f.y, nA, a1);
        f = __half22float2(__builtin_bit_cast(__half2, uA.y)); a2 = fmaf(f.x, nA, a2); a3 = fmaf(f.y, nA, a3);
        f = __half22float2(__builtin_bit_cast(__half2, uA.z)); a4 = fmaf(f.x, nA, a4); a5 = fmaf(f.y, nA, a5);
        f = __half22float2(__builtin_bit_cast(__half2, uA.w)); a6 = fmaf(f.x, nA, a6); a7 = fmaf(f.y, nA, a7);
        f = __half22float2(__builtin_bit_cast(__half2, uB.x)); a0 = fmaf(f.x, nB, a0); a1 = fmaf(f.y, nB, a1);
        f = __half22float2(__builtin_bit_cast(__half2, uB.y)); a2 = fmaf(f.x, nB, a2); a3 = fmaf(f.y, nB, a3);
        f = __half22float2(__builtin_bit_cast(__half2, uB.z)); a4 = fmaf(f.x, nB, a4); a5 = fmaf(f.y, nB, a5);
        f = __half22float2(__builtin_bit_cast(__half2, uB.w)); a6 = fmaf(f.x, nB, a6); a7 = fmaf(f.y, nB, a7);
    }
#pragma unroll
    for (int m = 8; m <= 32; m <<= 1) {
        a0 += __shfl_xor(a0, m); a1 += __shfl_xor(a1, m);
        a2 += __shfl_xor(a2, m); a3 += __shfl_xor(a3, m);
        a4 += __shfl_xor(a4, m); a5 += __shfl_xor(a5, m);
        a6 += __shfl_xor(a6, m); a7 += __shfl_xor(a7, m);
    }
    if (g == 0) {
        float dv = dis[node];
        if (BIAS_RELU) {
            const float4 b0 = *reinterpret_cast<const float4*>(bias + (q << 3));
            const float4 b1 = *reinterpret_cast<const float4*>(bias + (q << 3) + 4);
            a0 = fmaxf(fmaf(a0, dv, b0.x), 0.f) * dv; a1 = fmaxf(fmaf(a1, dv, b0.y), 0.f) * dv;
            a2 = fmaxf(fmaf(a2, dv, b0.z), 0.f) * dv; a3 = fmaxf(fmaf(a3, dv, b0.w), 0.f) * dv;
            a4 = fmaxf(fmaf(a4, dv, b1.x), 0.f) * dv; a5 = fmaxf(fmaf(a5, dv, b1.y), 0.f) * dv;
            a6 = fmaxf(fmaf(a6, dv, b1.z), 0.f) * dv; a7 = fmaxf(fmaf(a7, dv, b1.w), 0.f) * dv;
        } else {
            a0 *= dv; a1 *= dv; a2 *= dv; a3 *= dv;
            a4 *= dv; a5 *= dv; a6 *= dv; a7 *= dv;
        }
        __half2 o0 = __float22half2_rn(make_float2(a0, a1));
        __half2 o1 = __float22half2_rn(make_float2(a2, a3));
        __half2 o2 = __float22half2_rn(make_float2(a4, a5));
        __half2 o3 = __float22half2_rn(make_float2(a6, a7));
        uint4 u = make_uint4(__builtin_bit_cast(unsigned, o0), __builtin_bit_cast(unsigned, o1),
                             __builtin_bit_cast(unsigned, o2), __builtin_bit_cast(unsigned, o3));
        *reinterpret_cast<uint4*>(outh + ((size_t)node << 6) + (q << 3)) = u;
    }
}

extern "C" void kernel_launch(void* const* d_in, const int* in_sizes, int n_in,
                              void* d_out, int out_size, void* d_ws, size_t ws_size,
                              hipStream_t stream) {
    const float* x  = (const float*)d_in[0];
    const int*   ei = (const int*)d_in[1];
    const float* ew = (const float*)d_in[2];
    const float* W1 = (const float*)d_in[3];
    const float* b1 = (const float*)d_in[4];
    const float* W2 = (const float*)d_in[5];
    const float* b2 = (const float*)d_in[6];
    float* out = (float*)d_out;
    char*  ws  = (char*)d_ws;

    const int* rows = ei;
    const int* cols = ei + N_EDGES;

    // ---- workspace (byte offsets) ----
    int2*     csr      = (int2*)(ws + 0);                      // 12,800,000
    unsigned long long* pkA = (unsigned long long*)(ws + 12800000);  // 12,800,000 [dies at fill]
    unsigned* pkR      = (unsigned*)(ws + 25600000);           // 6,400,000 [dies at deg_reduce]
    __half*   h1       = (__half*)(ws + 12800000);             // fp16, over pkA
    __half*   g        = (__half*)(ws + 12800000);             // fp16, over h1 (gather2 out)
    __half*   t        = (__half*)(ws + 25600000);             // fp16, over pkR (gather1 out)
    int*      M        = (int*)(ws + 38400000);                // 802,816
    int*      Ms       = (int*)(ws + 39202816);                // 802,820
    int*      partials = (int*)(ws + 40005636);                // 788
    int*      offsets  = (int*)(ws + 40006424);                // 400,004
    float*    dis      = (float*)(ws + 40406428);              // 400,000
    __half*   F1       = (__half*)(ws + 40806432);             // 16,384
    __half*   F2       = (__half*)(ws + 40822816);             // 8,192

    const int TPB = 256;
    const int n2  = 2 * MROW;                    // 200,704
    const int nSB2 = (n2 + 1023) / 1024;         // 197

    // 0) pack W fragments
    wfrag_kernel<<<6, TPB, 0, stream>>>(W1, W2, F1, F2);

    // 1) per-block bucket histograms (combined matrix)
    count_kernel<<<NBLK, TPB, 0, stream>>>(rows, cols, M);

    // 2) one scan chain over the combined matrix
    block_sum_kernel<<<nSB2, 256, 0, stream>>>(M, partials, n2);
    scan_partials_kernel<<<1, 256, 0, stream>>>(partials, nSB2);
    scan_final_kernel<<<nSB2, 256, 0, stream>>>(M, partials, Ms, n2);

    // 3) LDS-sorted scatter into pkA (8B) + pkR (4B), coalesced writes
    scatter_kernel<<<NBLK, TPB, 0, stream>>>(rows, cols, ew, M, Ms, pkA, pkR);

    // 4) deg -> dis (4B row payloads)
    deg_reduce_kernel<<<NBKT, TPB, 0, stream>>>(pkR, Ms, dis);

    // 5) per-node offsets + CSR (r, w) — dis deferred to epilogues
    fill_kernel<<<NBKT, TPB, 0, stream>>>(pkA, Ms, csr, offsets);

    // 6) h1 = dis * (x @ W1) via MFMA (over dead pkA)
    gemm1_mfma<<<(N_NODES + 63) / 64, TPB, 0, stream>>>(x, F1, dis, h1);

    // 7) t = dis*relu(dis*gather(h1) + b1)  (over dead pkR)
    gather_vec_kernel<1><<<N_NODES / 8, 512, 0, stream>>>(h1, csr, offsets, b1, dis, t, N_NODES);

    // 8) g = dis*gather(t)  (over dead h1)
    gather_vec_kernel<0><<<N_NODES / 8, 512, 0, stream>>>(t, csr, offsets, b1, dis, g, N_NODES);

    // 9) out = g @ W2 + b2 via MFMA
    gemm2_mfma<<<(N_NODES + 63) / 64, TPB, 0, stream>>>(g, F2, b2, out);
}

// Round 12
// 165.830 us; speedup vs baseline: 6.5380x; 1.1688x over previous
//
#include <hip/hip_runtime.h>
#include <hip/hip_fp16.h>

#define N_NODES 100000
#define N_EDGES 1600000
#define IN_DIM 128
#define HID_DIM 64
#define OUT_DIM 64
#define NBKT 196    // node buckets of 512: ceil(100000/512)
#define BSH 9       // bucket shift
#define BMSK 511
#define NBLK 500    // edge-chunk blocks
#define CHUNK 3200  // 500*3200 = 1,600,000 (divisible by 4 for int4 loads)
#define MROW (NBKT * NBLK)   // 98,000: start of row-region in combined count matrix

typedef _Float16 half8 __attribute__((ext_vector_type(8)));
typedef float f32x4 __attribute__((ext_vector_type(4)));

// ============ count (+ merged wfrag): per-block histograms, int4 edge loads ============
__global__ void count_kernel(const int* __restrict__ rows, const int* __restrict__ cols,
                             int* __restrict__ M,
                             const float* __restrict__ W1, const float* __restrict__ W2,
                             __half* __restrict__ F1, __half* __restrict__ F2) {
    __shared__ unsigned hc[NBKT], hr[NBKT];
    if (blockIdx.x >= NBLK) {
        // ---- wfrag: pack W1/W2 into fp16 MFMA B-fragments ----
        int t = (blockIdx.x - NBLK) * 256 + threadIdx.x;
        if (t < 1024) {
            int lane = t & 63, fg = t >> 6;
            int col = (fg & 3) * 16 + (lane & 15);
            int kb = (fg >> 2) * 32 + (lane >> 4) * 8;
            __half v[8];
#pragma unroll
            for (int j = 0; j < 8; ++j) v[j] = __float2half(W1[(kb + j) * 64 + col]);
            *reinterpret_cast<uint4*>(F1 + (size_t)t * 8) = *reinterpret_cast<uint4*>(v);
        } else if (t < 1536) {
            int u = t - 1024;
            int lane = u & 63, fg = u >> 6;
            int col = (fg & 3) * 16 + (lane & 15);
            int kb = (fg >> 2) * 32 + (lane >> 4) * 8;
            __half v[8];
#pragma unroll
            for (int j = 0; j < 8; ++j) v[j] = __float2half(W2[(kb + j) * 64 + col]);
            *reinterpret_cast<uint4*>(F2 + (size_t)u * 8) = *reinterpret_cast<uint4*>(v);
        }
        return;
    }
    for (int i = threadIdx.x; i < NBKT; i += 256) { hc[i] = 0; hr[i] = 0; }
    __syncthreads();
    const int4* r4 = (const int4*)(rows + blockIdx.x * CHUNK);
    const int4* c4 = (const int4*)(cols + blockIdx.x * CHUNK);
    for (int i = threadIdx.x; i < CHUNK / 4; i += 256) {
        int4 r = r4[i], c = c4[i];
        atomicAdd(&hr[r.x >> BSH], 1u); atomicAdd(&hr[r.y >> BSH], 1u);
        atomicAdd(&hr[r.z >> BSH], 1u); atomicAdd(&hr[r.w >> BSH], 1u);
        atomicAdd(&hc[c.x >> BSH], 1u); atomicAdd(&hc[c.y >> BSH], 1u);
        atomicAdd(&hc[c.z >> BSH], 1u); atomicAdd(&hc[c.w >> BSH], 1u);
    }
    __syncthreads();
    for (int i = threadIdx.x; i < NBKT; i += 256) {
        M[i * NBLK + blockIdx.x] = (int)hc[i];
        M[MROW + i * NBLK + blockIdx.x] = (int)hr[i];
    }
}

// ============ exclusive scan (3 kernels) ============
__global__ void block_sum_kernel(const int* __restrict__ counts, int* __restrict__ partials, int n) {
    __shared__ int sh[256];
    int base = blockIdx.x * 1024;
    int s = 0;
    for (int i = threadIdx.x; i < 1024; i += 256) {
        int idx = base + i;
        s += (idx < n) ? counts[idx] : 0;
    }
    sh[threadIdx.x] = s;
    __syncthreads();
    for (int off = 128; off > 0; off >>= 1) {
        if (threadIdx.x < off) sh[threadIdx.x] += sh[threadIdx.x + off];
        __syncthreads();
    }
    if (threadIdx.x == 0) partials[blockIdx.x] = sh[0];
}

__global__ void scan_partials_kernel(int* __restrict__ p, int nb) {
    __shared__ int sh[256];
    int t = threadIdx.x;
    int v = (t < nb) ? p[t] : 0;
    sh[t] = v;
    __syncthreads();
    for (int off = 1; off < 256; off <<= 1) {
        int add = (t >= off) ? sh[t - off] : 0;
        __syncthreads();
        sh[t] += add;
        __syncthreads();
    }
    if (t < nb) p[t] = sh[t] - v;  // exclusive
}

__global__ void scan_final_kernel(const int* __restrict__ counts, const int* __restrict__ partials,
                                  int* __restrict__ offsets, int n) {
    __shared__ int sh[256];
    int t = threadIdx.x;
    int idx0 = blockIdx.x * 1024 + t * 4;
    int v[4];
    int s = 0;
#pragma unroll
    for (int j = 0; j < 4; ++j) {
        int id = idx0 + j;
        v[j] = (id < n) ? counts[id] : 0;
        s += v[j];
    }
    sh[t] = s;
    __syncthreads();
    for (int off = 1; off < 256; off <<= 1) {
        int add = (t >= off) ? sh[t - off] : 0;
        __syncthreads();
        sh[t] += add;
        __syncthreads();
    }
    int run = sh[t] - s + partials[blockIdx.x];
#pragma unroll
    for (int j = 0; j < 4; ++j) {
        int id = idx0 + j;
        if (id < n) offsets[id] = run;
        run += v[j];
    }
    if (idx0 <= n - 1 && n - 1 < idx0 + 4) offsets[n] = run;
}

// ============ scatter: block-local LDS counting sort, coalesced write-out, int4 reads ============
__global__ __launch_bounds__(256) void scatter_kernel(
        const int* __restrict__ rows, const int* __restrict__ cols,
        const float* __restrict__ w, const int* __restrict__ M, const int* __restrict__ Ms,
        unsigned long long* __restrict__ pkA, unsigned* __restrict__ pkR) {
    __shared__ unsigned long long pay[CHUNK];
    __shared__ unsigned char bkt[CHUNK];
    __shared__ unsigned scn[256];
    __shared__ unsigned base[NBKT], cur[NBKT], gbase[NBKT];
    const int blk = blockIdx.x, t = threadIdx.x;
    const int s = blk * CHUNK;
    const int4* r4 = (const int4*)(rows + s);
    const int4* c4 = (const int4*)(cols + s);
    const float4* w4 = (const float4*)(w + s);

    // ---- stage A: col-bucket payload (w32 | c_local9 | r17) ----
    unsigned cnt = (t < NBKT) ? (unsigned)M[t * NBLK + blk] : 0;
    scn[t] = cnt;
    __syncthreads();
    for (int off = 1; off < 256; off <<= 1) {
        unsigned a = (t >= off) ? scn[t - off] : 0;
        __syncthreads();
        scn[t] += a;
        __syncthreads();
    }
    if (t < NBKT) {
        unsigned b0 = scn[t] - cnt;
        base[t] = b0; cur[t] = b0;
        gbase[t] = (unsigned)Ms[t * NBLK + blk];
    }
    __syncthreads();
#define PUTA(RV, CV, WV) { unsigned b = (unsigned)(CV) >> BSH; \
        unsigned p = atomicAdd(&cur[b], 1u); \
        pay[p] = ((unsigned long long)__float_as_uint(WV) << 32) | \
                 (unsigned)((((CV) & BMSK) << 17) | (RV)); \
        bkt[p] = (unsigned char)b; }
    for (int i = t; i < CHUNK / 4; i += 256) {
        int4 rr = r4[i]; int4 cc = c4[i]; float4 ww = w4[i];
        PUTA(rr.x, cc.x, ww.x); PUTA(rr.y, cc.y, ww.y);
        PUTA(rr.z, cc.z, ww.z); PUTA(rr.w, cc.w, ww.w);
    }
    __syncthreads();
    for (int i = t; i < CHUNK; i += 256) {
        unsigned b = bkt[i];
        pkA[gbase[b] + (i - base[b])] = pay[i];
    }
    __syncthreads();

    // ---- stage B: row-bucket payload (fp16 w << 16 | r_local9) ----
    cnt = (t < NBKT) ? (unsigned)M[MROW + t * NBLK + blk] : 0;
    scn[t] = cnt;
    __syncthreads();
    for (int off = 1; off < 256; off <<= 1) {
        unsigned a = (t >= off) ? scn[t - off] : 0;
        __syncthreads();
        scn[t] += a;
        __syncthreads();
    }
    if (t < NBKT) {
        unsigned b0 = scn[t] - cnt;
        base[t] = b0; cur[t] = b0;
        gbase[t] = (unsigned)Ms[MROW + t * NBLK + blk] - (unsigned)N_EDGES;
    }
    __syncthreads();
    unsigned* pay32 = (unsigned*)pay;
#define PUTR(RV, WV) { unsigned b = (unsigned)(RV) >> BSH; \
        unsigned p = atomicAdd(&cur[b], 1u); \
        pay32[p] = ((unsigned)__half_as_ushort(__float2half(WV)) << 16) | (unsigned)((RV) & BMSK); \
        bkt[p] = (unsigned char)b; }
    for (int i = t; i < CHUNK / 4; i += 256) {
        int4 rr = r4[i]; float4 ww = w4[i];
        PUTR(rr.x, ww.x); PUTR(rr.y, ww.y); PUTR(rr.z, ww.z); PUTR(rr.w, ww.w);
    }
    __syncthreads();
    for (int i = t; i < CHUNK; i += 256) {
        unsigned b = bkt[i];
        pkR[gbase[b] + (i - base[b])] = pay32[i];
    }
}

// ============ merged fill (col region) + deg reduce (row region) ============
__global__ __launch_bounds__(256) void fill_deg_kernel(
        const unsigned long long* __restrict__ pkA, const unsigned* __restrict__ pkR,
        const int* __restrict__ Ms, int2* __restrict__ csr,
        int* __restrict__ offsets, float* __restrict__ dis) {
    __shared__ unsigned sh[768];   // fill: hist[512]+pairs[256]; deg: acc[512] (float alias)
    const int t = threadIdx.x;
    if (blockIdx.x < NBKT) {
        // ---- fill: offsets + CSR (r, raw w bits) ----
        unsigned* hist = sh;
        unsigned* pairs = sh + 512;
        const int b = blockIdx.x;
        hist[t] = 0; hist[t + 256] = 0;
        __syncthreads();
        const int s = Ms[b * NBLK];
        const int e = Ms[(b + 1) * NBLK];
        for (int i = s + t; i < e; i += 256) {
            unsigned lo = (unsigned)pkA[i];
            atomicAdd(&hist[(lo >> 17) & (unsigned)BMSK], 1u);
        }
        __syncthreads();
        unsigned h0 = hist[2 * t], h1 = hist[2 * t + 1];
        pairs[t] = h0 + h1;
        __syncthreads();
        for (int off = 1; off < 256; off <<= 1) {
            unsigned add = (t >= off) ? pairs[t - off] : 0;
            __syncthreads();
            pairs[t] += add;
            __syncthreads();
        }
        unsigned P = pairs[t] - (h0 + h1) + (unsigned)s;
        unsigned e0 = P, e1 = P + h0;
        int n0 = b * 512 + 2 * t;
        int n1 = n0 + 1;
        if (n0 <= N_NODES) offsets[n0] = (int)e0;
        if (n1 <= N_NODES) offsets[n1] = (int)e1;
        hist[2 * t] = e0; hist[2 * t + 1] = e1;   // reuse as cursors
        __syncthreads();
        for (int i = s + t; i < e; i += 256) {
            unsigned long long p = pkA[i];
            unsigned lo = (unsigned)p;
            unsigned cl = (lo >> 17) & (unsigned)BMSK;
            int r = (int)(lo & 0x1FFFFu);
            unsigned pos = atomicAdd(&hist[cl], 1u);  // LDS
            csr[pos] = make_int2(r, (int)(unsigned)(p >> 32));
        }
    } else {
        // ---- deg reduce -> dis ----
        float* acc = (float*)sh;
        const int b = blockIdx.x - NBKT;
        acc[t] = 0.f; acc[t + 256] = 0.f;
        __syncthreads();
        const int s = Ms[MROW + b * NBLK] - N_EDGES;
        const int e = Ms[MROW + (b + 1) * NBLK] - N_EDGES;
        for (int i = s + t; i < e; i += 256) {
            unsigned u = pkR[i];
            float wv = __half2float(__ushort_as_half((unsigned short)(u >> 16)));
            atomicAdd(&acc[u & (unsigned)BMSK], wv);  // LDS
        }
        __syncthreads();
#pragma unroll
        for (int k = 0; k < 2; ++k) {
            int node = b * 512 + t + k * 256;
            if (node < N_NODES) {
                float d = acc[t + k * 256];
                dis[node] = d > 0.f ? rsqrtf(fmaxf(d, 1e-12f)) : 0.f;
            }
        }
    }
}

// ============ GEMM1 (MFMA): h1[r] = dis[r] * (x @ W1)[r], fp16 out ============
__global__ __launch_bounds__(256) void gemm1_mfma(
        const float* __restrict__ x, const __half* __restrict__ F1,
        const float* __restrict__ dis, __half* __restrict__ h1) {
    const int wid = threadIdx.x >> 6, lane = threadIdx.x & 63;
    const int row0 = blockIdx.x * 64 + wid * 16;
    int arow = min(row0 + (lane & 15), N_NODES - 1);
    const int kb0 = (lane >> 4) * 8;
    const float* ap = x + (size_t)arow * 128 + kb0;

    f32x4 acc[4] = {};
#pragma unroll
    for (int c = 0; c < 4; ++c) {
        float4 a0 = *reinterpret_cast<const float4*>(ap + c * 32);
        float4 a1 = *reinterpret_cast<const float4*>(ap + c * 32 + 4);
        half8 af;
        af[0] = (_Float16)a0.x; af[1] = (_Float16)a0.y; af[2] = (_Float16)a0.z; af[3] = (_Float16)a0.w;
        af[4] = (_Float16)a1.x; af[5] = (_Float16)a1.y; af[6] = (_Float16)a1.z; af[7] = (_Float16)a1.w;
#pragma unroll
        for (int ct = 0; ct < 4; ++ct) {
            half8 bf = *reinterpret_cast<const half8*>(F1 + ((size_t)(c * 4 + ct) * 64 + lane) * 8);
            acc[ct] = __builtin_amdgcn_mfma_f32_16x16x32_f16(af, bf, acc[ct], 0, 0, 0);
        }
    }
    const int prow = row0 + ((lane >> 4) << 2);
    const int col = lane & 15;
#pragma unroll
    for (int r = 0; r < 4; ++r) {
        int rr = prow + r;
        if (rr < N_NODES) {
            float dv = dis[rr];
#pragma unroll
            for (int ct = 0; ct < 4; ++ct)
                h1[(size_t)rr * 64 + ct * 16 + col] = __float2half(acc[ct][r] * dv);
        }
    }
}

// ============ GEMM2 (MFMA): out = g @ W2 + b2, fp32 out ============
__global__ __launch_bounds__(256) void gemm2_mfma(
        const __half* __restrict__ g, const __half* __restrict__ F2,
        const float* __restrict__ b2, float* __restrict__ out) {
    const int wid = threadIdx.x >> 6, lane = threadIdx.x & 63;
    const int row0 = blockIdx.x * 64 + wid * 16;
    int arow = min(row0 + (lane & 15), N_NODES - 1);
    const int kb0 = (lane >> 4) * 8;
    const __half* ap = g + (size_t)arow * 64 + kb0;

    f32x4 acc[4] = {};
#pragma unroll
    for (int c = 0; c < 2; ++c) {
        half8 af = *reinterpret_cast<const half8*>(ap + c * 32);
#pragma unroll
        for (int ct = 0; ct < 4; ++ct) {
            half8 bf = *reinterpret_cast<const half8*>(F2 + ((size_t)(c * 4 + ct) * 64 + lane) * 8);
            acc[ct] = __builtin_amdgcn_mfma_f32_16x16x32_f16(af, bf, acc[ct], 0, 0, 0);
        }
    }
    const int prow = row0 + ((lane >> 4) << 2);
    const int col = lane & 15;
#pragma unroll
    for (int ct = 0; ct < 4; ++ct) {
        float bb = b2[ct * 16 + col];
#pragma unroll
        for (int r = 0; r < 4; ++r) {
            int rr = prow + r;
            if (rr < N_NODES) out[(size_t)rr * 64 + ct * 16 + col] = acc[ct][r] + bb;
        }
    }
}

// ============ gather: one wave per node; unclamped 16-edge bulk + remainder branch ============
// BIAS_RELU=1 (conv1): out = dis[v]*relu(dis[v]*S + b1).  =0 (conv2): out = dis[v]*S.
template <int BIAS_RELU>
__global__ __launch_bounds__(512) void gather_vec_kernel(
        const __half* __restrict__ h, const int2* __restrict__ csr,
        const int* __restrict__ offsets, const float* __restrict__ bias,
        const float* __restrict__ dis, __half* __restrict__ outh, int n) {
    int node = blockIdx.x * 8 + (threadIdx.x >> 6);
    int lane = threadIdx.x & 63;
    int q = lane & 7;
    int g = lane >> 3;
    int s = offsets[node];
    int e = offsets[node + 1];

    float a0 = 0.f, a1 = 0.f, a2 = 0.f, a3 = 0.f, a4 = 0.f, a5 = 0.f, a6 = 0.f, a7 = 0.f;
#define FMA8(U, NV) { float2 f_; \
    f_ = __half22float2(__builtin_bit_cast(__half2, (U).x)); a0 = fmaf(f_.x, NV, a0); a1 = fmaf(f_.y, NV, a1); \
    f_ = __half22float2(__builtin_bit_cast(__half2, (U).y)); a2 = fmaf(f_.x, NV, a2); a3 = fmaf(f_.y, NV, a3); \
    f_ = __half22float2(__builtin_bit_cast(__half2, (U).z)); a4 = fmaf(f_.x, NV, a4); a5 = fmaf(f_.y, NV, a5); \
    f_ = __half22float2(__builtin_bit_cast(__half2, (U).w)); a6 = fmaf(f_.x, NV, a6); a7 = fmaf(f_.y, NV, a7); }

    int j = s;
    for (; j + 16 <= e; j += 16) {   // bulk: no clamping, no zero-guards
        int2 pA = csr[j + g];
        int2 pB = csr[j + 8 + g];
        uint4 uA = *reinterpret_cast<const uint4*>(h + ((size_t)pA.x << 6) + (q << 3));
        uint4 uB = *reinterpret_cast<const uint4*>(h + ((size_t)pB.x << 6) + (q << 3));
        float nA = __int_as_float(pA.y);
        float nB = __int_as_float(pB.y);
        FMA8(uA, nA); FMA8(uB, nB);
    }
    int rem = e - j;
    if (rem > 8) {                   // 9..15 left: one clamped 16-step
        int eB = j + 8 + g;
        int2 pA = csr[j + g];
        int2 pB = csr[min(eB, e - 1)];
        uint4 uA = *reinterpret_cast<const uint4*>(h + ((size_t)pA.x << 6) + (q << 3));
        uint4 uB = *reinterpret_cast<const uint4*>(h + ((size_t)pB.x << 6) + (q << 3));
        float nA = __int_as_float(pA.y);
        float nB = (eB < e) ? __int_as_float(pB.y) : 0.f;
        FMA8(uA, nA); FMA8(uB, nB);
    } else if (rem > 0) {            // 1..8 left: one clamped 8-step
        int eA = j + g;
        int2 pA = csr[min(eA, e - 1)];
        uint4 uA = *reinterpret_cast<const uint4*>(h + ((size_t)pA.x << 6) + (q << 3));
        float nA = (eA < e) ? __int_as_float(pA.y) : 0.f;
        FMA8(uA, nA);
    }
#undef FMA8
#pragma unroll
    for (int m = 8; m <= 32; m <<= 1) {
        a0 += __shfl_xor(a0, m); a1 += __shfl_xor(a1, m);
        a2 += __shfl_xor(a2, m); a3 += __shfl_xor(a3, m);
        a4 += __shfl_xor(a4, m); a5 += __shfl_xor(a5, m);
        a6 += __shfl_xor(a6, m); a7 += __shfl_xor(a7, m);
    }
    if (g == 0) {
        float dv = dis[node];
        if (BIAS_RELU) {
            const float4 b0 = *reinterpret_cast<const float4*>(bias + (q << 3));
            const float4 b1 = *reinterpret_cast<const float4*>(bias + (q << 3) + 4);
            a0 = fmaxf(fmaf(a0, dv, b0.x), 0.f) * dv; a1 = fmaxf(fmaf(a1, dv, b0.y), 0.f) * dv;
            a2 = fmaxf(fmaf(a2, dv, b0.z), 0.f) * dv; a3 = fmaxf(fmaf(a3, dv, b0.w), 0.f) * dv;
            a4 = fmaxf(fmaf(a4, dv, b1.x), 0.f) * dv; a5 = fmaxf(fmaf(a5, dv, b1.y), 0.f) * dv;
            a6 = fmaxf(fmaf(a6, dv, b1.z), 0.f) * dv; a7 = fmaxf(fmaf(a7, dv, b1.w), 0.f) * dv;
        } else {
            a0 *= dv; a1 *= dv; a2 *= dv; a3 *= dv;
            a4 *= dv; a5 *= dv; a6 *= dv; a7 *= dv;
        }
        __half2 o0 = __float22half2_rn(make_float2(a0, a1));
        __half2 o1 = __float22half2_rn(make_float2(a2, a3));
        __half2 o2 = __float22half2_rn(make_float2(a4, a5));
        __half2 o3 = __float22half2_rn(make_float2(a6, a7));
        uint4 u = make_uint4(__builtin_bit_cast(unsigned, o0), __builtin_bit_cast(unsigned, o1),
                             __builtin_bit_cast(unsigned, o2), __builtin_bit_cast(unsigned, o3));
        *reinterpret_cast<uint4*>(outh + ((size_t)node << 6) + (q << 3)) = u;
    }
}

extern "C" void kernel_launch(void* const* d_in, const int* in_sizes, int n_in,
                              void* d_out, int out_size, void* d_ws, size_t ws_size,
                              hipStream_t stream) {
    const float* x  = (const float*)d_in[0];
    const int*   ei = (const int*)d_in[1];
    const float* ew = (const float*)d_in[2];
    const float* W1 = (const float*)d_in[3];
    const float* b1 = (const float*)d_in[4];
    const float* W2 = (const float*)d_in[5];
    const float* b2 = (const float*)d_in[6];
    float* out = (float*)d_out;
    char*  ws  = (char*)d_ws;

    const int* rows = ei;
    const int* cols = ei + N_EDGES;

    // ---- workspace (byte offsets) ----
    int2*     csr      = (int2*)(ws + 0);                      // 12,800,000
    unsigned long long* pkA = (unsigned long long*)(ws + 12800000);  // 12,800,000 [dies at fill]
    unsigned* pkR      = (unsigned*)(ws + 25600000);           // 6,400,000 [dies at deg]
    __half*   h1       = (__half*)(ws + 12800000);             // fp16, over pkA
    __half*   g        = (__half*)(ws + 12800000);             // fp16, over h1 (gather2 out)
    __half*   t        = (__half*)(ws + 25600000);             // fp16, over pkR (gather1 out)
    int*      M        = (int*)(ws + 38400000);                // 784,000
    int*      Ms       = (int*)(ws + 39184000);                // 784,004
    int*      partials = (int*)(ws + 39968016);                // 768
    int*      offsets  = (int*)(ws + 39968784);                // 400,004
    float*    dis      = (float*)(ws + 40368800);              // 400,000
    __half*   F1       = (__half*)(ws + 40768800);             // 16,384
    __half*   F2       = (__half*)(ws + 40785184);             // 8,192

    const int TPB = 256;
    const int n2  = 2 * MROW;                    // 196,000
    const int nSB2 = (n2 + 1023) / 1024;         // 192

    // 1) histograms (+ merged W-fragment pack, blocks 500..505)
    count_kernel<<<NBLK + 6, TPB, 0, stream>>>(rows, cols, M, W1, W2, F1, F2);

    // 2) one scan chain over the combined matrix
    block_sum_kernel<<<nSB2, 256, 0, stream>>>(M, partials, n2);
    scan_partials_kernel<<<1, 256, 0, stream>>>(partials, nSB2);
    scan_final_kernel<<<nSB2, 256, 0, stream>>>(M, partials, Ms, n2);

    // 3) LDS-sorted scatter into pkA (8B) + pkR (4B), coalesced writes
    scatter_kernel<<<NBLK, TPB, 0, stream>>>(rows, cols, ew, M, Ms, pkA, pkR);

    // 4) merged: offsets + CSR fill (col region) ∥ deg -> dis (row region)
    fill_deg_kernel<<<2 * NBKT, TPB, 0, stream>>>(pkA, pkR, Ms, csr, offsets, dis);

    // 5) h1 = dis * (x @ W1) via MFMA (over dead pkA)
    gemm1_mfma<<<(N_NODES + 63) / 64, TPB, 0, stream>>>(x, F1, dis, h1);

    // 6) t = dis*relu(dis*gather(h1) + b1)  (over dead pkR)
    gather_vec_kernel<1><<<N_NODES / 8, 512, 0, stream>>>(h1, csr, offsets, b1, dis, t, N_NODES);

    // 7) g = dis*gather(t)  (over dead h1)
    gather_vec_kernel<0><<<N_NODES / 8, 512, 0, stream>>>(t, csr, offsets, b1, dis, g, N_NODES);

    // 8) out = g @ W2 + b2 via MFMA
    gemm2_mfma<<<(N_NODES + 63) / 64, TPB, 0, stream>>>(g, F2, b2, out);
}

// Round 13
// 164.074 us; speedup vs baseline: 6.6080x; 1.0107x over previous
//
#include <hip/hip_runtime.h>
#include <hip/hip_fp16.h>

#define N_NODES 100000
#define N_EDGES 1600000
#define IN_DIM 128
#define HID_DIM 64
#define OUT_DIM 64
#define NBKT 196    // node buckets of 512: ceil(100000/512)
#define BSH 9       // bucket shift
#define BMSK 511
#define NBLK 500    // edge-chunk blocks
#define CHUNK 3200  // 500*3200 = 1,600,000 (divisible by 4 for int4 loads)
#define MROW (NBKT * NBLK)   // 98,000: start of row-region in combined count matrix

typedef _Float16 half8 __attribute__((ext_vector_type(8)));
typedef float f32x4 __attribute__((ext_vector_type(4)));

// ============ count (+ merged wfrag): per-block histograms, int4 edge loads ============
__global__ void count_kernel(const int* __restrict__ rows, const int* __restrict__ cols,
                             int* __restrict__ M,
                             const float* __restrict__ W1, const float* __restrict__ W2,
                             __half* __restrict__ F1, __half* __restrict__ F2) {
    __shared__ unsigned hc[NBKT], hr[NBKT];
    if (blockIdx.x >= NBLK) {
        int t = (blockIdx.x - NBLK) * 256 + threadIdx.x;
        if (t < 1024) {
            int lane = t & 63, fg = t >> 6;
            int col = (fg & 3) * 16 + (lane & 15);
            int kb = (fg >> 2) * 32 + (lane >> 4) * 8;
            __half v[8];
#pragma unroll
            for (int j = 0; j < 8; ++j) v[j] = __float2half(W1[(kb + j) * 64 + col]);
            *reinterpret_cast<uint4*>(F1 + (size_t)t * 8) = *reinterpret_cast<uint4*>(v);
        } else if (t < 1536) {
            int u = t - 1024;
            int lane = u & 63, fg = u >> 6;
            int col = (fg & 3) * 16 + (lane & 15);
            int kb = (fg >> 2) * 32 + (lane >> 4) * 8;
            __half v[8];
#pragma unroll
            for (int j = 0; j < 8; ++j) v[j] = __float2half(W2[(kb + j) * 64 + col]);
            *reinterpret_cast<uint4*>(F2 + (size_t)u * 8) = *reinterpret_cast<uint4*>(v);
        }
        return;
    }
    for (int i = threadIdx.x; i < NBKT; i += 256) { hc[i] = 0; hr[i] = 0; }
    __syncthreads();
    const int4* r4 = (const int4*)(rows + blockIdx.x * CHUNK);
    const int4* c4 = (const int4*)(cols + blockIdx.x * CHUNK);
    for (int i = threadIdx.x; i < CHUNK / 4; i += 256) {
        int4 r = r4[i], c = c4[i];
        atomicAdd(&hr[r.x >> BSH], 1u); atomicAdd(&hr[r.y >> BSH], 1u);
        atomicAdd(&hr[r.z >> BSH], 1u); atomicAdd(&hr[r.w >> BSH], 1u);
        atomicAdd(&hc[c.x >> BSH], 1u); atomicAdd(&hc[c.y >> BSH], 1u);
        atomicAdd(&hc[c.z >> BSH], 1u); atomicAdd(&hc[c.w >> BSH], 1u);
    }
    __syncthreads();
    for (int i = threadIdx.x; i < NBKT; i += 256) {
        M[i * NBLK + blockIdx.x] = (int)hc[i];
        M[MROW + i * NBLK + blockIdx.x] = (int)hr[i];
    }
}

// ============ exclusive scan (3 kernels) ============
__global__ void block_sum_kernel(const int* __restrict__ counts, int* __restrict__ partials, int n) {
    __shared__ int sh[256];
    int base = blockIdx.x * 1024;
    int s = 0;
    for (int i = threadIdx.x; i < 1024; i += 256) {
        int idx = base + i;
        s += (idx < n) ? counts[idx] : 0;
    }
    sh[threadIdx.x] = s;
    __syncthreads();
    for (int off = 128; off > 0; off >>= 1) {
        if (threadIdx.x < off) sh[threadIdx.x] += sh[threadIdx.x + off];
        __syncthreads();
    }
    if (threadIdx.x == 0) partials[blockIdx.x] = sh[0];
}

__global__ void scan_partials_kernel(int* __restrict__ p, int nb) {
    __shared__ int sh[256];
    int t = threadIdx.x;
    int v = (t < nb) ? p[t] : 0;
    sh[t] = v;
    __syncthreads();
    for (int off = 1; off < 256; off <<= 1) {
        int add = (t >= off) ? sh[t - off] : 0;
        __syncthreads();
        sh[t] += add;
        __syncthreads();
    }
    if (t < nb) p[t] = sh[t] - v;  // exclusive
}

__global__ void scan_final_kernel(const int* __restrict__ counts, const int* __restrict__ partials,
                                  int* __restrict__ offsets, int n) {
    __shared__ int sh[256];
    int t = threadIdx.x;
    int idx0 = blockIdx.x * 1024 + t * 4;
    int v[4];
    int s = 0;
#pragma unroll
    for (int j = 0; j < 4; ++j) {
        int id = idx0 + j;
        v[j] = (id < n) ? counts[id] : 0;
        s += v[j];
    }
    sh[t] = s;
    __syncthreads();
    for (int off = 1; off < 256; off <<= 1) {
        int add = (t >= off) ? sh[t - off] : 0;
        __syncthreads();
        sh[t] += add;
        __syncthreads();
    }
    int run = sh[t] - s + partials[blockIdx.x];
#pragma unroll
    for (int j = 0; j < 4; ++j) {
        int id = idx0 + j;
        if (id < n) offsets[id] = run;
        run += v[j];
    }
    if (idx0 <= n - 1 && n - 1 < idx0 + 4) offsets[n] = run;
}

// ============ scatter: block-local LDS counting sort, coalesced write-out, int4 reads ============
__global__ __launch_bounds__(256) void scatter_kernel(
        const int* __restrict__ rows, const int* __restrict__ cols,
        const float* __restrict__ w, const int* __restrict__ M, const int* __restrict__ Ms,
        unsigned long long* __restrict__ pkA, unsigned* __restrict__ pkR) {
    __shared__ unsigned long long pay[CHUNK];
    __shared__ unsigned char bkt[CHUNK];
    __shared__ unsigned scn[256];
    __shared__ unsigned base[NBKT], cur[NBKT], gbase[NBKT];
    const int blk = blockIdx.x, t = threadIdx.x;
    const int s = blk * CHUNK;
    const int4* r4 = (const int4*)(rows + s);
    const int4* c4 = (const int4*)(cols + s);
    const float4* w4 = (const float4*)(w + s);

    // ---- stage A: col-bucket payload (w32 | c_local9 | r17) ----
    unsigned cnt = (t < NBKT) ? (unsigned)M[t * NBLK + blk] : 0;
    scn[t] = cnt;
    __syncthreads();
    for (int off = 1; off < 256; off <<= 1) {
        unsigned a = (t >= off) ? scn[t - off] : 0;
        __syncthreads();
        scn[t] += a;
        __syncthreads();
    }
    if (t < NBKT) {
        unsigned b0 = scn[t] - cnt;
        base[t] = b0; cur[t] = b0;
        gbase[t] = (unsigned)Ms[t * NBLK + blk];
    }
    __syncthreads();
#define PUTA(RV, CV, WV) { unsigned b = (unsigned)(CV) >> BSH; \
        unsigned p = atomicAdd(&cur[b], 1u); \
        pay[p] = ((unsigned long long)__float_as_uint(WV) << 32) | \
                 (unsigned)((((CV) & BMSK) << 17) | (RV)); \
        bkt[p] = (unsigned char)b; }
    for (int i = t; i < CHUNK / 4; i += 256) {
        int4 rr = r4[i]; int4 cc = c4[i]; float4 ww = w4[i];
        PUTA(rr.x, cc.x, ww.x); PUTA(rr.y, cc.y, ww.y);
        PUTA(rr.z, cc.z, ww.z); PUTA(rr.w, cc.w, ww.w);
    }
    __syncthreads();
    for (int i = t; i < CHUNK; i += 256) {
        unsigned b = bkt[i];
        pkA[gbase[b] + (i - base[b])] = pay[i];
    }
    __syncthreads();

    // ---- stage B: row-bucket payload (fp16 w << 16 | r_local9) ----
    cnt = (t < NBKT) ? (unsigned)M[MROW + t * NBLK + blk] : 0;
    scn[t] = cnt;
    __syncthreads();
    for (int off = 1; off < 256; off <<= 1) {
        unsigned a = (t >= off) ? scn[t - off] : 0;
        __syncthreads();
        scn[t] += a;
        __syncthreads();
    }
    if (t < NBKT) {
        unsigned b0 = scn[t] - cnt;
        base[t] = b0; cur[t] = b0;
        gbase[t] = (unsigned)Ms[MROW + t * NBLK + blk] - (unsigned)N_EDGES;
    }
    __syncthreads();
    unsigned* pay32 = (unsigned*)pay;
#define PUTR(RV, WV) { unsigned b = (unsigned)(RV) >> BSH; \
        unsigned p = atomicAdd(&cur[b], 1u); \
        pay32[p] = ((unsigned)__half_as_ushort(__float2half(WV)) << 16) | (unsigned)((RV) & BMSK); \
        bkt[p] = (unsigned char)b; }
    for (int i = t; i < CHUNK / 4; i += 256) {
        int4 rr = r4[i]; float4 ww = w4[i];
        PUTR(rr.x, ww.x); PUTR(rr.y, ww.y); PUTR(rr.z, ww.z); PUTR(rr.w, ww.w);
    }
    __syncthreads();
    for (int i = t; i < CHUNK; i += 256) {
        unsigned b = bkt[i];
        pkR[gbase[b] + (i - base[b])] = pay32[i];
    }
}

// ============ merged fill (col region) + deg reduce (row region) ============
__global__ __launch_bounds__(256) void fill_deg_kernel(
        const unsigned long long* __restrict__ pkA, const unsigned* __restrict__ pkR,
        const int* __restrict__ Ms, int2* __restrict__ csr,
        int* __restrict__ offsets, float* __restrict__ dis) {
    __shared__ unsigned sh[768];
    const int t = threadIdx.x;
    if (blockIdx.x < NBKT) {
        unsigned* hist = sh;
        unsigned* pairs = sh + 512;
        const int b = blockIdx.x;
        hist[t] = 0; hist[t + 256] = 0;
        __syncthreads();
        const int s = Ms[b * NBLK];
        const int e = Ms[(b + 1) * NBLK];
        for (int i = s + t; i < e; i += 256) {
            unsigned lo = (unsigned)pkA[i];
            atomicAdd(&hist[(lo >> 17) & (unsigned)BMSK], 1u);
        }
        __syncthreads();
        unsigned h0 = hist[2 * t], h1 = hist[2 * t + 1];
        pairs[t] = h0 + h1;
        __syncthreads();
        for (int off = 1; off < 256; off <<= 1) {
            unsigned add = (t >= off) ? pairs[t - off] : 0;
            __syncthreads();
            pairs[t] += add;
            __syncthreads();
        }
        unsigned P = pairs[t] - (h0 + h1) + (unsigned)s;
        unsigned e0 = P, e1 = P + h0;
        int n0 = b * 512 + 2 * t;
        int n1 = n0 + 1;
        if (n0 <= N_NODES) offsets[n0] = (int)e0;
        if (n1 <= N_NODES) offsets[n1] = (int)e1;
        hist[2 * t] = e0; hist[2 * t + 1] = e1;
        __syncthreads();
        for (int i = s + t; i < e; i += 256) {
            unsigned long long p = pkA[i];
            unsigned lo = (unsigned)p;
            unsigned cl = (lo >> 17) & (unsigned)BMSK;
            int r = (int)(lo & 0x1FFFFu);
            unsigned pos = atomicAdd(&hist[cl], 1u);
            csr[pos] = make_int2(r, (int)(unsigned)(p >> 32));
        }
    } else {
        float* acc = (float*)sh;
        const int b = blockIdx.x - NBKT;
        acc[t] = 0.f; acc[t + 256] = 0.f;
        __syncthreads();
        const int s = Ms[MROW + b * NBLK] - N_EDGES;
        const int e = Ms[MROW + (b + 1) * NBLK] - N_EDGES;
        for (int i = s + t; i < e; i += 256) {
            unsigned u = pkR[i];
            float wv = __half2float(__ushort_as_half((unsigned short)(u >> 16)));
            atomicAdd(&acc[u & (unsigned)BMSK], wv);
        }
        __syncthreads();
#pragma unroll
        for (int k = 0; k < 2; ++k) {
            int node = b * 512 + t + k * 256;
            if (node < N_NODES) {
                float d = acc[t + k * 256];
                dis[node] = d > 0.f ? rsqrtf(fmaxf(d, 1e-12f)) : 0.f;
            }
        }
    }
}

// ============ GEMM1 (MFMA): h1[r] = dis[r] * (x @ W1)[r], fp16 out ============
__global__ __launch_bounds__(256) void gemm1_mfma(
        const float* __restrict__ x, const __half* __restrict__ F1,
        const float* __restrict__ dis, __half* __restrict__ h1) {
    const int wid = threadIdx.x >> 6, lane = threadIdx.x & 63;
    const int row0 = blockIdx.x * 64 + wid * 16;
    int arow = min(row0 + (lane & 15), N_NODES - 1);
    const int kb0 = (lane >> 4) * 8;
    const float* ap = x + (size_t)arow * 128 + kb0;

    f32x4 acc[4] = {};
#pragma unroll
    for (int c = 0; c < 4; ++c) {
        float4 a0 = *reinterpret_cast<const float4*>(ap + c * 32);
        float4 a1 = *reinterpret_cast<const float4*>(ap + c * 32 + 4);
        half8 af;
        af[0] = (_Float16)a0.x; af[1] = (_Float16)a0.y; af[2] = (_Float16)a0.z; af[3] = (_Float16)a0.w;
        af[4] = (_Float16)a1.x; af[5] = (_Float16)a1.y; af[6] = (_Float16)a1.z; af[7] = (_Float16)a1.w;
#pragma unroll
        for (int ct = 0; ct < 4; ++ct) {
            half8 bf = *reinterpret_cast<const half8*>(F1 + ((size_t)(c * 4 + ct) * 64 + lane) * 8);
            acc[ct] = __builtin_amdgcn_mfma_f32_16x16x32_f16(af, bf, acc[ct], 0, 0, 0);
        }
    }
    const int prow = row0 + ((lane >> 4) << 2);
    const int col = lane & 15;
#pragma unroll
    for (int r = 0; r < 4; ++r) {
        int rr = prow + r;
        if (rr < N_NODES) {
            float dv = dis[rr];
#pragma unroll
            for (int ct = 0; ct < 4; ++ct)
                h1[(size_t)rr * 64 + ct * 16 + col] = __float2half(acc[ct][r] * dv);
        }
    }
}

// ============ GEMM2 (MFMA): out = g @ W2 + b2, fp32 out ============
__global__ __launch_bounds__(256) void gemm2_mfma(
        const __half* __restrict__ g, const __half* __restrict__ F2,
        const float* __restrict__ b2, float* __restrict__ out) {
    const int wid = threadIdx.x >> 6, lane = threadIdx.x & 63;
    const int row0 = blockIdx.x * 64 + wid * 16;
    int arow = min(row0 + (lane & 15), N_NODES - 1);
    const int kb0 = (lane >> 4) * 8;
    const __half* ap = g + (size_t)arow * 64 + kb0;

    f32x4 acc[4] = {};
#pragma unroll
    for (int c = 0; c < 2; ++c) {
        half8 af = *reinterpret_cast<const half8*>(ap + c * 32);
#pragma unroll
        for (int ct = 0; ct < 4; ++ct) {
            half8 bf = *reinterpret_cast<const half8*>(F2 + ((size_t)(c * 4 + ct) * 64 + lane) * 8);
            acc[ct] = __builtin_amdgcn_mfma_f32_16x16x32_f16(af, bf, acc[ct], 0, 0, 0);
        }
    }
    const int prow = row0 + ((lane >> 4) << 2);
    const int col = lane & 15;
#pragma unroll
    for (int ct = 0; ct < 4; ++ct) {
        float bb = b2[ct * 16 + col];
#pragma unroll
        for (int r = 0; r < 4; ++r) {
            int rr = prow + r;
            if (rr < N_NODES) out[(size_t)rr * 64 + ct * 16 + col] = acc[ct][r] + bb;
        }
    }
}

// ============ gather: TWO nodes per wave (2x independent load chains for MLP) ============
// lane = 8*g + q. Per iter: 4 independent csr loads -> 4 independent h-row loads
// covering 32 edges (16 per node). Clamped+guarded (guard cost measured ~nil, R12).
__device__ __forceinline__ void fma8(float* a, uint4 u, float nv) {
    float2 f;
    f = __half22float2(__builtin_bit_cast(__half2, u.x)); a[0] = fmaf(f.x, nv, a[0]); a[1] = fmaf(f.y, nv, a[1]);
    f = __half22float2(__builtin_bit_cast(__half2, u.y)); a[2] = fmaf(f.x, nv, a[2]); a[3] = fmaf(f.y, nv, a[3]);
    f = __half22float2(__builtin_bit_cast(__half2, u.z)); a[4] = fmaf(f.x, nv, a[4]); a[5] = fmaf(f.y, nv, a[5]);
    f = __half22float2(__builtin_bit_cast(__half2, u.w)); a[6] = fmaf(f.x, nv, a[6]); a[7] = fmaf(f.y, nv, a[7]);
}

template <int BIAS_RELU>
__device__ __forceinline__ void gather_epilogue(float* a, int node, int q,
                                                const float* bias, const float* dis,
                                                __half* outh) {
    float dv = dis[node];
    if (BIAS_RELU) {
        const float4 b0 = *reinterpret_cast<const float4*>(bias + (q << 3));
        const float4 b1 = *reinterpret_cast<const float4*>(bias + (q << 3) + 4);
        a[0] = fmaxf(fmaf(a[0], dv, b0.x), 0.f) * dv; a[1] = fmaxf(fmaf(a[1], dv, b0.y), 0.f) * dv;
        a[2] = fmaxf(fmaf(a[2], dv, b0.z), 0.f) * dv; a[3] = fmaxf(fmaf(a[3], dv, b0.w), 0.f) * dv;
        a[4] = fmaxf(fmaf(a[4], dv, b1.x), 0.f) * dv; a[5] = fmaxf(fmaf(a[5], dv, b1.y), 0.f) * dv;
        a[6] = fmaxf(fmaf(a[6], dv, b1.z), 0.f) * dv; a[7] = fmaxf(fmaf(a[7], dv, b1.w), 0.f) * dv;
    } else {
#pragma unroll
        for (int k = 0; k < 8; ++k) a[k] *= dv;
    }
    __half2 o0 = __float22half2_rn(make_float2(a[0], a[1]));
    __half2 o1 = __float22half2_rn(make_float2(a[2], a[3]));
    __half2 o2 = __float22half2_rn(make_float2(a[4], a[5]));
    __half2 o3 = __float22half2_rn(make_float2(a[6], a[7]));
    uint4 u = make_uint4(__builtin_bit_cast(unsigned, o0), __builtin_bit_cast(unsigned, o1),
                         __builtin_bit_cast(unsigned, o2), __builtin_bit_cast(unsigned, o3));
    *reinterpret_cast<uint4*>(outh + ((size_t)node << 6) + (q << 3)) = u;
}

template <int BIAS_RELU>
__global__ __launch_bounds__(512) void gather_vec_kernel(
        const __half* __restrict__ h, const int2* __restrict__ csr,
        const int* __restrict__ offsets, const float* __restrict__ bias,
        const float* __restrict__ dis, __half* __restrict__ outh, int n) {
    const int wid = threadIdx.x >> 6;
    const int n0 = blockIdx.x * 16 + wid * 2;   // 6250 * 16 = 100000 exactly
    const int n1 = n0 + 1;
    const int lane = threadIdx.x & 63;
    const int q = lane & 7;
    const int g = lane >> 3;
    const int s0 = offsets[n0], e0 = offsets[n0 + 1];
    const int s1 = offsets[n1], e1 = offsets[n1 + 1];
    const int cl0 = max(e0 - 1, s0);   // degree-0 safe clamp
    const int cl1 = max(e1 - 1, s1);

    float xa[8] = {}, ya[8] = {};
    const int L = max(e0 - s0, e1 - s1);
    for (int j = 0; j < L; j += 16) {
        int iA0 = s0 + j + g,     iB0 = s0 + j + 8 + g;
        int iA1 = s1 + j + g,     iB1 = s1 + j + 8 + g;
        int2 pA0 = csr[min(iA0, cl0)];
        int2 pB0 = csr[min(iB0, cl0)];
        int2 pA1 = csr[min(iA1, cl1)];
        int2 pB1 = csr[min(iB1, cl1)];
        uint4 uA0 = *reinterpret_cast<const uint4*>(h + ((size_t)pA0.x << 6) + (q << 3));
        uint4 uB0 = *reinterpret_cast<const uint4*>(h + ((size_t)pB0.x << 6) + (q << 3));
        uint4 uA1 = *reinterpret_cast<const uint4*>(h + ((size_t)pA1.x << 6) + (q << 3));
        uint4 uB1 = *reinterpret_cast<const uint4*>(h + ((size_t)pB1.x << 6) + (q << 3));
        float nA0 = (iA0 < e0) ? __int_as_float(pA0.y) : 0.f;
        float nB0 = (iB0 < e0) ? __int_as_float(pB0.y) : 0.f;
        float nA1 = (iA1 < e1) ? __int_as_float(pA1.y) : 0.f;
        float nB1 = (iB1 < e1) ? __int_as_float(pB1.y) : 0.f;
        fma8(xa, uA0, nA0); fma8(xa, uB0, nB0);
        fma8(ya, uA1, nA1); fma8(ya, uB1, nB1);
    }
#pragma unroll
    for (int m = 8; m <= 32; m <<= 1) {
#pragma unroll
        for (int k = 0; k < 8; ++k) {
            xa[k] += __shfl_xor(xa[k], m);
            ya[k] += __shfl_xor(ya[k], m);
        }
    }
    if (g == 0) {
        gather_epilogue<BIAS_RELU>(xa, n0, q, bias, dis, outh);
    } else if (g == 1) {
        gather_epilogue<BIAS_RELU>(ya, n1, q, bias, dis, outh);
    }
}

extern "C" void kernel_launch(void* const* d_in, const int* in_sizes, int n_in,
                              void* d_out, int out_size, void* d_ws, size_t ws_size,
                              hipStream_t stream) {
    const float* x  = (const float*)d_in[0];
    const int*   ei = (const int*)d_in[1];
    const float* ew = (const float*)d_in[2];
    const float* W1 = (const float*)d_in[3];
    const float* b1 = (const float*)d_in[4];
    const float* W2 = (const float*)d_in[5];
    const float* b2 = (const float*)d_in[6];
    float* out = (float*)d_out;
    char*  ws  = (char*)d_ws;

    const int* rows = ei;
    const int* cols = ei + N_EDGES;

    // ---- workspace (byte offsets) ----
    int2*     csr      = (int2*)(ws + 0);                      // 12,800,000
    unsigned long long* pkA = (unsigned long long*)(ws + 12800000);  // [dies at fill]
    unsigned* pkR      = (unsigned*)(ws + 25600000);           // [dies at deg]
    __half*   h1       = (__half*)(ws + 12800000);             // fp16, over pkA
    __half*   g        = (__half*)(ws + 12800000);             // fp16, over h1 (gather2 out)
    __half*   t        = (__half*)(ws + 25600000);             // fp16, over pkR (gather1 out)
    int*      M        = (int*)(ws + 38400000);                // 784,000
    int*      Ms       = (int*)(ws + 39184000);                // 784,004
    int*      partials = (int*)(ws + 39968016);                // 768
    int*      offsets  = (int*)(ws + 39968784);                // 400,004
    float*    dis      = (float*)(ws + 40368800);              // 400,000
    __half*   F1       = (__half*)(ws + 40768800);             // 16,384
    __half*   F2       = (__half*)(ws + 40785184);             // 8,192

    const int TPB = 256;
    const int n2  = 2 * MROW;                    // 196,000
    const int nSB2 = (n2 + 1023) / 1024;         // 192

    // 1) histograms (+ merged W-fragment pack)
    count_kernel<<<NBLK + 6, TPB, 0, stream>>>(rows, cols, M, W1, W2, F1, F2);

    // 2) one scan chain over the combined matrix
    block_sum_kernel<<<nSB2, 256, 0, stream>>>(M, partials, n2);
    scan_partials_kernel<<<1, 256, 0, stream>>>(partials, nSB2);
    scan_final_kernel<<<nSB2, 256, 0, stream>>>(M, partials, Ms, n2);

    // 3) LDS-sorted scatter into pkA (8B) + pkR (4B), coalesced writes
    scatter_kernel<<<NBLK, TPB, 0, stream>>>(rows, cols, ew, M, Ms, pkA, pkR);

    // 4) merged: offsets + CSR fill (col region) ∥ deg -> dis (row region)
    fill_deg_kernel<<<2 * NBKT, TPB, 0, stream>>>(pkA, pkR, Ms, csr, offsets, dis);

    // 5) h1 = dis * (x @ W1) via MFMA (over dead pkA)
    gemm1_mfma<<<(N_NODES + 63) / 64, TPB, 0, stream>>>(x, F1, dis, h1);

    // 6) t = dis*relu(dis*gather(h1) + b1)  (over dead pkR)
    gather_vec_kernel<1><<<N_NODES / 16, 512, 0, stream>>>(h1, csr, offsets, b1, dis, t, N_NODES);

    // 7) g = dis*gather(t)  (over dead h1)
    gather_vec_kernel<0><<<N_NODES / 16, 512, 0, stream>>>(t, csr, offsets, b1, dis, g, N_NODES);

    // 8) out = g @ W2 + b2 via MFMA
    gemm2_mfma<<<(N_NODES + 63) / 64, TPB, 0, stream>>>(g, F2, b2, out);
}